// Round 3
// baseline (269383.276 us; speedup 1.0000x reference)
//
#include <hip/hip_runtime.h>
#include <math.h>

#define DEV static __device__ __forceinline__
typedef unsigned short u16;
typedef unsigned int u32;

DEV float sigm(float x){ return 1.0f/(1.0f+__expf(-x)); }
DEV float tanh_f(float x){ float e=__expf(2.0f*x); return 1.0f - 2.0f/(e+1.0f); }

DEV float b2f(u16 u){ union {u32 i; float f;} c; c.i = ((u32)u)<<16; return c.f; }
DEV u16 f2b(float f){ union {u32 i; float f;} c; c.f = f; u32 r = (c.i + 0x7FFFu + ((c.i>>16)&1u)) >> 16; return (u16)r; }

// ---------------- grid barrier (device-scope) -------------------------------
DEV void gridbar(unsigned* bar, unsigned nwg){
  __threadfence();
  __syncthreads();
  if (threadIdx.x==0){
    unsigned g = __hip_atomic_load(bar+1, __ATOMIC_RELAXED, __HIP_MEMORY_SCOPE_AGENT);
    unsigned a = __hip_atomic_fetch_add(bar, 1u, __ATOMIC_ACQ_REL, __HIP_MEMORY_SCOPE_AGENT);
    if (a == nwg-1u){
      __hip_atomic_store(bar, 0u, __ATOMIC_RELAXED, __HIP_MEMORY_SCOPE_AGENT);
      __hip_atomic_fetch_add(bar+1, 1u, __ATOMIC_RELEASE, __HIP_MEMORY_SCOPE_AGENT);
    } else {
      unsigned long long sp=0;
      while (__hip_atomic_load(bar+1, __ATOMIC_ACQUIRE, __HIP_MEMORY_SCOPE_AGENT)==g){
        if (++sp > 4000000000ull) break; // safety: garbage instead of hang
      }
    }
  }
  __syncthreads();
}

// ---------------- persistent cooperative LSTM layer ------------------------
// INBF/OUTBF: bf16 (1) or fp32 (0) for xin / hseq. hcur + cell state stay fp32.
template<int KX, int H, int CPW, int KSPLIT, int INBF, int OUTBF>
__global__ __launch_bounds__(256,1) void rec_lstm(
    const void* __restrict__ xin_, long bstr, long tstr,
    const float* __restrict__ Wih, const float* __restrict__ Whh,
    const float* __restrict__ bias,
    void* __restrict__ hseq_, int ldOut, int offOut,
    float* __restrict__ hcur, int T, int rev, unsigned* __restrict__ bar)
{
  constexpr int KTOT = KX + H;
  constexpr int U = CPW/4;
  constexpr int KCH = KTOT/KSPLIT;
  constexpr unsigned NWG = 128;
  __shared__ __align__(16) float vT[KTOT*36];
  __shared__ float gl[CPW*32];
  __shared__ float red[1024];
  __shared__ float cst[U*32];
  const int t = threadIdx.x;
  const int wg = blockIdx.x;
  for (int i = wg*256+t; i < 32*H; i += 128*256) hcur[i] = 0.0f; // zero parity 0
  if (t < U*32) cst[t] = 0.0f;
  gridbar(bar, NWG);
  const int ks  = (KSPLIT==2) ? (t>>7) : (t>>6);   // wave-uniform k-split id
  const int c_l = (t>>3) & (CPW-1);
  const int bq  = t & 7;
  const int col = (c_l&3)*H + wg*U + (c_l>>2);
  const float* wih_row = Wih + (long)col*KX;
  const float* wh2     = Whh + (long)col*H - KX;
  const int kbeg = ks*KCH, kend = kbeg+KCH;
  const int kx_hi = (kend < KX) ? kend : KX;
  const int kh_lo = (kbeg > KX) ? kbeg : KX;
  for (int s=0; s<T; ++s){
    const int tt = rev ? (T-1-s) : s;
    const float* hc = hcur + (s&1)*32*H;
    // stage [x_t | h] transposed: vT[k*36 + b]
    for (int i = t*4; i < 32*KTOT; i += 1024){
      int b = i / KTOT;
      int k = i - b*KTOT;
      float4 v;
      if (k < KX){
        if (INBF){
          const u16* xp = (const u16*)xin_ + (long)b*bstr + (long)tt*tstr + k;
          ushort4 u = *(const ushort4*)xp;
          v.x=b2f(u.x); v.y=b2f(u.y); v.z=b2f(u.z); v.w=b2f(u.w);
        } else {
          v = *(const float4*)((const float*)xin_ + (long)b*bstr + (long)tt*tstr + k);
        }
      } else v = *(const float4*)(hc + b*H + (k-KX));
      vT[(k+0)*36+b]=v.x; vT[(k+1)*36+b]=v.y; vT[(k+2)*36+b]=v.z; vT[(k+3)*36+b]=v.w;
    }
    __syncthreads();
    float a0=0.f,a1=0.f,a2=0.f,a3=0.f;
    for (int k=kbeg;k<kx_hi;k+=4){
      float4 w = *(const float4*)(wih_row+k);
      const float* vp = &vT[k*36 + bq*4];
      float4 v0=*(const float4*)(vp), v1=*(const float4*)(vp+36), v2=*(const float4*)(vp+72), v3=*(const float4*)(vp+108);
      a0 += w.x*v0.x + w.y*v1.x + w.z*v2.x + w.w*v3.x;
      a1 += w.x*v0.y + w.y*v1.y + w.z*v2.y + w.w*v3.y;
      a2 += w.x*v0.z + w.y*v1.z + w.z*v2.z + w.w*v3.z;
      a3 += w.x*v0.w + w.y*v1.w + w.z*v2.w + w.w*v3.w;
    }
    for (int k=kh_lo;k<kend;k+=4){
      float4 w = *(const float4*)(wh2+k);
      const float* vp = &vT[k*36 + bq*4];
      float4 v0=*(const float4*)(vp), v1=*(const float4*)(vp+36), v2=*(const float4*)(vp+72), v3=*(const float4*)(vp+108);
      a0 += w.x*v0.x + w.y*v1.x + w.z*v2.x + w.w*v3.x;
      a1 += w.x*v0.y + w.y*v1.y + w.z*v2.y + w.w*v3.y;
      a2 += w.x*v0.z + w.y*v1.z + w.z*v2.z + w.w*v3.z;
      a3 += w.x*v0.w + w.y*v1.w + w.z*v2.w + w.w*v3.w;
    }
    {
      float* rp = &red[((c_l*8+bq)*KSPLIT + ks)*4];
      rp[0]=a0; rp[1]=a1; rp[2]=a2; rp[3]=a3;
    }
    __syncthreads();
    if (t < CPW*8){
      const int c=t>>3, q=t&7;
      const int colc = (c&3)*H + wg*U + (c>>2);
      float g0=bias[colc], g1=g0, g2=g0, g3=g0;
      #pragma unroll
      for (int kk=0;kk<KSPLIT;++kk){
        const float* rp = &red[((c*8+q)*KSPLIT+kk)*4];
        g0+=rp[0]; g1+=rp[1]; g2+=rp[2]; g3+=rp[3];
      }
      gl[c*32+q*4+0]=g0; gl[c*32+q*4+1]=g1; gl[c*32+q*4+2]=g2; gl[c*32+q*4+3]=g3;
    }
    __syncthreads();
    if (t < U*32){
      const int u_=t>>5, b=t&31;
      const float gi=gl[(u_*4+0)*32+b], gf=gl[(u_*4+1)*32+b], gg=gl[(u_*4+2)*32+b], go=gl[(u_*4+3)*32+b];
      float c2 = sigm(gf)*cst[t] + sigm(gi)*tanh_f(gg);
      float h2 = sigm(go)*tanh_f(c2);
      cst[t]=c2;
      const int ug = wg*U+u_;
      hcur[(((s&1)^1))*32*H + b*H + ug] = h2;
      const long oi = (long)(tt*32+b)*ldOut + offOut + ug;
      if (OUTBF) ((u16*)hseq_)[oi] = f2b(h2);
      else       ((float*)hseq_)[oi] = h2;
    }
    gridbar(bar, NWG);
  }
}

// ---------------- tiled GEMM: C = [A0|A1] . W^T + bias ---------------------
// A = concat along k at K0 (pass A1=A0, K0=K for single input). ABF/CBF dtype flags.
template<int ABF, int CBF>
__global__ __launch_bounds__(256,1) void gemm_bias(
  const void* __restrict__ A0, long lda0, const void* __restrict__ A1, long lda1, int K0,
  const float* __restrict__ W, const float* __restrict__ bias, void* __restrict__ C,
  int M, int N, int K, int ldw, int act)
{
  __shared__ __align__(16) float As[16*132];
  __shared__ __align__(16) float Bs[16*132];
  const int t = threadIdx.x;
  const int m0 = blockIdx.x*128, n0 = blockIdx.y*128;
  const int tx = t&15, ty = t>>4;
  float acc[8][8];
  for (int i=0;i<8;++i)
    for (int j=0;j<8;++j) acc[i][j]=0.f;
  const int row = t>>1, seg = t&1;
  for (int k0=0;k0<K;k0+=16){
    {
      const int kk = k0 + seg*8;
      const void* Ab; long lda; int kof;
      if (kk < K0){ Ab=A0; lda=lda0; kof=kk; } else { Ab=A1; lda=lda1; kof=kk-K0; }
      float v[8];
      if (ABF){
        const u16* ap = (const u16*)Ab + (long)(m0+row)*lda + kof;
        union { uint4 q; u16 s[8]; } u; u.q = *(const uint4*)ap;
        #pragma unroll
        for (int j=0;j<8;++j) v[j]=b2f(u.s[j]);
      } else {
        const float* ap = (const float*)Ab + (long)(m0+row)*lda + kof;
        float4 x0 = *(const float4*)(ap);
        float4 x1 = *(const float4*)(ap+4);
        v[0]=x0.x;v[1]=x0.y;v[2]=x0.z;v[3]=x0.w;v[4]=x1.x;v[5]=x1.y;v[6]=x1.z;v[7]=x1.w;
      }
      const int kb = seg*8;
      #pragma unroll
      for (int j=0;j<8;++j) As[(kb+j)*132+row]=v[j];
    }
    {
      const int n = n0 + row;
      float4 y0 = {0,0,0,0}, y1 = {0,0,0,0};
      if (n < N){
        const float* wp = W + (long)n*ldw + k0 + seg*8;
        y0 = *(const float4*)(wp); y1 = *(const float4*)(wp+4);
      }
      const int kb = seg*8;
      Bs[(kb+0)*132+row]=y0.x; Bs[(kb+1)*132+row]=y0.y; Bs[(kb+2)*132+row]=y0.z; Bs[(kb+3)*132+row]=y0.w;
      Bs[(kb+4)*132+row]=y1.x; Bs[(kb+5)*132+row]=y1.y; Bs[(kb+6)*132+row]=y1.z; Bs[(kb+7)*132+row]=y1.w;
    }
    __syncthreads();
    #pragma unroll
    for (int k=0;k<16;++k){
      const float* ap = &As[k*132 + ty*8];
      const float* bp = &Bs[k*132 + tx*8];
      float4 A0v=*(const float4*)(ap), A1v=*(const float4*)(ap+4);
      float4 B0v=*(const float4*)(bp), B1v=*(const float4*)(bp+4);
      float av[8]={A0v.x,A0v.y,A0v.z,A0v.w,A1v.x,A1v.y,A1v.z,A1v.w};
      float bv[8]={B0v.x,B0v.y,B0v.z,B0v.w,B1v.x,B1v.y,B1v.z,B1v.w};
      #pragma unroll
      for (int i=0;i<8;++i){
        #pragma unroll
        for (int j=0;j<8;++j) acc[i][j] += av[i]*bv[j];
      }
    }
    __syncthreads();
  }
  float bv[8];
  #pragma unroll
  for (int j=0;j<8;++j){ int n = n0+tx*8+j; bv[j] = (n<N)? bias[n] : 0.f; }
  const bool full = (n0+128 <= N);
  #pragma unroll
  for (int i=0;i<8;++i){
    const int m = m0 + ty*8 + i;
    float v[8];
    #pragma unroll
    for (int j=0;j<8;++j){
      float x = acc[i][j] + bv[j];
      if (act) x = (x > 0.f) ? x : 0.1f*x;
      v[j] = x;
    }
    if (CBF){ // bf16 out: callers guarantee full tiles (N%128==0)
      u16* cp = (u16*)C + (long)m*N + n0 + tx*8;
      union { uint4 q; u16 s[8]; } u;
      #pragma unroll
      for (int j=0;j<8;++j) u.s[j]=f2b(v[j]);
      *(uint4*)cp = u.q;
    } else {
      float* cp = (float*)C + (long)m*N + n0 + tx*8;
      if (full){
        float4 s0 = {v[0],v[1],v[2],v[3]}, s1 = {v[4],v[5],v[6],v[7]};
        *(float4*)(cp) = s0; *(float4*)(cp+4) = s1;
      } else {
        #pragma unroll
        for (int j=0;j<8;++j) if (n0+tx*8+j < N) cp[j] = v[j];
      }
    }
  }
}

// ---------------- elementwise helpers --------------------------------------
__global__ void mask_bf16(u16* __restrict__ buf, int F, const float* __restrict__ xm){
  long id8 = ((long)blockIdx.x*256 + threadIdx.x)*8;
  int row = (int)(id8 / F);
  int tt = row>>5, b = row&31;
  float m = xm[b*4096 + 4*tt];
  union { uint4 q; u16 s[8]; } u;
  u.q = *(uint4*)(buf + id8);
  #pragma unroll
  for (int j=0;j<8;++j) u.s[j] = f2b(b2f(u.s[j])*m);
  *(uint4*)(buf + id8) = u.q;
}

__global__ void embed_gather(const float* __restrict__ emb, const int* __restrict__ y,
                             float* __restrict__ out){
  int id = blockIdx.x*256 + threadIdx.x; // 2048*256
  int p = id&255, r = id>>8;
  int l = r>>5, b = r&31;
  out[id] = emb[(long)y[b*65 + l]*256 + p];
}

__global__ void zero_f(float* __restrict__ p, int n){
  int id = blockIdx.x*256 + threadIdx.x;
  if (id < n) p[id] = 0.f;
}

__global__ void set_val(float* p, float v){ p[0] = v; }

__global__ void attfea_k(const float* __restrict__ lstms, const float* __restrict__ ctxs,
                         const float* __restrict__ ym, float* __restrict__ attf){
  long id4 = ((long)blockIdx.x*256 + threadIdx.x)*4; // 2048*512
  int r = (int)(id4>>9); int f = (int)(id4&511);
  int l = r>>5, b = r&31;
  float m = ym[b*65 + l + 1];
  float4 v = (f<256) ? *(const float4*)(lstms + (long)r*256 + f)
                     : *(const float4*)(ctxs  + (long)r*256 + (f-256));
  v.x*=m; v.y*=m; v.z*=m; v.w*=m;
  *(float4*)(attf + id4) = v;
}

__global__ void dcat_k(const float* __restrict__ attf, const float* __restrict__ dout,
                       const float* __restrict__ ym, float* __restrict__ dcat){
  long id4 = ((long)blockIdx.x*256 + threadIdx.x)*4; // 2048*768
  int r = (int)(id4/768); int f = (int)(id4 - (long)r*768);
  int l = r>>5, b = r&31;
  float m = ym[b*65 + l + 1];
  float4 v = (f<512) ? *(const float4*)(attf + (long)r*512 + f)
                     : *(const float4*)(dout + (long)r*256 + (f-512));
  v.x*=m; v.y*=m; v.z*=m; v.w*=m;
  *(float4*)(dcat + id4) = v;
}

// ---------------- decoder attention step kernels ----------------------------
__global__ __launch_bounds__(256,1) void k1_dec(
  const float* __restrict__ bodyR, float* __restrict__ bodyW,
  const float* __restrict__ epart, const float* __restrict__ Whh,
  const float* __restrict__ Wih, float* __restrict__ cc,
  float* __restrict__ lstms, int s)
{
  __shared__ __align__(16) float vT[512*36];
  __shared__ float gl[32*32];
  const int t = threadIdx.x, wg = blockIdx.x; // 32 WGs
  for (int i = t*4; i < 32*512; i += 1024){
    int b = i>>9, k = i&511;
    float4 v = *(const float4*)(bodyR + b*512 + k);
    vT[(k+0)*36+b]=v.x; vT[(k+1)*36+b]=v.y; vT[(k+2)*36+b]=v.z; vT[(k+3)*36+b]=v.w;
  }
  __syncthreads();
  const int c_l = t>>3, bq = t&7;
  const int col = (c_l&3)*256 + wg*8 + (c_l>>2);
  float a0=0.f,a1=0.f,a2=0.f,a3=0.f;
  for (int k=0;k<256;k+=4){
    float4 w = *(const float4*)(Whh + (long)col*256 + k);
    const float* vp = &vT[k*36 + bq*4];
    float4 v0=*(const float4*)(vp), v1=*(const float4*)(vp+36), v2=*(const float4*)(vp+72), v3=*(const float4*)(vp+108);
    a0 += w.x*v0.x + w.y*v1.x + w.z*v2.x + w.w*v3.x;
    a1 += w.x*v0.y + w.y*v1.y + w.z*v2.y + w.w*v3.y;
    a2 += w.x*v0.z + w.y*v1.z + w.z*v2.z + w.w*v3.z;
    a3 += w.x*v0.w + w.y*v1.w + w.z*v2.w + w.w*v3.w;
  }
  for (int k=256;k<512;k+=4){
    float4 w = *(const float4*)(Wih + (long)col*512 + k);
    const float* vp = &vT[k*36 + bq*4];
    float4 v0=*(const float4*)(vp), v1=*(const float4*)(vp+36), v2=*(const float4*)(vp+72), v3=*(const float4*)(vp+108);
    a0 += w.x*v0.x + w.y*v1.x + w.z*v2.x + w.w*v3.x;
    a1 += w.x*v0.y + w.y*v1.y + w.z*v2.y + w.w*v3.y;
    a2 += w.x*v0.z + w.y*v1.z + w.z*v2.z + w.w*v3.z;
    a3 += w.x*v0.w + w.y*v1.w + w.z*v2.w + w.w*v3.w;
  }
  gl[c_l*32+bq*4+0] = a0 + epart[((long)s*32 + bq*4+0)*1024 + col];
  gl[c_l*32+bq*4+1] = a1 + epart[((long)s*32 + bq*4+1)*1024 + col];
  gl[c_l*32+bq*4+2] = a2 + epart[((long)s*32 + bq*4+2)*1024 + col];
  gl[c_l*32+bq*4+3] = a3 + epart[((long)s*32 + bq*4+3)*1024 + col];
  __syncthreads();
  {
    const int u_ = t>>5, b = t&31, ug = wg*8 + u_;
    const float gi=gl[(u_*4+0)*32+b], gf=gl[(u_*4+1)*32+b], gg=gl[(u_*4+2)*32+b], go=gl[(u_*4+3)*32+b];
    float c0 = cc[b*256+ug];
    float c2 = sigm(gf)*c0 + sigm(gi)*tanh_f(gg);
    float h2 = sigm(go)*tanh_f(c2);
    cc[b*256+ug] = c2;
    bodyW[b*512 + ug] = h2;
    lstms[((long)s*32 + b)*256 + ug] = h2;
  }
}

__global__ __launch_bounds__(256,1) void k2_dec(
  const float* __restrict__ bodyW, const float* __restrict__ vW,
  const float* __restrict__ vb, float* __restrict__ state)
{
  __shared__ __align__(16) float hT[256*36];
  const int t = threadIdx.x, wg = blockIdx.x;
  for (int i = t*4; i < 8192; i += 1024){
    int b = i>>8, k = i&255;
    float4 v = *(const float4*)(bodyW + b*512 + k);
    hT[(k+0)*36+b]=v.x; hT[(k+1)*36+b]=v.y; hT[(k+2)*36+b]=v.z; hT[(k+3)*36+b]=v.w;
  }
  __syncthreads();
  const int p = wg*32 + (t>>3), bq = t&7;
  float a0=0.f,a1=0.f,a2=0.f,a3=0.f;
  for (int k=0;k<256;k+=4){
    float4 w = *(const float4*)(vW + (long)p*256 + k);
    const float* vp = &hT[k*36 + bq*4];
    float4 v0=*(const float4*)(vp), v1=*(const float4*)(vp+36), v2=*(const float4*)(vp+72), v3=*(const float4*)(vp+108);
    a0 += w.x*v0.x + w.y*v1.x + w.z*v2.x + w.w*v3.x;
    a1 += w.x*v0.y + w.y*v1.y + w.z*v2.y + w.w*v3.y;
    a2 += w.x*v0.z + w.y*v1.z + w.z*v2.z + w.w*v3.z;
    a3 += w.x*v0.w + w.y*v1.w + w.z*v2.w + w.w*v3.w;
  }
  float bb = vb[p];
  state[(bq*4+0)*256 + p] = a0 + bb;
  state[(bq*4+1)*256 + p] = a1 + bb;
  state[(bq*4+2)*256 + p] = a2 + bb;
  state[(bq*4+3)*256 + p] = a3 + bb;
}

// K3: atth is bf16
__global__ __launch_bounds__(256,1) void k3_dec(
  const float* __restrict__ state, const u16* __restrict__ atth,
  const float* __restrict__ wav, const float* __restrict__ xm,
  float* __restrict__ sc, float* __restrict__ scm)
{
  __shared__ float st[256], wv[256], red[256];
  const int t = threadIdx.x;
  const int b = blockIdx.x>>2, ch = blockIdx.x&3;
  st[t] = state[b*256 + t];
  wv[t] = wav[t];
  __syncthreads();
  const int tp = ch*256 + t;
  const u16* ap = atth + ((long)tp*32 + b)*256;
  float acc = 0.f;
  for (int p=0;p<256;p+=4){
    ushort4 a = *(const ushort4*)(ap+p);
    acc += wv[p+0]*tanh_f(st[p+0]+b2f(a.x));
    acc += wv[p+1]*tanh_f(st[p+1]+b2f(a.y));
    acc += wv[p+2]*tanh_f(st[p+2]+b2f(a.z));
    acc += wv[p+3]*tanh_f(st[p+3]+b2f(a.w));
  }
  acc += (xm[b*4096 + 4*tp] - 1.0f)*1e30f;
  sc[b*1024 + tp] = acc;
  red[t] = acc;
  __syncthreads();
  for (int o=128;o>0;o>>=1){ if (t<o) red[t]=fmaxf(red[t],red[t+o]); __syncthreads(); }
  if (t==0) scm[b*4+ch] = red[0];
}

// K4: eout is bf16
__global__ __launch_bounds__(256,1) void k4_dec(
  const float* __restrict__ sc, const float* __restrict__ scm,
  const u16* __restrict__ eout, float* __restrict__ ctxs,
  float* __restrict__ bodyW, int s)
{
  __shared__ float al[1024];
  __shared__ float red[256];
  const int t = threadIdx.x, b = blockIdx.x;
  float m = fmaxf(fmaxf(scm[b*4+0],scm[b*4+1]), fmaxf(scm[b*4+2],scm[b*4+3]));
  float ps = 0.f;
  #pragma unroll
  for (int j=0;j<4;++j){
    int tp = t + j*256;
    float e = __expf(sc[b*1024+tp] - m);
    al[tp] = e; ps += e;
  }
  red[t]=ps; __syncthreads();
  for (int o=128;o>0;o>>=1){ if (t<o) red[t]+=red[t+o]; __syncthreads(); }
  float rinv = 1.0f/red[0];
  float acc = 0.f;
  const u16* ep = eout + b*256 + t;
  for (int tp=0;tp<1024;++tp) acc += al[tp] * b2f(ep[(long)tp*8192]);
  float cv = acc*rinv;
  ctxs[((long)s*32 + b)*256 + t] = cv;
  bodyW[b*512 + 256 + t] = cv;
}

// ---------------- loss ------------------------------------------------------
__global__ __launch_bounds__(256,1) void loss_row(
  const float* __restrict__ logits, const int* __restrict__ y,
  const float* __restrict__ ym, float* __restrict__ rows)
{
  __shared__ float red[256];
  const int r = blockIdx.x, t = threadIdx.x;
  const float* row = logits + (long)r*4235;
  float mx = -3.0e38f;
  for (int i=t;i<4235;i+=256) mx = fmaxf(mx, row[i]);
  red[t]=mx; __syncthreads();
  for (int o=128;o>0;o>>=1){ if (t<o) red[t]=fmaxf(red[t],red[t+o]); __syncthreads(); }
  const float M = red[0];
  __syncthreads();
  float se=0.f, sl=0.f;
  for (int i=t;i<4235;i+=256){ float v=row[i]; se += __expf(v-M); sl += v; }
  red[t]=se; __syncthreads();
  for (int o=128;o>0;o>>=1){ if (t<o) red[t]+=red[t+o]; __syncthreads(); }
  const float SE = red[0];
  __syncthreads();
  red[t]=sl; __syncthreads();
  for (int o=128;o>0;o>>=1){ if (t<o) red[t]+=red[t+o]; __syncthreads(); }
  const float SL = red[0];
  if (t==0){
    const int tt = r>>5, b = r&31;
    const float lse = M + logf(SE);
    const float mk = (ym[b*65 + tt + 1] > 0.f) ? 1.f : 0.f;
    rows[r]        = (4235.0f*lse - SL)*mk;
    rows[2048 + r] = (lse - row[y[b*65 + tt + 1]])*mk;
    rows[4096 + r] = mk;
  }
}

__global__ __launch_bounds__(256,1) void loss_final(const float* __restrict__ rows, float* __restrict__ out){
  __shared__ float red[256];
  const int t = threadIdx.x;
  float s1=0.f,s2=0.f,s3=0.f;
  for (int i=t;i<2048;i+=256){ s1+=rows[i]; s2+=rows[2048+i]; s3+=rows[4096+i]; }
  red[t]=s1; __syncthreads();
  for (int o=128;o>0;o>>=1){ if (t<o) red[t]+=red[t+o]; __syncthreads(); }
  const float S = red[0]; __syncthreads();
  red[t]=s2; __syncthreads();
  for (int o=128;o>0;o>>=1){ if (t<o) red[t]+=red[t+o]; __syncthreads(); }
  const float NL = red[0]; __syncthreads();
  red[t]=s3; __syncthreads();
  for (int o=128;o>0;o>>=1){ if (t<o) red[t]+=red[t+o]; __syncthreads(); }
  const float N = red[0];
  if (t==0){
    float n = (N > 0.f) ? N : 1.f;
    out[0] = (S/n)*(0.1f/4235.0f) + 0.9f*(NL/n);
  }
}

// ---------------- launcher --------------------------------------------------
extern "C" void kernel_launch(void* const* d_in, const int* in_sizes, int n_in,
                              void* d_out, int out_size, void* d_ws, size_t ws_size,
                              hipStream_t stream)
{
  const float* x    = (const float*)d_in[0];
  const float* xm   = (const float*)d_in[1];
  const int*   y    = (const int*)  d_in[2];
  const float* ym   = (const float*)d_in[3];
  const float* l1_Wih=(const float*)d_in[4];  const float* l1_Whh=(const float*)d_in[5];  const float* l1_b=(const float*)d_in[6];
  const float* l2_Wih=(const float*)d_in[7];  const float* l2_Whh=(const float*)d_in[8];  const float* l2_b=(const float*)d_in[9];
  const float* l3_Wih=(const float*)d_in[10]; const float* l3_Whh=(const float*)d_in[11]; const float* l3_b=(const float*)d_in[12];
  const float* bf_Wih=(const float*)d_in[13]; const float* bf_Whh=(const float*)d_in[14]; const float* bf_b=(const float*)d_in[15];
  const float* bb_Wih=(const float*)d_in[16]; const float* bb_Whh=(const float*)d_in[17]; const float* bb_b=(const float*)d_in[18];
  const float* c1_W=(const float*)d_in[19]; const float* c1_b=(const float*)d_in[20];
  const float* c2_W=(const float*)d_in[21]; const float* c2_b=(const float*)d_in[22];
  const float* emb =(const float*)d_in[23];
  const float* att_Wih=(const float*)d_in[24]; const float* att_Whh=(const float*)d_in[25]; const float* att_b=(const float*)d_in[26];
  const float* w_W=(const float*)d_in[27]; const float* w_b=(const float*)d_in[28];
  const float* v_W=(const float*)d_in[29]; const float* v_b=(const float*)d_in[30];
  const float* wav=(const float*)d_in[31];
  const float* dec_Wih=(const float*)d_in[32]; const float* dec_Whh=(const float*)d_in[33]; const float* dec_b=(const float*)d_in[34];
  const float* cls_W=(const float*)d_in[35]; const float* cls_b=(const float*)d_in[36];

  // workspace layout (bytes)
  const size_t o_bar  = 0;
  const size_t o_hcur = 256;                      // 2*32*512 fp32 = 128KB
  const size_t o_r0   = 262144;                   // 32 MiB (bf16 seq / decoder arena)
  const size_t o_r1   = o_r0 + 33554432ull;       // 35 MiB (bf16 seq / fp32 LOGIT)
  const size_t o_r2   = o_r1 + 36700160ull;       // 64 MiB (h3 -> c1out | eout | atth)
  const size_t REQ    = o_r2 + 67108864ull;       // ~131.3 MiB
  if (ws_size < REQ){
    set_val<<<1,1,0,stream>>>((float*)d_out, -(float)(ws_size>>20)); // report ws MiB
    return;
  }
  char* ws = (char*)d_ws;
  unsigned* bar = (unsigned*)(ws + o_bar);
  float* hcur = (float*)(ws + o_hcur);
  u16* R0  = (u16*)(ws + o_r0);
  u16* R1  = (u16*)(ws + o_r1);
  u16* R2a = (u16*)(ws + o_r2);           // 32768x512 bf16 (h3, then conv1 out)
  u16* R2b = R2a + 16777216;              // 32768x256 bf16 (eout)
  u16* R2c = R2b + 8388608;               // 32768x256 bf16 (att_h)
  float* LOGIT = (float*)(ws + o_r1);     // 2048x4235 fp32 (after bb consumed)
  // decoder arena overlays R0 (bf consumed after conv1)
  float* AR    = (float*)(ws + o_r0);
  float* EMBED = AR;                      // 2048*256
  float* EPART = EMBED + 524288;          // 2048*1024
  float* LSTMS = EPART + 2097152;         // 2048*256
  float* CTXS  = LSTMS + 524288;          // 2048*256
  float* ATTF  = CTXS  + 524288;          // 2048*512
  float* DOUT  = ATTF  + 1048576;         // 2048*256
  float* DCAT  = DOUT  + 524288;          // 2048*768
  float* SC    = DCAT  + 1572864;         // 32*1024
  float* SCM   = SC    + 32768;           // 128
  float* ROWS  = SCM   + 128;             // 3*2048
  float* BODY  = ROWS  + 6144;            // 2*32*512
  float* CC    = BODY  + 32768;           // 32*256
  float* STATE = CC    + 8192;            // 32*256

  (void)hipMemsetAsync(ws + o_bar, 0, 256, stream);

  // ---------------- encoder recurrences (persistent cooperative) -----------
  rec_lstm<320,512,16,2,0,1><<<128,256,0,stream>>>(x, 327680L, 320L, l1_Wih, l1_Whh, l1_b,
      R0, 512, 0, hcur, 1024, 0, bar);
  rec_lstm<512,512,16,2,1,1><<<128,256,0,stream>>>(R0, 512L, 16384L, l2_Wih, l2_Whh, l2_b,
      R1, 512, 0, hcur, 1024, 0, bar);
  rec_lstm<512,512,16,2,1,1><<<128,256,0,stream>>>(R1, 512L, 16384L, l3_Wih, l3_Whh, l3_b,
      R2a, 512, 0, hcur, 1024, 0, bar);
  mask_bf16<<<8192,256,0,stream>>>(R2a, 512, xm);    // h3 *= m
  rec_lstm<512,512,16,2,1,1><<<128,256,0,stream>>>(R2a, 512L, 16384L, bf_Wih, bf_Whh, bf_b,
      R0, 512, 0, hcur, 1024, 0, bar);
  rec_lstm<512,512,16,2,1,1><<<128,256,0,stream>>>(R2a, 512L, 16384L, bb_Wih, bb_Whh, bb_b,
      R1, 512, 0, hcur, 1024, 1, bar);
  mask_bf16<<<8192,256,0,stream>>>(R0, 512, xm);     // bf *= m
  mask_bf16<<<8192,256,0,stream>>>(R1, 512, xm);     // bb *= m
  // conv1 (leaky) on concat [bf|bb], conv2, mask, att_h
  gemm_bias<1,1><<<dim3(256,4),256,0,stream>>>(R0, 512, R1, 512, 512,
      c1_W, c1_b, R2a, 32768, 512, 1024, 1024, 1);
  gemm_bias<1,1><<<dim3(256,2),256,0,stream>>>(R2a, 512, R2a, 512, 512,
      c2_W, c2_b, R2b, 32768, 256, 512, 512, 0);
  mask_bf16<<<4096,256,0,stream>>>(R2b, 256, xm);    // eout *= m
  gemm_bias<1,1><<<dim3(256,2),256,0,stream>>>(R2b, 256, R2b, 256, 256,
      w_W, w_b, R2c, 32768, 256, 256, 256, 0);

  // ---------------- decoder -------------------------------------------------
  embed_gather<<<2048,256,0,stream>>>(emb, y, EMBED);
  gemm_bias<0,0><<<dim3(16,8),256,0,stream>>>(EMBED, 256, EMBED, 256, 256,
      att_Wih, att_b, EPART, 2048, 1024, 256, 512, 0);
  zero_f<<<160,256,0,stream>>>(BODY, 40960); // body[2] + cc
  for (int s=0;s<64;++s){
    float* bodyR = BODY + (s&1)*16384;
    float* bodyW = BODY + ((s+1)&1)*16384;
    k1_dec<<<32,256,0,stream>>>(bodyR, bodyW, EPART, att_Whh, att_Wih, CC, LSTMS, s);
    k2_dec<<<8,256,0,stream>>>(bodyW, v_W, v_b, STATE);
    k3_dec<<<128,256,0,stream>>>(STATE, R2c, wav, xm, SC, SCM);
    k4_dec<<<32,256,0,stream>>>(SC, SCM, R2b, CTXS, bodyW, s);
  }
  attfea_k<<<1024,256,0,stream>>>(LSTMS, CTXS, ym, ATTF);
  rec_lstm<512,256,8,4,0,0><<<128,256,0,stream>>>(ATTF, 512L, 16384L, dec_Wih, dec_Whh, dec_b,
      DOUT, 256, 0, hcur, 64, 0, bar);
  dcat_k<<<1536,256,0,stream>>>(ATTF, DOUT, ym, DCAT);
  gemm_bias<0,0><<<dim3(16,34),256,0,stream>>>(DCAT, 768, DCAT, 768, 768,
      cls_W, cls_b, LOGIT, 2048, 4235, 768, 768, 0);
  loss_row<<<2048,256,0,stream>>>(LOGIT, y, ym, ROWS);
  loss_final<<<1,256,0,stream>>>(ROWS, (float*)d_out);
}

// Round 4
// 127878.516 us; speedup vs baseline: 2.1066x; 2.1066x over previous
//
#include <hip/hip_runtime.h>
#include <math.h>

#define DEV static __device__ __forceinline__
typedef unsigned short u16;
typedef unsigned int u32;

typedef __attribute__((ext_vector_type(8))) __bf16 bf16x8;
typedef __attribute__((ext_vector_type(4))) float f32x4;

DEV float sigm(float x){ return 1.0f/(1.0f+__expf(-x)); }
DEV float tanh_f(float x){ float e=__expf(2.0f*x); return 1.0f - 2.0f/(e+1.0f); }

DEV float b2f(u16 u){ union {u32 i; float f;} c; c.i = ((u32)u)<<16; return c.f; }
DEV u16 f2b(float f){ union {u32 i; float f;} c; c.f = f; u32 r = (c.i + 0x7FFFu + ((c.i>>16)&1u)) >> 16; return (u16)r; }

// ---------------- grid barrier (device-scope) -------------------------------
DEV void gridbar(unsigned* bar, unsigned nwg){
  __threadfence();
  __syncthreads();
  if (threadIdx.x==0){
    unsigned g = __hip_atomic_load(bar+1, __ATOMIC_RELAXED, __HIP_MEMORY_SCOPE_AGENT);
    unsigned a = __hip_atomic_fetch_add(bar, 1u, __ATOMIC_ACQ_REL, __HIP_MEMORY_SCOPE_AGENT);
    if (a == nwg-1u){
      __hip_atomic_store(bar, 0u, __ATOMIC_RELAXED, __HIP_MEMORY_SCOPE_AGENT);
      __hip_atomic_fetch_add(bar+1, 1u, __ATOMIC_RELEASE, __HIP_MEMORY_SCOPE_AGENT);
    } else {
      unsigned long long sp=0;
      while (__hip_atomic_load(bar+1, __ATOMIC_ACQUIRE, __HIP_MEMORY_SCOPE_AGENT)==g){
        if (++sp > 4000000000ull) break; // safety: garbage instead of hang
      }
    }
  }
  __syncthreads();
}

// ---------------- persistent MFMA LSTM layer --------------------------------
// Per step: gates[b, col] over cols = 4 gates x H units; WG owns 4 units
// (16 cols = one MFMA n-tile, col c -> weight row (c&3)*H + u0 + (c>>2)).
// 4 waves = 4 k-slices of KTOT=[x(512 padded)|h(H)]; weights live in VGPRs
// (bf16) across the whole sequence. V=[x_t|h] staged in LDS bf16, XOR-swizzled
// via pre-swizzled source offsets (write linear, read swizzled).
// xin rows: [t*32+b][512] bf16. hcur: [2][32][H] bf16.
template<int KXREAL, int H, int SL23, int OUTBF>
__global__ __launch_bounds__(256,1) void rec_mfma(
    const u16* __restrict__ xin,
    const float* __restrict__ Wih, const float* __restrict__ Whh,
    const float* __restrict__ bias,
    void* __restrict__ hseq,
    u16* __restrict__ hcur,
    int T, int rev, unsigned* __restrict__ bar, unsigned nwg)
{
  constexpr int KTOT = 512 + 2*SL23;
  constexpr int NF23 = SL23/32;
  __shared__ __align__(16) char Vs[32*KTOT*2];
  __shared__ float P[4*16*36];
  __shared__ float cst[128];
  __shared__ float biasl[16];
  const int t = threadIdx.x;
  const int wg = blockIdx.x;
  const int u0 = wg*4;
  const int w = t>>6, lane = t&63;
  const int c  = lane&15;       // B col / A row (mtile 0)
  const int lg = lane>>4;       // k subgroup 0..3
  const int r  = (c&3)*H + u0 + (c>>2);
  const int nf = (w<2) ? 8 : NF23;
  const int wkbase = (w<2) ? w*256 : 512 + (w-2)*SL23;
  // ---- one-time weight preload into registers (bf16) ----
  bf16x8 bw[8];
  #pragma unroll
  for (int f=0; f<8; ++f){
    union { bf16x8 v; u16 s[8]; } u;
    int k8 = wkbase + f*32 + lg*8;
    if (f < nf && k8 < 512 && k8 < KXREAL){
      const float* p = Wih + (long)r*KXREAL + k8;
      #pragma unroll
      for (int j=0;j<8;++j) u.s[j] = f2b(p[j]);
    } else if (f < nf && k8 >= 512){
      const float* p = Whh + (long)r*H + (k8-512);
      #pragma unroll
      for (int j=0;j<8;++j) u.s[j] = f2b(p[j]);
    } else {
      #pragma unroll
      for (int j=0;j<8;++j) u.s[j] = 0;
    }
    bw[f]=u.v;
  }
  if (t < 16) biasl[t] = bias[(t&3)*H + u0 + (t>>2)];
  if (t < 128) cst[t] = 0.f;
  if (t < 128){ int b=t&31, uu=t>>5; hcur[b*H + u0+uu] = 0; }
  gridbar(bar, nwg);
  // staging geometry (per wave slice, contiguous LDS region)
  const int rowB = (w<2) ? 512 : SL23*2;     // bytes per b-row in slice
  const int NI   = (w<2) ? 16  : SL23/16;    // 1KB-instr count (32*rowB/1024)
  const int lpr  = rowB/16;                  // lanes per row
  const int waveOff = (w<2) ? w*16384 : 32768 + (w-2)*SL23*64;
  const int sb   = lane/lpr;
  const int coff = (lane - sb*lpr)*16;
  const int rpi  = 64/lpr;
  for (int s=0; s<T; ++s){
    const int tt = rev ? (T-1-s) : s;
    // ---- stage own k-slice (pre-swizzled source, linear LDS slot) ----
    {
      const char* hbase = (const char*)(hcur + (s&1)*32*H);
      #pragma unroll
      for (int i=0; i<16; ++i){
        if (i >= NI) break;
        int b = i*rpi + sb;
        const char* src;
        if (w < 2) src = (const char*)(xin + ((long)tt*32 + b)*512 + w*256);
        else       src = hbase + b*(H*2) + (w-2)*SL23*2;
        int off = coff ^ ((b&7)<<4);
        *(uint4*)(Vs + waveOff + i*1024 + lane*16) = *(const uint4*)(src + off);
      }
    }
    // ---- MFMA over own k-slice ----
    f32x4 acc0 = {0.f,0.f,0.f,0.f}, acc1 = {0.f,0.f,0.f,0.f};
    {
      const int b1 = c + 16;
      #pragma unroll
      for (int f=0; f<8; ++f){
        if (f >= nf) break;
        int koff = f*64 + lg*16;
        union { bf16x8 v; uint4 q; } a0, a1;
        a0.q = *(const uint4*)(Vs + waveOff + c *rowB + (koff ^ ((c &7)<<4)));
        a1.q = *(const uint4*)(Vs + waveOff + b1*rowB + (koff ^ ((b1&7)<<4)));
        acc0 = __builtin_amdgcn_mfma_f32_16x16x32_bf16(a0.v, bw[f], acc0, 0,0,0);
        acc1 = __builtin_amdgcn_mfma_f32_16x16x32_bf16(a1.v, bw[f], acc1, 0,0,0);
      }
    }
    // ---- partials to LDS: P[(w*16+c)*36 + b], b = batch row ----
    {
      float* pp = &P[(w*16 + c)*36 + lg*4];
      *(f32x4*)pp      = acc0;
      *(f32x4*)(pp+16) = acc1;
    }
    __syncthreads();
    // ---- reduce 4 waves + pointwise (128 threads: b x 4 units) ----
    if (t < 128){
      int b = t&31, uu = t>>5;
      float g4[4];
      #pragma unroll
      for (int g=0; g<4; ++g){
        int cc = uu*4 + g;
        float sum = biasl[cc];
        #pragma unroll
        for (int ww=0; ww<4; ++ww) sum += P[(ww*16+cc)*36 + b];
        g4[g] = sum;
      }
      float c2 = sigm(g4[1])*cst[t] + sigm(g4[0])*tanh_f(g4[2]);
      float h2 = sigm(g4[3])*tanh_f(c2);
      cst[t] = c2;
      int ug = u0 + uu;
      hcur[((s&1)^1)*32*H + b*H + ug] = f2b(h2);
      long oi = ((long)tt*32 + b)*H + ug;
      if (OUTBF) ((u16*)hseq)[oi] = f2b(h2);
      else       ((float*)hseq)[oi] = h2;
    }
    gridbar(bar, nwg);
  }
}

// ---------------- x pre-convert: fp32 (B,1024,320) -> bf16 [t*32+b][512] ----
__global__ void cvt_x(const float* __restrict__ x, u16* __restrict__ xp){
  long id8 = ((long)blockIdx.x*256 + threadIdx.x)*8; // 16,777,216 total elems
  int rr = (int)(id8 >> 9); int k = (int)(id8 & 511);
  int tt = rr >> 5, b = rr & 31;
  union { uint4 q; u16 s[8]; } u;
  if (k < 320){
    const float* p = x + (long)b*327680 + (long)tt*320 + k;
    float4 v0 = *(const float4*)p, v1 = *(const float4*)(p+4);
    u.s[0]=f2b(v0.x); u.s[1]=f2b(v0.y); u.s[2]=f2b(v0.z); u.s[3]=f2b(v0.w);
    u.s[4]=f2b(v1.x); u.s[5]=f2b(v1.y); u.s[6]=f2b(v1.z); u.s[7]=f2b(v1.w);
  } else {
    #pragma unroll
    for (int j=0;j<8;++j) u.s[j]=0;
  }
  *(uint4*)(xp + id8) = u.q;
}

// ---------------- tiled GEMM: C = [A0|A1] . W^T + bias ---------------------
template<int ABF, int CBF>
__global__ __launch_bounds__(256,1) void gemm_bias(
  const void* __restrict__ A0, long lda0, const void* __restrict__ A1, long lda1, int K0,
  const float* __restrict__ W, const float* __restrict__ bias, void* __restrict__ C,
  int M, int N, int K, int ldw, int act)
{
  __shared__ __align__(16) float As[16*132];
  __shared__ __align__(16) float Bs[16*132];
  const int t = threadIdx.x;
  const int m0 = blockIdx.x*128, n0 = blockIdx.y*128;
  const int tx = t&15, ty = t>>4;
  float acc[8][8];
  for (int i=0;i<8;++i)
    for (int j=0;j<8;++j) acc[i][j]=0.f;
  const int row = t>>1, seg = t&1;
  for (int k0=0;k0<K;k0+=16){
    {
      const int kk = k0 + seg*8;
      const void* Ab; long lda; int kof;
      if (kk < K0){ Ab=A0; lda=lda0; kof=kk; } else { Ab=A1; lda=lda1; kof=kk-K0; }
      float v[8];
      if (ABF){
        const u16* ap = (const u16*)Ab + (long)(m0+row)*lda + kof;
        union { uint4 q; u16 s[8]; } u; u.q = *(const uint4*)ap;
        #pragma unroll
        for (int j=0;j<8;++j) v[j]=b2f(u.s[j]);
      } else {
        const float* ap = (const float*)Ab + (long)(m0+row)*lda + kof;
        float4 x0 = *(const float4*)(ap);
        float4 x1 = *(const float4*)(ap+4);
        v[0]=x0.x;v[1]=x0.y;v[2]=x0.z;v[3]=x0.w;v[4]=x1.x;v[5]=x1.y;v[6]=x1.z;v[7]=x1.w;
      }
      const int kb = seg*8;
      #pragma unroll
      for (int j=0;j<8;++j) As[(kb+j)*132+row]=v[j];
    }
    {
      const int n = n0 + row;
      float4 y0 = {0,0,0,0}, y1 = {0,0,0,0};
      if (n < N){
        const float* wp = W + (long)n*ldw + k0 + seg*8;
        y0 = *(const float4*)(wp); y1 = *(const float4*)(wp+4);
      }
      const int kb = seg*8;
      Bs[(kb+0)*132+row]=y0.x; Bs[(kb+1)*132+row]=y0.y; Bs[(kb+2)*132+row]=y0.z; Bs[(kb+3)*132+row]=y0.w;
      Bs[(kb+4)*132+row]=y1.x; Bs[(kb+5)*132+row]=y1.y; Bs[(kb+6)*132+row]=y1.z; Bs[(kb+7)*132+row]=y1.w;
    }
    __syncthreads();
    #pragma unroll
    for (int k=0;k<16;++k){
      const float* ap = &As[k*132 + ty*8];
      const float* bp = &Bs[k*132 + tx*8];
      float4 A0v=*(const float4*)(ap), A1v=*(const float4*)(ap+4);
      float4 B0v=*(const float4*)(bp), B1v=*(const float4*)(bp+4);
      float av[8]={A0v.x,A0v.y,A0v.z,A0v.w,A1v.x,A1v.y,A1v.z,A1v.w};
      float bv[8]={B0v.x,B0v.y,B0v.z,B0v.w,B1v.x,B1v.y,B1v.z,B1v.w};
      #pragma unroll
      for (int i=0;i<8;++i){
        #pragma unroll
        for (int j=0;j<8;++j) acc[i][j] += av[i]*bv[j];
      }
    }
    __syncthreads();
  }
  float bv[8];
  #pragma unroll
  for (int j=0;j<8;++j){ int n = n0+tx*8+j; bv[j] = (n<N)? bias[n] : 0.f; }
  const bool full = (n0+128 <= N);
  #pragma unroll
  for (int i=0;i<8;++i){
    const int m = m0 + ty*8 + i;
    float v[8];
    #pragma unroll
    for (int j=0;j<8;++j){
      float x = acc[i][j] + bv[j];
      if (act) x = (x > 0.f) ? x : 0.1f*x;
      v[j] = x;
    }
    if (CBF){
      u16* cp = (u16*)C + (long)m*N + n0 + tx*8;
      union { uint4 q; u16 s[8]; } u;
      #pragma unroll
      for (int j=0;j<8;++j) u.s[j]=f2b(v[j]);
      *(uint4*)cp = u.q;
    } else {
      float* cp = (float*)C + (long)m*N + n0 + tx*8;
      if (full){
        float4 s0 = {v[0],v[1],v[2],v[3]}, s1 = {v[4],v[5],v[6],v[7]};
        *(float4*)(cp) = s0; *(float4*)(cp+4) = s1;
      } else {
        #pragma unroll
        for (int j=0;j<8;++j) if (n0+tx*8+j < N) cp[j] = v[j];
      }
    }
  }
}

// ---------------- elementwise helpers --------------------------------------
__global__ void mask_bf16(u16* __restrict__ buf, int F, const float* __restrict__ xm){
  long id8 = ((long)blockIdx.x*256 + threadIdx.x)*8;
  int row = (int)(id8 / F);
  int tt = row>>5, b = row&31;
  float m = xm[b*4096 + 4*tt];
  union { uint4 q; u16 s[8]; } u;
  u.q = *(uint4*)(buf + id8);
  #pragma unroll
  for (int j=0;j<8;++j) u.s[j] = f2b(b2f(u.s[j])*m);
  *(uint4*)(buf + id8) = u.q;
}

__global__ void embed_gather(const float* __restrict__ emb, const int* __restrict__ y,
                             float* __restrict__ out){
  int id = blockIdx.x*256 + threadIdx.x; // 2048*256
  int p = id&255, r = id>>8;
  int l = r>>5, b = r&31;
  out[id] = emb[(long)y[b*65 + l]*256 + p];
}

__global__ void zero_f(float* __restrict__ p, int n){
  int id = blockIdx.x*256 + threadIdx.x;
  if (id < n) p[id] = 0.f;
}

__global__ void set_val(float* p, float v){ p[0] = v; }

__global__ void attfea_k(const float* __restrict__ lstms, const float* __restrict__ ctxs,
                         const float* __restrict__ ym, float* __restrict__ attf,
                         u16* __restrict__ attfb){
  long id4 = ((long)blockIdx.x*256 + threadIdx.x)*4; // 2048*512
  int r = (int)(id4>>9); int f = (int)(id4&511);
  int l = r>>5, b = r&31;
  float m = ym[b*65 + l + 1];
  float4 v = (f<256) ? *(const float4*)(lstms + (long)r*256 + f)
                     : *(const float4*)(ctxs  + (long)r*256 + (f-256));
  v.x*=m; v.y*=m; v.z*=m; v.w*=m;
  *(float4*)(attf + id4) = v;
  u16* ob = attfb + id4;
  ob[0]=f2b(v.x); ob[1]=f2b(v.y); ob[2]=f2b(v.z); ob[3]=f2b(v.w);
}

__global__ void dcat_k(const float* __restrict__ attf, const float* __restrict__ dout,
                       const float* __restrict__ ym, float* __restrict__ dcat){
  long id4 = ((long)blockIdx.x*256 + threadIdx.x)*4; // 2048*768
  int r = (int)(id4/768); int f = (int)(id4 - (long)r*768);
  int l = r>>5, b = r&31;
  float m = ym[b*65 + l + 1];
  float4 v = (f<512) ? *(const float4*)(attf + (long)r*512 + f)
                     : *(const float4*)(dout + (long)r*256 + (f-512));
  v.x*=m; v.y*=m; v.z*=m; v.w*=m;
  *(float4*)(dcat + id4) = v;
}

// ---------------- decoder attention step kernels ----------------------------
__global__ __launch_bounds__(256,1) void k1_dec(
  const float* __restrict__ bodyR, float* __restrict__ bodyW,
  const float* __restrict__ epart, const float* __restrict__ Whh,
  const float* __restrict__ Wih, float* __restrict__ cc,
  float* __restrict__ lstms, int s)
{
  __shared__ __align__(16) float vT[512*36];
  __shared__ float gl[32*32];
  const int t = threadIdx.x, wg = blockIdx.x; // 32 WGs
  for (int i = t*4; i < 32*512; i += 1024){
    int b = i>>9, k = i&511;
    float4 v = *(const float4*)(bodyR + b*512 + k);
    vT[(k+0)*36+b]=v.x; vT[(k+1)*36+b]=v.y; vT[(k+2)*36+b]=v.z; vT[(k+3)*36+b]=v.w;
  }
  __syncthreads();
  const int c_l = t>>3, bq = t&7;
  const int col = (c_l&3)*256 + wg*8 + (c_l>>2);
  float a0=0.f,a1=0.f,a2=0.f,a3=0.f;
  for (int k=0;k<256;k+=4){
    float4 w = *(const float4*)(Whh + (long)col*256 + k);
    const float* vp = &vT[k*36 + bq*4];
    float4 v0=*(const float4*)(vp), v1=*(const float4*)(vp+36), v2=*(const float4*)(vp+72), v3=*(const float4*)(vp+108);
    a0 += w.x*v0.x + w.y*v1.x + w.z*v2.x + w.w*v3.x;
    a1 += w.x*v0.y + w.y*v1.y + w.z*v2.y + w.w*v3.y;
    a2 += w.x*v0.z + w.y*v1.z + w.z*v2.z + w.w*v3.z;
    a3 += w.x*v0.w + w.y*v1.w + w.z*v2.w + w.w*v3.w;
  }
  for (int k=256;k<512;k+=4){
    float4 w = *(const float4*)(Wih + (long)col*512 + k);
    const float* vp = &vT[k*36 + bq*4];
    float4 v0=*(const float4*)(vp), v1=*(const float4*)(vp+36), v2=*(const float4*)(vp+72), v3=*(const float4*)(vp+108);
    a0 += w.x*v0.x + w.y*v1.x + w.z*v2.x + w.w*v3.x;
    a1 += w.x*v0.y + w.y*v1.y + w.z*v2.y + w.w*v3.y;
    a2 += w.x*v0.z + w.y*v1.z + w.z*v2.z + w.w*v3.z;
    a3 += w.x*v0.w + w.y*v1.w + w.z*v2.w + w.w*v3.w;
  }
  gl[c_l*32+bq*4+0] = a0 + epart[((long)s*32 + bq*4+0)*1024 + col];
  gl[c_l*32+bq*4+1] = a1 + epart[((long)s*32 + bq*4+1)*1024 + col];
  gl[c_l*32+bq*4+2] = a2 + epart[((long)s*32 + bq*4+2)*1024 + col];
  gl[c_l*32+bq*4+3] = a3 + epart[((long)s*32 + bq*4+3)*1024 + col];
  __syncthreads();
  {
    const int u_ = t>>5, b = t&31, ug = wg*8 + u_;
    const float gi=gl[(u_*4+0)*32+b], gf=gl[(u_*4+1)*32+b], gg=gl[(u_*4+2)*32+b], go=gl[(u_*4+3)*32+b];
    float c0 = cc[b*256+ug];
    float c2 = sigm(gf)*c0 + sigm(gi)*tanh_f(gg);
    float h2 = sigm(go)*tanh_f(c2);
    cc[b*256+ug] = c2;
    bodyW[b*512 + ug] = h2;
    lstms[((long)s*32 + b)*256 + ug] = h2;
  }
}

__global__ __launch_bounds__(256,1) void k2_dec(
  const float* __restrict__ bodyW, const float* __restrict__ vW,
  const float* __restrict__ vb, float* __restrict__ state)
{
  __shared__ __align__(16) float hT[256*36];
  const int t = threadIdx.x, wg = blockIdx.x;
  for (int i = t*4; i < 8192; i += 1024){
    int b = i>>8, k = i&255;
    float4 v = *(const float4*)(bodyW + b*512 + k);
    hT[(k+0)*36+b]=v.x; hT[(k+1)*36+b]=v.y; hT[(k+2)*36+b]=v.z; hT[(k+3)*36+b]=v.w;
  }
  __syncthreads();
  const int p = wg*32 + (t>>3), bq = t&7;
  float a0=0.f,a1=0.f,a2=0.f,a3=0.f;
  for (int k=0;k<256;k+=4){
    float4 w = *(const float4*)(vW + (long)p*256 + k);
    const float* vp = &hT[k*36 + bq*4];
    float4 v0=*(const float4*)(vp), v1=*(const float4*)(vp+36), v2=*(const float4*)(vp+72), v3=*(const float4*)(vp+108);
    a0 += w.x*v0.x + w.y*v1.x + w.z*v2.x + w.w*v3.x;
    a1 += w.x*v0.y + w.y*v1.y + w.z*v2.y + w.w*v3.y;
    a2 += w.x*v0.z + w.y*v1.z + w.z*v2.z + w.w*v3.z;
    a3 += w.x*v0.w + w.y*v1.w + w.z*v2.w + w.w*v3.w;
  }
  float bb = vb[p];
  state[(bq*4+0)*256 + p] = a0 + bb;
  state[(bq*4+1)*256 + p] = a1 + bb;
  state[(bq*4+2)*256 + p] = a2 + bb;
  state[(bq*4+3)*256 + p] = a3 + bb;
}

__global__ __launch_bounds__(256,1) void k3_dec(
  const float* __restrict__ state, const u16* __restrict__ atth,
  const float* __restrict__ wav, const float* __restrict__ xm,
  float* __restrict__ sc, float* __restrict__ scm)
{
  __shared__ float st[256], wv[256], red[256];
  const int t = threadIdx.x;
  const int b = blockIdx.x>>2, ch = blockIdx.x&3;
  st[t] = state[b*256 + t];
  wv[t] = wav[t];
  __syncthreads();
  const int tp = ch*256 + t;
  const u16* ap = atth + ((long)tp*32 + b)*256;
  float acc = 0.f;
  for (int p=0;p<256;p+=4){
    ushort4 a = *(const ushort4*)(ap+p);
    acc += wv[p+0]*tanh_f(st[p+0]+b2f(a.x));
    acc += wv[p+1]*tanh_f(st[p+1]+b2f(a.y));
    acc += wv[p+2]*tanh_f(st[p+2]+b2f(a.z));
    acc += wv[p+3]*tanh_f(st[p+3]+b2f(a.w));
  }
  acc += (xm[b*4096 + 4*tp] - 1.0f)*1e30f;
  sc[b*1024 + tp] = acc;
  red[t] = acc;
  __syncthreads();
  for (int o=128;o>0;o>>=1){ if (t<o) red[t]=fmaxf(red[t],red[t+o]); __syncthreads(); }
  if (t==0) scm[b*4+ch] = red[0];
}

__global__ __launch_bounds__(256,1) void k4_dec(
  const float* __restrict__ sc, const float* __restrict__ scm,
  const u16* __restrict__ eout, float* __restrict__ ctxs,
  float* __restrict__ bodyW, int s)
{
  __shared__ float al[1024];
  __shared__ float red[256];
  const int t = threadIdx.x, b = blockIdx.x;
  float m = fmaxf(fmaxf(scm[b*4+0],scm[b*4+1]), fmaxf(scm[b*4+2],scm[b*4+3]));
  float ps = 0.f;
  #pragma unroll
  for (int j=0;j<4;++j){
    int tp = t + j*256;
    float e = __expf(sc[b*1024+tp] - m);
    al[tp] = e; ps += e;
  }
  red[t]=ps; __syncthreads();
  for (int o=128;o>0;o>>=1){ if (t<o) red[t]+=red[t+o]; __syncthreads(); }
  float rinv = 1.0f/red[0];
  float acc = 0.f;
  const u16* ep = eout + b*256 + t;
  for (int tp=0;tp<1024;++tp) acc += al[tp] * b2f(ep[(long)tp*8192]);
  float cv = acc*rinv;
  ctxs[((long)s*32 + b)*256 + t] = cv;
  bodyW[b*512 + 256 + t] = cv;
}

// ---------------- loss ------------------------------------------------------
__global__ __launch_bounds__(256,1) void loss_row(
  const float* __restrict__ logits, const int* __restrict__ y,
  const float* __restrict__ ym, float* __restrict__ rows)
{
  __shared__ float red[256];
  const int r = blockIdx.x, t = threadIdx.x;
  const float* row = logits + (long)r*4235;
  float mx = -3.0e38f;
  for (int i=t;i<4235;i+=256) mx = fmaxf(mx, row[i]);
  red[t]=mx; __syncthreads();
  for (int o=128;o>0;o>>=1){ if (t<o) red[t]=fmaxf(red[t],red[t+o]); __syncthreads(); }
  const float M = red[0];
  __syncthreads();
  float se=0.f, sl=0.f;
  for (int i=t;i<4235;i+=256){ float v=row[i]; se += __expf(v-M); sl += v; }
  red[t]=se; __syncthreads();
  for (int o=128;o>0;o>>=1){ if (t<o) red[t]+=red[t+o]; __syncthreads(); }
  const float SE = red[0];
  __syncthreads();
  red[t]=sl; __syncthreads();
  for (int o=128;o>0;o>>=1){ if (t<o) red[t]+=red[t+o]; __syncthreads(); }
  const float SL = red[0];
  if (t==0){
    const int tt = r>>5, b = r&31;
    const float lse = M + logf(SE);
    const float mk = (ym[b*65 + tt + 1] > 0.f) ? 1.f : 0.f;
    rows[r]        = (4235.0f*lse - SL)*mk;
    rows[2048 + r] = (lse - row[y[b*65 + tt + 1]])*mk;
    rows[4096 + r] = mk;
  }
}

__global__ __launch_bounds__(256,1) void loss_final(const float* __restrict__ rows, float* __restrict__ out){
  __shared__ float red[256];
  const int t = threadIdx.x;
  float s1=0.f,s2=0.f,s3=0.f;
  for (int i=t;i<2048;i+=256){ s1+=rows[i]; s2+=rows[2048+i]; s3+=rows[4096+i]; }
  red[t]=s1; __syncthreads();
  for (int o=128;o>0;o>>=1){ if (t<o) red[t]+=red[t+o]; __syncthreads(); }
  const float S = red[0]; __syncthreads();
  red[t]=s2; __syncthreads();
  for (int o=128;o>0;o>>=1){ if (t<o) red[t]+=red[t+o]; __syncthreads(); }
  const float NL = red[0]; __syncthreads();
  red[t]=s3; __syncthreads();
  for (int o=128;o>0;o>>=1){ if (t<o) red[t]+=red[t+o]; __syncthreads(); }
  const float N = red[0];
  if (t==0){
    float n = (N > 0.f) ? N : 1.f;
    out[0] = (S/n)*(0.1f/4235.0f) + 0.9f*(NL/n);
  }
}

// ---------------- launcher --------------------------------------------------
extern "C" void kernel_launch(void* const* d_in, const int* in_sizes, int n_in,
                              void* d_out, int out_size, void* d_ws, size_t ws_size,
                              hipStream_t stream)
{
  const float* x    = (const float*)d_in[0];
  const float* xm   = (const float*)d_in[1];
  const int*   y    = (const int*)  d_in[2];
  const float* ym   = (const float*)d_in[3];
  const float* l1_Wih=(const float*)d_in[4];  const float* l1_Whh=(const float*)d_in[5];  const float* l1_b=(const float*)d_in[6];
  const float* l2_Wih=(const float*)d_in[7];  const float* l2_Whh=(const float*)d_in[8];  const float* l2_b=(const float*)d_in[9];
  const float* l3_Wih=(const float*)d_in[10]; const float* l3_Whh=(const float*)d_in[11]; const float* l3_b=(const float*)d_in[12];
  const float* bf_Wih=(const float*)d_in[13]; const float* bf_Whh=(const float*)d_in[14]; const float* bf_b=(const float*)d_in[15];
  const float* bb_Wih=(const float*)d_in[16]; const float* bb_Whh=(const float*)d_in[17]; const float* bb_b=(const float*)d_in[18];
  const float* c1_W=(const float*)d_in[19]; const float* c1_b=(const float*)d_in[20];
  const float* c2_W=(const float*)d_in[21]; const float* c2_b=(const float*)d_in[22];
  const float* emb =(const float*)d_in[23];
  const float* att_Wih=(const float*)d_in[24]; const float* att_Whh=(const float*)d_in[25]; const float* att_b=(const float*)d_in[26];
  const float* w_W=(const float*)d_in[27]; const float* w_b=(const float*)d_in[28];
  const float* v_W=(const float*)d_in[29]; const float* v_b=(const float*)d_in[30];
  const float* wav=(const float*)d_in[31];
  const float* dec_Wih=(const float*)d_in[32]; const float* dec_Whh=(const float*)d_in[33]; const float* dec_b=(const float*)d_in[34];
  const float* cls_W=(const float*)d_in[35]; const float* cls_b=(const float*)d_in[36];

  // workspace layout (bytes) — same footprint as R3 (131.3 MiB, verified fit)
  const size_t o_bar  = 0;
  const size_t o_hcur = 256;                      // hcur bf16 2x32x512 = 64KB
  const size_t o_r0   = 262144;                   // 32 MiB
  const size_t o_r1   = o_r0 + 33554432ull;       // 35 MiB
  const size_t o_r2   = o_r1 + 36700160ull;       // 64 MiB
  const size_t REQ    = o_r2 + 67108864ull;
  if (ws_size < REQ){
    set_val<<<1,1,0,stream>>>((float*)d_out, -(float)(ws_size>>20));
    return;
  }
  char* ws = (char*)d_ws;
  unsigned* bar = (unsigned*)(ws + o_bar);
  u16* hcur = (u16*)(ws + o_hcur);
  u16* R0  = (u16*)(ws + o_r0);
  u16* R1  = (u16*)(ws + o_r1);
  u16* R2a = (u16*)(ws + o_r2);           // xpad (32MiB), later h3 / conv1-out
  u16* R2b = R2a + 16777216;              // eout bf16
  u16* R2c = R2b + 8388608;               // att_h bf16
  float* LOGIT = (float*)(ws + o_r1);     // 2048x4235 fp32 (after bb consumed)
  float* AR    = (float*)(ws + o_r0);     // decoder arena (after bf consumed)
  float* EMBED = AR;                      // 2048*256
  float* EPART = EMBED + 524288;          // 2048*1024
  float* LSTMS = EPART + 2097152;         // 2048*256
  float* CTXS  = LSTMS + 524288;          // 2048*256
  float* ATTF  = CTXS  + 524288;          // 2048*512
  float* DOUT  = ATTF  + 1048576;         // 2048*256
  float* DCAT  = DOUT  + 524288;          // 2048*768
  float* SC    = DCAT  + 1572864;         // 32*1024
  float* SCM   = SC    + 32768;           // 128
  float* ROWS  = SCM   + 128;             // 3*2048
  float* BODY  = ROWS  + 6144;            // 2*32*512
  float* CC    = BODY  + 32768;           // 32*256
  float* STATE = CC    + 8192;            // 32*256
  u16*  ATTFB  = (u16*)(STATE + 8192);    // 2048*512 bf16

  (void)hipMemsetAsync(ws + o_bar, 0, 256, stream);

  // ---------------- encoder recurrences (persistent MFMA) -------------------
  cvt_x<<<8192,256,0,stream>>>(x, R2a);
  rec_mfma<320,512,256,1><<<128,256,0,stream>>>(R2a, l1_Wih, l1_Whh, l1_b,
      R0, hcur, 1024, 0, bar, 128);
  rec_mfma<512,512,256,1><<<128,256,0,stream>>>(R0, l2_Wih, l2_Whh, l2_b,
      R1, hcur, 1024, 0, bar, 128);
  rec_mfma<512,512,256,1><<<128,256,0,stream>>>(R1, l3_Wih, l3_Whh, l3_b,
      R2a, hcur, 1024, 0, bar, 128);
  mask_bf16<<<8192,256,0,stream>>>(R2a, 512, xm);    // h3 *= m
  rec_mfma<512,512,256,1><<<128,256,0,stream>>>(R2a, bf_Wih, bf_Whh, bf_b,
      R0, hcur, 1024, 0, bar, 128);
  rec_mfma<512,512,256,1><<<128,256,0,stream>>>(R2a, bb_Wih, bb_Whh, bb_b,
      R1, hcur, 1024, 1, bar, 128);
  mask_bf16<<<8192,256,0,stream>>>(R0, 512, xm);     // bf *= m
  mask_bf16<<<8192,256,0,stream>>>(R1, 512, xm);     // bb *= m
  // conv1 (leaky) on concat [bf|bb], conv2, mask, att_h
  gemm_bias<1,1><<<dim3(256,4),256,0,stream>>>(R0, 512, R1, 512, 512,
      c1_W, c1_b, R2a, 32768, 512, 1024, 1024, 1);
  gemm_bias<1,1><<<dim3(256,2),256,0,stream>>>(R2a, 512, R2a, 512, 512,
      c2_W, c2_b, R2b, 32768, 256, 512, 512, 0);
  mask_bf16<<<4096,256,0,stream>>>(R2b, 256, xm);    // eout *= m
  gemm_bias<1,1><<<dim3(256,2),256,0,stream>>>(R2b, 256, R2b, 256, 256,
      w_W, w_b, R2c, 32768, 256, 256, 256, 0);

  // ---------------- decoder -------------------------------------------------
  embed_gather<<<2048,256,0,stream>>>(emb, y, EMBED);
  gemm_bias<0,0><<<dim3(16,8),256,0,stream>>>(EMBED, 256, EMBED, 256, 256,
      att_Wih, att_b, EPART, 2048, 1024, 256, 512, 0);
  zero_f<<<160,256,0,stream>>>(BODY, 40960); // body[2] + cc
  for (int s=0;s<64;++s){
    float* bodyR = BODY + (s&1)*16384;
    float* bodyW = BODY + ((s+1)&1)*16384;
    k1_dec<<<32,256,0,stream>>>(bodyR, bodyW, EPART, att_Whh, att_Wih, CC, LSTMS, s);
    k2_dec<<<8,256,0,stream>>>(bodyW, v_W, v_b, STATE);
    k3_dec<<<128,256,0,stream>>>(STATE, R2c, wav, xm, SC, SCM);
    k4_dec<<<32,256,0,stream>>>(SC, SCM, R2b, CTXS, bodyW, s);
  }
  attfea_k<<<1024,256,0,stream>>>(LSTMS, CTXS, ym, ATTF, ATTFB);
  rec_mfma<512,256,128,0><<<64,256,0,stream>>>(ATTFB, dec_Wih, dec_Whh, dec_b,
      DOUT, hcur, 64, 0, bar, 64);
  dcat_k<<<1536,256,0,stream>>>(ATTF, DOUT, ym, DCAT);
  gemm_bias<0,0><<<dim3(16,34),256,0,stream>>>(DCAT, 768, DCAT, 768, 768,
      cls_W, cls_b, LOGIT, 2048, 4235, 768, 768, 0);
  loss_row<<<2048,256,0,stream>>>(LOGIT, y, ym, ROWS);
  loss_final<<<1,256,0,stream>>>(ROWS, (float*)d_out);
}

// Round 5
// 52981.256 us; speedup vs baseline: 5.0845x; 2.4137x over previous
//
#include <hip/hip_runtime.h>
#include <math.h>

#define DEV static __device__ __forceinline__
typedef unsigned short u16;
typedef unsigned int u32;

typedef __attribute__((ext_vector_type(8))) __bf16 bf16x8;
typedef __attribute__((ext_vector_type(4))) float f32x4;

DEV float sigm(float x){ return 1.0f/(1.0f+__expf(-x)); }
DEV float tanh_f(float x){ float e=__expf(2.0f*x); return 1.0f - 2.0f/(e+1.0f); }

DEV float b2f(u16 u){ union {u32 i; float f;} c; c.i = ((u32)u)<<16; return c.f; }
DEV u16 f2b(float f){ union {u32 i; float f;} c; c.f = f; u32 r = (c.i + 0x7FFFu + ((c.i>>16)&1u)) >> 16; return (u16)r; }

// ---------------- grid barrier v2: per-WG flags + master aggregation --------
// No shared RMW: each WG release-stores its own monotone flag; WG0 wave 0
// polls flags RELAXED (no per-poll L2 inv), then release-stores gen; all WGs
// poll gen RELAXED and acquire once on exit.
DEV void gridbar2(unsigned* flags, unsigned* gen, unsigned target, int nwg){
  __syncthreads();
  const int t = threadIdx.x;
  if (t==0){
    __threadfence();
    __hip_atomic_store(&flags[blockIdx.x], target, __ATOMIC_RELEASE, __HIP_MEMORY_SCOPE_AGENT);
  }
  if (blockIdx.x==0 && t<64){
    for(;;){
      bool ok = true;
      for (int j=t; j<nwg; j+=64)
        ok &= ((int)(__hip_atomic_load(&flags[j], __ATOMIC_RELAXED, __HIP_MEMORY_SCOPE_AGENT) - target) >= 0);
      if (__all(ok)) break;
      __builtin_amdgcn_s_sleep(2);
    }
    if (t==0)
      __hip_atomic_store(gen, target, __ATOMIC_RELEASE, __HIP_MEMORY_SCOPE_AGENT);
  }
  if (t==0){
    while ((int)(__hip_atomic_load(gen, __ATOMIC_RELAXED, __HIP_MEMORY_SCOPE_AGENT) - target) < 0)
      __builtin_amdgcn_s_sleep(2);
    (void)__hip_atomic_load(gen, __ATOMIC_ACQUIRE, __HIP_MEMORY_SCOPE_AGENT);
  }
  __syncthreads();
}

// ---------------- pipelined persistent MFMA LSTM (encoder, H=512) ----------
// NL layers advance on a time diagonal: layer l processes t = s - l.
// WG owns 4 hidden units of every layer; weights register-resident.
struct PipeL {
  const float *Wih, *Whh, *bias;
  const u16* in; u16* out; u16* hcur;
  int kx, maskout, inring, outring;
};
struct PipeArgs {
  PipeL L[4];
  const float* xm;
  int T;
  unsigned* flags; unsigned* gen; unsigned base; int nwg; int rev;
};

template<int NL>
__global__ __launch_bounds__(256,1) void pipe_lstm(PipeArgs A){
  __shared__ __align__(16) char Vs[65536];
  __shared__ float P[4*64*36];
  __shared__ float cst[4*128];
  __shared__ float biasl[4*16];
  const int t = threadIdx.x, wg = blockIdx.x;
  const int u0 = wg*4;
  const int w = t>>6, lane = t&63;
  const int c = lane&15, lg = lane>>4;
  const int r = (c&3)*512 + u0 + (c>>2);
  // ---- one-time weight preload (bf16, 32 VGPRs per layer per wave) ----
  bf16x8 bw[NL][8];
  #pragma unroll
  for (int l=0;l<NL;++l){
    const int kx = A.L[l].kx;
    #pragma unroll
    for (int f=0;f<8;++f){
      union { bf16x8 v; u16 s[8]; } u;
      int k8 = w*256 + f*32 + lg*8;
      if (k8 < 512){
        if (k8 < kx){
          const float* p = A.L[l].Wih + (long)r*kx + k8;
          for (int j=0;j<8;++j) u.s[j]=f2b(p[j]);
        } else { for (int j=0;j<8;++j) u.s[j]=0; }
      } else {
        const float* p = A.L[l].Whh + (long)r*512 + (k8-512);
        for (int j=0;j<8;++j) u.s[j]=f2b(p[j]);
      }
      bw[l][f]=u.v;
    }
  }
  if (t<16){
    #pragma unroll
    for (int l=0;l<NL;++l) biasl[l*16+t] = A.L[l].bias[(t&3)*512 + u0 + (t>>2)];
  }
  if (t<128){
    #pragma unroll
    for (int l=0;l<NL;++l) cst[l*128+t]=0.f;
  }
  #pragma unroll
  for (int l=0;l<NL;++l)
    for (int i=wg*256+t; i<32*512; i+=A.nwg*256) A.L[l].hcur[i]=0;
  gridbar2(A.flags, A.gen, A.base+1, A.nwg);
  const int sb = lane>>5;          // row-within-pair
  const int coff = (lane&31)*16;   // byte col within 512B row slice
  const int waveOff = w*16384;
  const int T = A.T;
  for (int s=0; s<T+NL-1; ++s){
    #pragma unroll
    for (int l=0;l<NL;++l){
      const int sc = s-l;
      if (sc < 0 || sc >= T) continue;
      const int tt = A.rev ? (T-1-sc) : sc;
      // ---- stage own k-slice (write linear, source pre-swizzled) ----
      #pragma unroll
      for (int i=0;i<16;++i){
        int b = i*2 + sb;
        const char* src;
        if (w<2){
          long row = A.L[l].inring ? (long)((tt&7)*32 + b) : ((long)tt*32 + b);
          src = (const char*)(A.L[l].in + row*512 + w*256);
        } else {
          src = (const char*)(A.L[l].hcur + (sc&1)*32*512 + b*512 + (w-2)*256);
        }
        int off = coff ^ ((b&7)<<4);
        *(uint4*)(Vs + waveOff + i*1024 + lane*16) = *(const uint4*)(src + off);
      }
      // ---- MFMA over own k-slice ----
      f32x4 acc0={0.f,0.f,0.f,0.f}, acc1={0.f,0.f,0.f,0.f};
      const int b1 = c+16;
      #pragma unroll
      for (int f=0;f<8;++f){
        int koff = f*64 + lg*16;
        union { bf16x8 v; uint4 q; } a0, a1;
        a0.q = *(const uint4*)(Vs + waveOff + c *512 + (koff ^ ((c &7)<<4)));
        a1.q = *(const uint4*)(Vs + waveOff + b1*512 + (koff ^ ((b1&7)<<4)));
        acc0 = __builtin_amdgcn_mfma_f32_16x16x32_bf16(a0.v, bw[l][f], acc0, 0,0,0);
        acc1 = __builtin_amdgcn_mfma_f32_16x16x32_bf16(a1.v, bw[l][f], acc1, 0,0,0);
      }
      float* pp = &P[l*2304 + (w*16+c)*36 + lg*4];
      *(f32x4*)pp      = acc0;
      *(f32x4*)(pp+16) = acc1;
    }
    __syncthreads();
    if (t<128){
      int b=t&31, uu=t>>5;
      #pragma unroll
      for (int l=0;l<NL;++l){
        const int sc = s-l;
        if (sc<0 || sc>=T) continue;
        const int tt = A.rev ? (T-1-sc) : sc;
        float g4[4];
        #pragma unroll
        for (int g=0; g<4; ++g){
          int cc = uu*4+g;
          float sum = biasl[l*16+cc];
          #pragma unroll
          for (int ww=0; ww<4; ++ww) sum += P[l*2304 + (ww*16+cc)*36 + b];
          g4[g]=sum;
        }
        float c2 = sigm(g4[1])*cst[l*128+t] + sigm(g4[0])*tanh_f(g4[2]);
        float h2 = sigm(g4[3])*tanh_f(c2);
        cst[l*128+t]=c2;
        int ug = u0+uu;
        A.L[l].hcur[((sc&1)^1)*32*512 + b*512 + ug] = f2b(h2);
        float ov = h2;
        if (A.L[l].maskout) ov *= A.xm[b*4096 + 4*tt];
        long row = A.L[l].outring ? (long)((tt&7)*32 + b) : ((long)tt*32 + b);
        A.L[l].out[row*512 + ug] = f2b(ov);
      }
    }
    gridbar2(A.flags, A.gen, A.base+2+s, A.nwg);
  }
}

// ---------------- persistent MFMA LSTM (single layer; used for decoder) -----
template<int KXREAL, int H, int SL23, int OUTBF>
__global__ __launch_bounds__(256,1) void rec_mfma(
    const u16* __restrict__ xin,
    const float* __restrict__ Wih, const float* __restrict__ Whh,
    const float* __restrict__ bias,
    void* __restrict__ hseq,
    u16* __restrict__ hcur,
    int T, int rev, unsigned* flags, unsigned* gen, unsigned base, int nwg)
{
  constexpr int KTOT = 512 + 2*SL23;
  constexpr int NF23 = SL23/32;
  __shared__ __align__(16) char Vs[32*KTOT*2];
  __shared__ float P[4*16*36];
  __shared__ float cst[128];
  __shared__ float biasl[16];
  const int t = threadIdx.x;
  const int wg = blockIdx.x;
  const int u0 = wg*4;
  const int w = t>>6, lane = t&63;
  const int c  = lane&15;
  const int lg = lane>>4;
  const int r  = (c&3)*H + u0 + (c>>2);
  const int nf = (w<2) ? 8 : NF23;
  const int wkbase = (w<2) ? w*256 : 512 + (w-2)*SL23;
  bf16x8 bw[8];
  #pragma unroll
  for (int f=0; f<8; ++f){
    union { bf16x8 v; u16 s[8]; } u;
    int k8 = wkbase + f*32 + lg*8;
    if (f < nf && k8 < 512 && k8 < KXREAL){
      const float* p = Wih + (long)r*KXREAL + k8;
      for (int j=0;j<8;++j) u.s[j] = f2b(p[j]);
    } else if (f < nf && k8 >= 512){
      const float* p = Whh + (long)r*H + (k8-512);
      for (int j=0;j<8;++j) u.s[j] = f2b(p[j]);
    } else {
      for (int j=0;j<8;++j) u.s[j] = 0;
    }
    bw[f]=u.v;
  }
  if (t < 16) biasl[t] = bias[(t&3)*H + u0 + (t>>2)];
  if (t < 128) cst[t] = 0.f;
  if (t < 128){ int b=t&31, uu=t>>5; hcur[b*H + u0+uu] = 0; }
  gridbar2(flags, gen, base+1, nwg);
  const int rowB = (w<2) ? 512 : SL23*2;
  const int NI   = (w<2) ? 16  : SL23/16;
  const int lpr  = rowB/16;
  const int waveOff = (w<2) ? w*16384 : 32768 + (w-2)*SL23*64;
  const int sb   = lane/lpr;
  const int coff = (lane - sb*lpr)*16;
  const int rpi  = 64/lpr;
  for (int s=0; s<T; ++s){
    const int tt = rev ? (T-1-s) : s;
    {
      const char* hbase = (const char*)(hcur + (s&1)*32*H);
      #pragma unroll
      for (int i=0; i<16; ++i){
        if (i >= NI) break;
        int b = i*rpi + sb;
        const char* src;
        if (w < 2) src = (const char*)(xin + ((long)tt*32 + b)*512 + w*256);
        else       src = hbase + b*(H*2) + (w-2)*SL23*2;
        int off = coff ^ ((b&7)<<4);
        *(uint4*)(Vs + waveOff + i*1024 + lane*16) = *(const uint4*)(src + off);
      }
    }
    f32x4 acc0 = {0.f,0.f,0.f,0.f}, acc1 = {0.f,0.f,0.f,0.f};
    {
      const int b1 = c + 16;
      #pragma unroll
      for (int f=0; f<8; ++f){
        if (f >= nf) break;
        int koff = f*64 + lg*16;
        union { bf16x8 v; uint4 q; } a0, a1;
        a0.q = *(const uint4*)(Vs + waveOff + c *rowB + (koff ^ ((c &7)<<4)));
        a1.q = *(const uint4*)(Vs + waveOff + b1*rowB + (koff ^ ((b1&7)<<4)));
        acc0 = __builtin_amdgcn_mfma_f32_16x16x32_bf16(a0.v, bw[f], acc0, 0,0,0);
        acc1 = __builtin_amdgcn_mfma_f32_16x16x32_bf16(a1.v, bw[f], acc1, 0,0,0);
      }
    }
    {
      float* pp = &P[(w*16 + c)*36 + lg*4];
      *(f32x4*)pp      = acc0;
      *(f32x4*)(pp+16) = acc1;
    }
    __syncthreads();
    if (t < 128){
      int b = t&31, uu = t>>5;
      float g4[4];
      #pragma unroll
      for (int g=0; g<4; ++g){
        int cc = uu*4 + g;
        float sum = biasl[cc];
        #pragma unroll
        for (int ww=0; ww<4; ++ww) sum += P[(ww*16+cc)*36 + b];
        g4[g] = sum;
      }
      float c2 = sigm(g4[1])*cst[t] + sigm(g4[0])*tanh_f(g4[2]);
      float h2 = sigm(g4[3])*tanh_f(c2);
      cst[t] = c2;
      int ug = u0 + uu;
      hcur[((s&1)^1)*32*H + b*H + ug] = f2b(h2);
      long oi = ((long)tt*32 + b)*H + ug;
      if (OUTBF) ((u16*)hseq)[oi] = f2b(h2);
      else       ((float*)hseq)[oi] = h2;
    }
    gridbar2(flags, gen, base+2+s, nwg);
  }
}

// ---------------- x pre-convert: fp32 (B,1024,320) -> bf16 [t*32+b][512] ----
__global__ void cvt_x(const float* __restrict__ x, u16* __restrict__ xp){
  long id8 = ((long)blockIdx.x*256 + threadIdx.x)*8;
  int rr = (int)(id8 >> 9); int k = (int)(id8 & 511);
  int tt = rr >> 5, b = rr & 31;
  union { uint4 q; u16 s[8]; } u;
  if (k < 320){
    const float* p = x + (long)b*327680 + (long)tt*320 + k;
    float4 v0 = *(const float4*)p, v1 = *(const float4*)(p+4);
    u.s[0]=f2b(v0.x); u.s[1]=f2b(v0.y); u.s[2]=f2b(v0.z); u.s[3]=f2b(v0.w);
    u.s[4]=f2b(v1.x); u.s[5]=f2b(v1.y); u.s[6]=f2b(v1.z); u.s[7]=f2b(v1.w);
  } else {
    for (int j=0;j<8;++j) u.s[j]=0;
  }
  *(uint4*)(xp + id8) = u.q;
}

// ---------------- tiled GEMM: C = [A0|A1] . W^T + bias ---------------------
template<int ABF, int CBF>
__global__ __launch_bounds__(256,1) void gemm_bias(
  const void* __restrict__ A0, long lda0, const void* __restrict__ A1, long lda1, int K0,
  const float* __restrict__ W, const float* __restrict__ bias, void* __restrict__ C,
  int M, int N, int K, int ldw, int act)
{
  __shared__ __align__(16) float As[16*132];
  __shared__ __align__(16) float Bs[16*132];
  const int t = threadIdx.x;
  const int m0 = blockIdx.x*128, n0 = blockIdx.y*128;
  const int tx = t&15, ty = t>>4;
  float acc[8][8];
  for (int i=0;i<8;++i)
    for (int j=0;j<8;++j) acc[i][j]=0.f;
  const int row = t>>1, seg = t&1;
  for (int k0=0;k0<K;k0+=16){
    {
      const int kk = k0 + seg*8;
      const void* Ab; long lda; int kof;
      if (kk < K0){ Ab=A0; lda=lda0; kof=kk; } else { Ab=A1; lda=lda1; kof=kk-K0; }
      float v[8];
      if (ABF){
        const u16* ap = (const u16*)Ab + (long)(m0+row)*lda + kof;
        union { uint4 q; u16 s[8]; } u; u.q = *(const uint4*)ap;
        #pragma unroll
        for (int j=0;j<8;++j) v[j]=b2f(u.s[j]);
      } else {
        const float* ap = (const float*)Ab + (long)(m0+row)*lda + kof;
        float4 x0 = *(const float4*)(ap);
        float4 x1 = *(const float4*)(ap+4);
        v[0]=x0.x;v[1]=x0.y;v[2]=x0.z;v[3]=x0.w;v[4]=x1.x;v[5]=x1.y;v[6]=x1.z;v[7]=x1.w;
      }
      const int kb = seg*8;
      #pragma unroll
      for (int j=0;j<8;++j) As[(kb+j)*132+row]=v[j];
    }
    {
      const int n = n0 + row;
      float4 y0 = {0,0,0,0}, y1 = {0,0,0,0};
      if (n < N){
        const float* wp = W + (long)n*ldw + k0 + seg*8;
        y0 = *(const float4*)(wp); y1 = *(const float4*)(wp+4);
      }
      const int kb = seg*8;
      Bs[(kb+0)*132+row]=y0.x; Bs[(kb+1)*132+row]=y0.y; Bs[(kb+2)*132+row]=y0.z; Bs[(kb+3)*132+row]=y0.w;
      Bs[(kb+4)*132+row]=y1.x; Bs[(kb+5)*132+row]=y1.y; Bs[(kb+6)*132+row]=y1.z; Bs[(kb+7)*132+row]=y1.w;
    }
    __syncthreads();
    #pragma unroll
    for (int k=0;k<16;++k){
      const float* ap = &As[k*132 + ty*8];
      const float* bp = &Bs[k*132 + tx*8];
      float4 A0v=*(const float4*)(ap), A1v=*(const float4*)(ap+4);
      float4 B0v=*(const float4*)(bp), B1v=*(const float4*)(bp+4);
      float av[8]={A0v.x,A0v.y,A0v.z,A0v.w,A1v.x,A1v.y,A1v.z,A1v.w};
      float bv[8]={B0v.x,B0v.y,B0v.z,B0v.w,B1v.x,B1v.y,B1v.z,B1v.w};
      #pragma unroll
      for (int i=0;i<8;++i){
        #pragma unroll
        for (int j=0;j<8;++j) acc[i][j] += av[i]*bv[j];
      }
    }
    __syncthreads();
  }
  float bv[8];
  #pragma unroll
  for (int j=0;j<8;++j){ int n = n0+tx*8+j; bv[j] = (n<N)? bias[n] : 0.f; }
  const bool full = (n0+128 <= N);
  #pragma unroll
  for (int i=0;i<8;++i){
    const int m = m0 + ty*8 + i;
    float v[8];
    #pragma unroll
    for (int j=0;j<8;++j){
      float x = acc[i][j] + bv[j];
      if (act) x = (x > 0.f) ? x : 0.1f*x;
      v[j] = x;
    }
    if (CBF){
      u16* cp = (u16*)C + (long)m*N + n0 + tx*8;
      union { uint4 q; u16 s[8]; } u;
      #pragma unroll
      for (int j=0;j<8;++j) u.s[j]=f2b(v[j]);
      *(uint4*)cp = u.q;
    } else {
      float* cp = (float*)C + (long)m*N + n0 + tx*8;
      if (full){
        float4 s0 = {v[0],v[1],v[2],v[3]}, s1 = {v[4],v[5],v[6],v[7]};
        *(float4*)(cp) = s0; *(float4*)(cp+4) = s1;
      } else {
        #pragma unroll
        for (int j=0;j<8;++j) if (n0+tx*8+j < N) cp[j] = v[j];
      }
    }
  }
}

// ---------------- elementwise helpers --------------------------------------
__global__ void mask_bf16(u16* __restrict__ buf, int F, const float* __restrict__ xm){
  long id8 = ((long)blockIdx.x*256 + threadIdx.x)*8;
  int row = (int)(id8 / F);
  int tt = row>>5, b = row&31;
  float m = xm[b*4096 + 4*tt];
  union { uint4 q; u16 s[8]; } u;
  u.q = *(uint4*)(buf + id8);
  #pragma unroll
  for (int j=0;j<8;++j) u.s[j] = f2b(b2f(u.s[j])*m);
  *(uint4*)(buf + id8) = u.q;
}

__global__ void embed_gather(const float* __restrict__ emb, const int* __restrict__ y,
                             float* __restrict__ out){
  int id = blockIdx.x*256 + threadIdx.x;
  int p = id&255, r = id>>8;
  int l = r>>5, b = r&31;
  out[id] = emb[(long)y[b*65 + l]*256 + p];
}

__global__ void zero_f(float* __restrict__ p, int n){
  int id = blockIdx.x*256 + threadIdx.x;
  if (id < n) p[id] = 0.f;
}

__global__ void set_val(float* p, float v){ p[0] = v; }

__global__ void attfea_k(const float* __restrict__ lstms, const float* __restrict__ ctxs,
                         const float* __restrict__ ym, float* __restrict__ attf,
                         u16* __restrict__ attfb){
  long id4 = ((long)blockIdx.x*256 + threadIdx.x)*4;
  int r = (int)(id4>>9); int f = (int)(id4&511);
  int l = r>>5, b = r&31;
  float m = ym[b*65 + l + 1];
  float4 v = (f<256) ? *(const float4*)(lstms + (long)r*256 + f)
                     : *(const float4*)(ctxs  + (long)r*256 + (f-256));
  v.x*=m; v.y*=m; v.z*=m; v.w*=m;
  *(float4*)(attf + id4) = v;
  u16* ob = attfb + id4;
  ob[0]=f2b(v.x); ob[1]=f2b(v.y); ob[2]=f2b(v.z); ob[3]=f2b(v.w);
}

__global__ void dcat_k(const float* __restrict__ attf, const float* __restrict__ dout,
                       const float* __restrict__ ym, float* __restrict__ dcat){
  long id4 = ((long)blockIdx.x*256 + threadIdx.x)*4;
  int r = (int)(id4/768); int f = (int)(id4 - (long)r*768);
  int l = r>>5, b = r&31;
  float m = ym[b*65 + l + 1];
  float4 v = (f<512) ? *(const float4*)(attf + (long)r*512 + f)
                     : *(const float4*)(dout + (long)r*256 + (f-512));
  v.x*=m; v.y*=m; v.z*=m; v.w*=m;
  *(float4*)(dcat + id4) = v;
}

// ---------------- decoder attention step kernels ----------------------------
__global__ __launch_bounds__(256,1) void k1_dec(
  const float* __restrict__ bodyR, float* __restrict__ bodyW,
  const float* __restrict__ epart, const float* __restrict__ Whh,
  const float* __restrict__ Wih, float* __restrict__ cc,
  float* __restrict__ lstms, int s)
{
  __shared__ __align__(16) float vT[512*36];
  __shared__ float gl[32*32];
  const int t = threadIdx.x, wg = blockIdx.x;
  for (int i = t*4; i < 32*512; i += 1024){
    int b = i>>9, k = i&511;
    float4 v = *(const float4*)(bodyR + b*512 + k);
    vT[(k+0)*36+b]=v.x; vT[(k+1)*36+b]=v.y; vT[(k+2)*36+b]=v.z; vT[(k+3)*36+b]=v.w;
  }
  __syncthreads();
  const int c_l = t>>3, bq = t&7;
  const int col = (c_l&3)*256 + wg*8 + (c_l>>2);
  float a0=0.f,a1=0.f,a2=0.f,a3=0.f;
  for (int k=0;k<256;k+=4){
    float4 w = *(const float4*)(Whh + (long)col*256 + k);
    const float* vp = &vT[k*36 + bq*4];
    float4 v0=*(const float4*)(vp), v1=*(const float4*)(vp+36), v2=*(const float4*)(vp+72), v3=*(const float4*)(vp+108);
    a0 += w.x*v0.x + w.y*v1.x + w.z*v2.x + w.w*v3.x;
    a1 += w.x*v0.y + w.y*v1.y + w.z*v2.y + w.w*v3.y;
    a2 += w.x*v0.z + w.y*v1.z + w.z*v2.z + w.w*v3.z;
    a3 += w.x*v0.w + w.y*v1.w + w.z*v2.w + w.w*v3.w;
  }
  for (int k=256;k<512;k+=4){
    float4 w = *(const float4*)(Wih + (long)col*512 + k);
    const float* vp = &vT[k*36 + bq*4];
    float4 v0=*(const float4*)(vp), v1=*(const float4*)(vp+36), v2=*(const float4*)(vp+72), v3=*(const float4*)(vp+108);
    a0 += w.x*v0.x + w.y*v1.x + w.z*v2.x + w.w*v3.x;
    a1 += w.x*v0.y + w.y*v1.y + w.z*v2.y + w.w*v3.y;
    a2 += w.x*v0.z + w.y*v1.z + w.z*v2.z + w.w*v3.z;
    a3 += w.x*v0.w + w.y*v1.w + w.z*v2.w + w.w*v3.w;
  }
  gl[c_l*32+bq*4+0] = a0 + epart[((long)s*32 + bq*4+0)*1024 + col];
  gl[c_l*32+bq*4+1] = a1 + epart[((long)s*32 + bq*4+1)*1024 + col];
  gl[c_l*32+bq*4+2] = a2 + epart[((long)s*32 + bq*4+2)*1024 + col];
  gl[c_l*32+bq*4+3] = a3 + epart[((long)s*32 + bq*4+3)*1024 + col];
  __syncthreads();
  {
    const int u_ = t>>5, b = t&31, ug = wg*8 + u_;
    const float gi=gl[(u_*4+0)*32+b], gf=gl[(u_*4+1)*32+b], gg=gl[(u_*4+2)*32+b], go=gl[(u_*4+3)*32+b];
    float c0 = cc[b*256+ug];
    float c2 = sigm(gf)*c0 + sigm(gi)*tanh_f(gg);
    float h2 = sigm(go)*tanh_f(c2);
    cc[b*256+ug] = c2;
    bodyW[b*512 + ug] = h2;
    lstms[((long)s*32 + b)*256 + ug] = h2;
  }
}

__global__ __launch_bounds__(256,1) void k2_dec(
  const float* __restrict__ bodyW, const float* __restrict__ vW,
  const float* __restrict__ vb, float* __restrict__ state)
{
  __shared__ __align__(16) float hT[256*36];
  const int t = threadIdx.x, wg = blockIdx.x;
  for (int i = t*4; i < 8192; i += 1024){
    int b = i>>8, k = i&255;
    float4 v = *(const float4*)(bodyW + b*512 + k);
    hT[(k+0)*36+b]=v.x; hT[(k+1)*36+b]=v.y; hT[(k+2)*36+b]=v.z; hT[(k+3)*36+b]=v.w;
  }
  __syncthreads();
  const int p = wg*32 + (t>>3), bq = t&7;
  float a0=0.f,a1=0.f,a2=0.f,a3=0.f;
  for (int k=0;k<256;k+=4){
    float4 w = *(const float4*)(vW + (long)p*256 + k);
    const float* vp = &hT[k*36 + bq*4];
    float4 v0=*(const float4*)(vp), v1=*(const float4*)(vp+36), v2=*(const float4*)(vp+72), v3=*(const float4*)(vp+108);
    a0 += w.x*v0.x + w.y*v1.x + w.z*v2.x + w.w*v3.x;
    a1 += w.x*v0.y + w.y*v1.y + w.z*v2.y + w.w*v3.y;
    a2 += w.x*v0.z + w.y*v1.z + w.z*v2.z + w.w*v3.z;
    a3 += w.x*v0.w + w.y*v1.w + w.z*v2.w + w.w*v3.w;
  }
  float bb = vb[p];
  state[(bq*4+0)*256 + p] = a0 + bb;
  state[(bq*4+1)*256 + p] = a1 + bb;
  state[(bq*4+2)*256 + p] = a2 + bb;
  state[(bq*4+3)*256 + p] = a3 + bb;
}

__global__ __launch_bounds__(256,1) void k3_dec(
  const float* __restrict__ state, const u16* __restrict__ atth,
  const float* __restrict__ wav, const float* __restrict__ xm,
  float* __restrict__ sc, float* __restrict__ scm)
{
  __shared__ float st[256], wv[256], red[256];
  const int t = threadIdx.x;
  const int b = blockIdx.x>>2, ch = blockIdx.x&3;
  st[t] = state[b*256 + t];
  wv[t] = wav[t];
  __syncthreads();
  const int tp = ch*256 + t;
  const u16* ap = atth + ((long)tp*32 + b)*256;
  float acc = 0.f;
  for (int p=0;p<256;p+=4){
    ushort4 a = *(const ushort4*)(ap+p);
    acc += wv[p+0]*tanh_f(st[p+0]+b2f(a.x));
    acc += wv[p+1]*tanh_f(st[p+1]+b2f(a.y));
    acc += wv[p+2]*tanh_f(st[p+2]+b2f(a.z));
    acc += wv[p+3]*tanh_f(st[p+3]+b2f(a.w));
  }
  acc += (xm[b*4096 + 4*tp] - 1.0f)*1e30f;
  sc[b*1024 + tp] = acc;
  red[t] = acc;
  __syncthreads();
  for (int o=128;o>0;o>>=1){ if (t<o) red[t]=fmaxf(red[t],red[t+o]); __syncthreads(); }
  if (t==0) scm[b*4+ch] = red[0];
}

__global__ __launch_bounds__(256,1) void k4_dec(
  const float* __restrict__ sc, const float* __restrict__ scm,
  const u16* __restrict__ eout, float* __restrict__ ctxs,
  float* __restrict__ bodyW, int s)
{
  __shared__ float al[1024];
  __shared__ float red[256];
  const int t = threadIdx.x, b = blockIdx.x;
  float m = fmaxf(fmaxf(scm[b*4+0],scm[b*4+1]), fmaxf(scm[b*4+2],scm[b*4+3]));
  float ps = 0.f;
  #pragma unroll
  for (int j=0;j<4;++j){
    int tp = t + j*256;
    float e = __expf(sc[b*1024+tp] - m);
    al[tp] = e; ps += e;
  }
  red[t]=ps; __syncthreads();
  for (int o=128;o>0;o>>=1){ if (t<o) red[t]+=red[t+o]; __syncthreads(); }
  float rinv = 1.0f/red[0];
  float acc = 0.f;
  const u16* ep = eout + b*256 + t;
  for (int tp=0;tp<1024;++tp) acc += al[tp] * b2f(ep[(long)tp*8192]);
  float cv = acc*rinv;
  ctxs[((long)s*32 + b)*256 + t] = cv;
  bodyW[b*512 + 256 + t] = cv;
}

// ---------------- loss ------------------------------------------------------
__global__ __launch_bounds__(256,1) void loss_row(
  const float* __restrict__ logits, const int* __restrict__ y,
  const float* __restrict__ ym, float* __restrict__ rows)
{
  __shared__ float red[256];
  const int r = blockIdx.x, t = threadIdx.x;
  const float* row = logits + (long)r*4235;
  float mx = -3.0e38f;
  for (int i=t;i<4235;i+=256) mx = fmaxf(mx, row[i]);
  red[t]=mx; __syncthreads();
  for (int o=128;o>0;o>>=1){ if (t<o) red[t]=fmaxf(red[t],red[t+o]); __syncthreads(); }
  const float M = red[0];
  __syncthreads();
  float se=0.f, sl=0.f;
  for (int i=t;i<4235;i+=256){ float v=row[i]; se += __expf(v-M); sl += v; }
  red[t]=se; __syncthreads();
  for (int o=128;o>0;o>>=1){ if (t<o) red[t]+=red[t+o]; __syncthreads(); }
  const float SE = red[0];
  __syncthreads();
  red[t]=sl; __syncthreads();
  for (int o=128;o>0;o>>=1){ if (t<o) red[t]+=red[t+o]; __syncthreads(); }
  const float SL = red[0];
  if (t==0){
    const int tt = r>>5, b = r&31;
    const float lse = M + logf(SE);
    const float mk = (ym[b*65 + tt + 1] > 0.f) ? 1.f : 0.f;
    rows[r]        = (4235.0f*lse - SL)*mk;
    rows[2048 + r] = (lse - row[y[b*65 + tt + 1]])*mk;
    rows[4096 + r] = mk;
  }
}

__global__ __launch_bounds__(256,1) void loss_final(const float* __restrict__ rows, float* __restrict__ out){
  __shared__ float red[256];
  const int t = threadIdx.x;
  float s1=0.f,s2=0.f,s3=0.f;
  for (int i=t;i<2048;i+=256){ s1+=rows[i]; s2+=rows[2048+i]; s3+=rows[4096+i]; }
  red[t]=s1; __syncthreads();
  for (int o=128;o>0;o>>=1){ if (t<o) red[t]+=red[t+o]; __syncthreads(); }
  const float S = red[0]; __syncthreads();
  red[t]=s2; __syncthreads();
  for (int o=128;o>0;o>>=1){ if (t<o) red[t]+=red[t+o]; __syncthreads(); }
  const float NL = red[0]; __syncthreads();
  red[t]=s3; __syncthreads();
  for (int o=128;o>0;o>>=1){ if (t<o) red[t]+=red[t+o]; __syncthreads(); }
  const float N = red[0];
  if (t==0){
    float n = (N > 0.f) ? N : 1.f;
    out[0] = (S/n)*(0.1f/4235.0f) + 0.9f*(NL/n);
  }
}

// ---------------- launcher --------------------------------------------------
extern "C" void kernel_launch(void* const* d_in, const int* in_sizes, int n_in,
                              void* d_out, int out_size, void* d_ws, size_t ws_size,
                              hipStream_t stream)
{
  const float* x    = (const float*)d_in[0];
  const float* xm   = (const float*)d_in[1];
  const int*   y    = (const int*)  d_in[2];
  const float* ym   = (const float*)d_in[3];
  const float* l1_Wih=(const float*)d_in[4];  const float* l1_Whh=(const float*)d_in[5];  const float* l1_b=(const float*)d_in[6];
  const float* l2_Wih=(const float*)d_in[7];  const float* l2_Whh=(const float*)d_in[8];  const float* l2_b=(const float*)d_in[9];
  const float* l3_Wih=(const float*)d_in[10]; const float* l3_Whh=(const float*)d_in[11]; const float* l3_b=(const float*)d_in[12];
  const float* bf_Wih=(const float*)d_in[13]; const float* bf_Whh=(const float*)d_in[14]; const float* bf_b=(const float*)d_in[15];
  const float* bb_Wih=(const float*)d_in[16]; const float* bb_Whh=(const float*)d_in[17]; const float* bb_b=(const float*)d_in[18];
  const float* c1_W=(const float*)d_in[19]; const float* c1_b=(const float*)d_in[20];
  const float* c2_W=(const float*)d_in[21]; const float* c2_b=(const float*)d_in[22];
  const float* emb =(const float*)d_in[23];
  const float* att_Wih=(const float*)d_in[24]; const float* att_Whh=(const float*)d_in[25]; const float* att_b=(const float*)d_in[26];
  const float* w_W=(const float*)d_in[27]; const float* w_b=(const float*)d_in[28];
  const float* v_W=(const float*)d_in[29]; const float* v_b=(const float*)d_in[30];
  const float* wav=(const float*)d_in[31];
  const float* dec_Wih=(const float*)d_in[32]; const float* dec_Whh=(const float*)d_in[33]; const float* dec_b=(const float*)d_in[34];
  const float* cls_W=(const float*)d_in[35]; const float* cls_b=(const float*)d_in[36];

  // workspace layout (bytes); REQ kept at R3/R4's verified-fit value
  const size_t REQ = 137625600ull; // ~131.3 MiB
  if (ws_size < REQ){
    set_val<<<1,1,0,stream>>>((float*)d_out, -(float)(ws_size>>20));
    return;
  }
  char* ws = (char*)d_ws;
  unsigned* FLAGS = (unsigned*)(ws);            // 512B
  unsigned* GEN   = (unsigned*)(ws + 2048);
  u16* HC0 = (u16*)(ws + 65536);                // 5 x 64KB encoder hcur
  u16* HC1 = (u16*)(ws + 131072);
  u16* HC2 = (u16*)(ws + 196608);
  u16* HC3 = (u16*)(ws + 262144);
  u16* HC4 = (u16*)(ws + 327680);
  u16* DECHC = (u16*)(ws + 393216);             // 32KB
  u16* RING0 = (u16*)(ws + 1048576);            // 512KB
  u16* RING1 = (u16*)(ws + 1572864);            // 512KB
  u16* XP   = (u16*)(ws + 2097152);             // 32MB  [2,34)
  u16* HS2  = (u16*)(ws + 35651584);            // 32MB  [34,66)
  u16* HSF  = (u16*)(ws + 69206016);            // 32MB  [66,98)
  u16* HSB  = XP;                               // phase B overlay
  u16* C1OUT = HS2;                             // after bb done
  u16* EOUTB = HSF;                             // 16MB  (HSF dead after conv1)
  u16* ATTHB = (u16*)(ws + 85983232);           // 16MB  [82,98)
  float* LOGIT = (float*)XP;                    // 34.7MB [2,36.7) after conv2
  float* AR    = (float*)(ws + 102760448);      // decoder arena [98,~130.4)
  float* EMBED = AR;
  float* EPART = EMBED + 524288;
  float* LSTMS = EPART + 2097152;
  float* CTXS  = LSTMS + 524288;
  float* ATTF  = CTXS  + 524288;
  float* DOUT  = ATTF  + 1048576;
  float* DCAT  = DOUT  + 524288;
  float* SC    = DCAT  + 1572864;
  float* SCM   = SC    + 32768;
  float* ROWS  = SCM   + 128;
  float* BODY  = ROWS  + 6144;
  float* CC    = BODY  + 32768;
  float* STATE = CC    + 8192;
  u16*  ATTFB  = (u16*)(STATE + 8192);

  (void)hipMemsetAsync(ws, 0, 4096, stream);

  // ---------------- encoder: phase A (l1,l2,l3,bf pipelined) ----------------
  cvt_x<<<8192,256,0,stream>>>(x, XP);
  PipeArgs pa;
  pa.L[0] = { l1_Wih, l1_Whh, l1_b, XP,    RING0, HC0, 320, 0, 0, 1 };
  pa.L[1] = { l2_Wih, l2_Whh, l2_b, RING0, RING1, HC1, 512, 0, 1, 1 };
  pa.L[2] = { l3_Wih, l3_Whh, l3_b, RING1, HS2,   HC2, 512, 1, 1, 0 };
  pa.L[3] = { bf_Wih, bf_Whh, bf_b, HS2,   HSF,   HC3, 512, 1, 0, 0 };
  pa.xm = xm; pa.T = 1024; pa.flags = FLAGS; pa.gen = GEN; pa.base = 0; pa.nwg = 128; pa.rev = 0;
  pipe_lstm<4><<<128,256,0,stream>>>(pa);
  // ---------------- encoder: phase B (bb, reverse) --------------------------
  PipeArgs pb;
  pb.L[0] = { bb_Wih, bb_Whh, bb_b, HS2, HSB, HC4, 512, 1, 0, 0 };
  pb.L[1] = pb.L[0]; pb.L[2] = pb.L[0]; pb.L[3] = pb.L[0];
  pb.xm = xm; pb.T = 1024; pb.flags = FLAGS; pb.gen = GEN; pb.base = 1028; pb.nwg = 128; pb.rev = 1;
  pipe_lstm<1><<<128,256,0,stream>>>(pb);
  // conv1 (leaky) on concat [bf|bb], conv2, mask, att_h
  gemm_bias<1,1><<<dim3(256,4),256,0,stream>>>(HSF, 512, HSB, 512, 512,
      c1_W, c1_b, C1OUT, 32768, 512, 1024, 1024, 1);
  gemm_bias<1,1><<<dim3(256,2),256,0,stream>>>(C1OUT, 512, C1OUT, 512, 512,
      c2_W, c2_b, EOUTB, 32768, 256, 512, 512, 0);
  mask_bf16<<<4096,256,0,stream>>>(EOUTB, 256, xm);
  gemm_bias<1,1><<<dim3(256,2),256,0,stream>>>(EOUTB, 256, EOUTB, 256, 256,
      w_W, w_b, ATTHB, 32768, 256, 256, 256, 0);

  // ---------------- decoder -------------------------------------------------
  embed_gather<<<2048,256,0,stream>>>(emb, y, EMBED);
  gemm_bias<0,0><<<dim3(16,8),256,0,stream>>>(EMBED, 256, EMBED, 256, 256,
      att_Wih, att_b, EPART, 2048, 1024, 256, 512, 0);
  zero_f<<<160,256,0,stream>>>(BODY, 40960);
  for (int s=0;s<64;++s){
    float* bodyR = BODY + (s&1)*16384;
    float* bodyW = BODY + ((s+1)&1)*16384;
    k1_dec<<<32,256,0,stream>>>(bodyR, bodyW, EPART, att_Whh, att_Wih, CC, LSTMS, s);
    k2_dec<<<8,256,0,stream>>>(bodyW, v_W, v_b, STATE);
    k3_dec<<<128,256,0,stream>>>(STATE, ATTHB, wav, xm, SC, SCM);
    k4_dec<<<32,256,0,stream>>>(SC, SCM, EOUTB, CTXS, bodyW, s);
  }
  attfea_k<<<1024,256,0,stream>>>(LSTMS, CTXS, ym, ATTF, ATTFB);
  rec_mfma<512,256,128,0><<<64,256,0,stream>>>(ATTFB, dec_Wih, dec_Whh, dec_b,
      DOUT, DECHC, 64, 0, FLAGS, GEN, 2053, 64);
  dcat_k<<<1536,256,0,stream>>>(ATTF, DOUT, ym, DCAT);
  gemm_bias<0,0><<<dim3(16,34),256,0,stream>>>(DCAT, 768, DCAT, 768, 768,
      cls_W, cls_b, LOGIT, 2048, 4235, 768, 768, 0);
  loss_row<<<2048,256,0,stream>>>(LOGIT, y, ym, ROWS);
  loss_final<<<1,256,0,stream>>>(ROWS, (float*)d_out);
}

// Round 6
// 29483.582 us; speedup vs baseline: 9.1367x; 1.7970x over previous
//
#include <hip/hip_runtime.h>
#include <math.h>

#define DEV static __device__ __forceinline__
typedef unsigned short u16;
typedef unsigned int u32;

typedef __attribute__((ext_vector_type(8))) __bf16 bf16x8;
typedef __attribute__((ext_vector_type(4))) float f32x4;

DEV float sigm(float x){ return 1.0f/(1.0f+__expf(-x)); }
DEV float tanh_f(float x){ float e=__expf(2.0f*x); return 1.0f - 2.0f/(e+1.0f); }

DEV float b2f(u16 u){ union {u32 i; float f;} c; c.i = ((u32)u)<<16; return c.f; }
DEV u16 f2b(float f){ union {u32 i; float f;} c; c.f = f; u32 r = (c.i + 0x7FFFu + ((c.i>>16)&1u)) >> 16; return (u16)r; }

// coherent (cross-XCD) dword ops — system scope: write-through / L2-bypass
DEV void cstore(u32* p, u32 v){ __hip_atomic_store(p, v, __ATOMIC_RELAXED, __HIP_MEMORY_SCOPE_SYSTEM); }
DEV u32  cload(const u32* p){ return __hip_atomic_load(p, __ATOMIC_RELAXED, __HIP_MEMORY_SCOPE_SYSTEM); }

// poll all producer flags >= target (no fences, no cache maintenance)
DEV void waitflags(unsigned* flags, unsigned target, int nwg){
  const int lane = threadIdx.x & 63;
  unsigned long long spin = 0;
  for(;;){
    bool ok = true;
    for (int j=lane; j<nwg; j+=64)
      ok &= ((int)(cload(&flags[j]) - target) >= 0);
    if (__all(ok)) break;
    if (++spin > 2000000ull) break; // safety: garbage instead of hang
    __builtin_amdgcn_s_sleep(1);
  }
}

// ---------------- pipelined persistent MFMA LSTM (H=512) --------------------
// NL layers on a time diagonal. Cross-WG h exchange via EX[l][par][32][512]
// (u16, coherent u32 stores / coherent global_load_lds reads). No fences.
struct PL2 { const float *Wih, *Whh, *bias; const u16* xplain; u16* hout; int kx, maskout; };
struct PA2 {
  PL2 L[4];
  u16* ex;        // [NL][2][32][512] u16
  u16* exm;       // [2][32][512] u16 (masked l3 output, phase A only)
  const float* xm;
  unsigned* flags;
  int T, nwg, rev; unsigned base;
};

template<int NL>
__global__ __launch_bounds__(256,1) void pipe2(PA2 A){
  __shared__ __align__(16) char Vs[65536];
  __shared__ float P[NL*2304];
  __shared__ float cst[NL*128];
  __shared__ float biasl[NL*16];
  const int t = threadIdx.x, wg = blockIdx.x;
  const int u0 = wg*4;
  const int w = t>>6, lane = t&63;
  const int c = lane&15, lg = lane>>4;
  const int r = (c&3)*512 + u0 + (c>>2);
  u32* exu  = (u32*)A.ex;    // [NL][2][32][256]
  u32* exmu = (u32*)A.exm;   // [2][32][256]
  // one-time weight preload (bf16, 32 VGPR per layer per wave)
  bf16x8 bw[NL][8];
  #pragma unroll
  for (int l=0;l<NL;++l){
    const int kx = A.L[l].kx;
    #pragma unroll
    for (int f=0;f<8;++f){
      union { bf16x8 v; u16 s[8]; } u;
      int k8 = w*256 + f*32 + lg*8;
      if (k8 < 512){
        if (k8 < kx){
          const float* p = A.L[l].Wih + (long)r*kx + k8;
          for (int j=0;j<8;++j) u.s[j]=f2b(p[j]);
        } else { for (int j=0;j<8;++j) u.s[j]=0; }
      } else {
        const float* p = A.L[l].Whh + (long)r*512 + (k8-512);
        for (int j=0;j<8;++j) u.s[j]=f2b(p[j]);
      }
      bw[l][f]=u.v;
    }
  }
  if (t<16){
    #pragma unroll
    for (int l=0;l<NL;++l) biasl[l*16+t] = A.L[l].bias[(t&3)*512 + u0 + (t>>2)];
  }
  if (t<128){
    #pragma unroll
    for (int l=0;l<NL;++l) cst[l*128+t]=0.f;
  }
  // zero own EX columns (both parities, all layers + EXM) via coherent stores
  for (int i=t; i<(NL+1)*128; i+=256){
    int reg = i>>7, rem = i&127;
    int par = (rem>>6)&1, b = (rem>>1)&31, j = rem&1;
    u32* p = (reg<NL) ? exu + (reg*2+par)*8192 + b*256 + wg*2 + j
                      : exmu + par*8192 + b*256 + wg*2 + j;
    cstore(p, 0);
  }
  __syncthreads();  // drains vmcnt per wave before barrier -> stores acked
  if (t==0) cstore(&A.flags[wg], A.base+1);
  const int sb = lane>>5;
  const int coffb = (lane&31)*16;
  const int T = A.T;
  for (int s=0; s<T+NL-1; ++s){
    waitflags(A.flags, A.base+s+1, A.nwg);
    const int par = (s-1)&1;
    #pragma unroll
    for (int l=0;l<NL;++l){
      const int sc = s-l;
      if (sc < 0 || sc >= T) continue;
      const int tt = A.rev ? (T-1-sc) : sc;
      // ---- stage own 512B-per-row k-slice into wave-private LDS ----
      const char* base_;
      if (w<2){
        if (l==0)            base_ = (const char*)A.L[0].xplain + (long)tt*32768 + w*512;
        else if (l==3)       base_ = (const char*)A.exm + par*32768 + w*512;
        else                 base_ = (const char*)A.ex + ((l-1)*2+par)*32768 + w*512;
      } else {
        base_ = (const char*)A.ex + (l*2+par)*32768 + (w-2)*512;
      }
      #pragma unroll
      for (int i=0;i<16;++i){
        int b = i*2 + sb;
        const char* src = base_ + b*1024 + (coffb ^ ((b&7)<<4));
        void* ldst = (void*)(Vs + w*16384 + i*1024);
        if (w<2 && l==0) __builtin_amdgcn_global_load_lds((const u32*)src, (u32*)ldst, 16, 0, 0);
        else             __builtin_amdgcn_global_load_lds((const u32*)src, (u32*)ldst, 16, 0, 0x11);
      }
      asm volatile("s_waitcnt vmcnt(0)" ::: "memory");
      // ---- MFMA over own k-slice ----
      f32x4 acc0={0.f,0.f,0.f,0.f}, acc1={0.f,0.f,0.f,0.f};
      const int b1 = c+16;
      #pragma unroll
      for (int f=0;f<8;++f){
        int koff = f*64 + lg*16;
        union { bf16x8 v; uint4 q; } a0, a1;
        a0.q = *(const uint4*)(Vs + w*16384 + c *512 + (koff ^ ((c &7)<<4)));
        a1.q = *(const uint4*)(Vs + w*16384 + b1*512 + (koff ^ ((b1&7)<<4)));
        acc0 = __builtin_amdgcn_mfma_f32_16x16x32_bf16(a0.v, bw[l][f], acc0, 0,0,0);
        acc1 = __builtin_amdgcn_mfma_f32_16x16x32_bf16(a1.v, bw[l][f], acc1, 0,0,0);
      }
      float* pp = &P[l*2304 + (w*16+c)*36 + lg*4];
      *(f32x4*)pp      = acc0;
      *(f32x4*)(pp+16) = acc1;
    }
    __syncthreads();
    if (t<128){
      const int b = t&31, uu = t>>5, wpw = t>>6;
      #pragma unroll
      for (int l=0;l<NL;++l){
        const int sc = s-l;
        if (sc<0 || sc>=T) continue;
        const int tt = A.rev ? (T-1-sc) : sc;
        float g4[4];
        #pragma unroll
        for (int g=0; g<4; ++g){
          int cc = uu*4+g;
          float sum = biasl[l*16+cc];
          #pragma unroll
          for (int ww=0; ww<4; ++ww) sum += P[l*2304 + (ww*16+cc)*36 + b];
          g4[g]=sum;
        }
        float c2 = sigm(g4[1])*cst[l*128+t] + sigm(g4[0])*tanh_f(g4[2]);
        float h2 = sigm(g4[3])*tanh_f(c2);
        cst[l*128+t]=c2;
        // post unmasked h to EX[l][s&1] (packed u32, coherent)
        u32 hv = (u32)f2b(h2);
        u32 ot = (u32)__shfl_xor((int)hv, 32);
        if (lane<32)
          cstore(exu + (l*2+(s&1))*8192 + b*256 + wg*2 + wpw, (hv&0xffffu)|(ot<<16));
        if (NL==4 && l==2){
          float m = A.xm[b*4096 + 4*tt];
          float hm = h2*m;
          u32 hmv = (u32)f2b(hm);
          u32 otm = (u32)__shfl_xor((int)hmv, 32);
          if (lane<32)
            cstore(exmu + (s&1)*8192 + b*256 + wg*2 + wpw, (hmv&0xffffu)|(otm<<16));
          if (A.L[l].hout) A.L[l].hout[((long)tt*32+b)*512 + u0+uu] = f2b(hm);
        } else if (A.L[l].hout){
          float ov = h2;
          if (A.L[l].maskout) ov *= A.xm[b*4096 + 4*tt];
          A.L[l].hout[((long)tt*32+b)*512 + u0+uu] = f2b(ov);
        }
      }
    }
    __syncthreads();
    if (t==0) cstore(&A.flags[wg], A.base+s+2);
  }
}

// ---------------- decoder persistent MFMA LSTM (H=256), same protocol -------
__global__ __launch_bounds__(256,1) void dec_rec2(
    const u16* __restrict__ xin, const float* __restrict__ Wih,
    const float* __restrict__ Whh, const float* __restrict__ bias,
    float* __restrict__ dout, u16* __restrict__ exd,
    unsigned* flags, unsigned base, int T)
{
  __shared__ __align__(16) char Vs[49152];
  __shared__ float P[2304];
  __shared__ float cst[128];
  __shared__ float biasl[16];
  const int t = threadIdx.x, wg = blockIdx.x; // 64 WGs
  const int u0 = wg*4;
  const int w = t>>6, lane = t&63, c = lane&15, lg = lane>>4;
  const int r = (c&3)*256 + u0 + (c>>2);
  u32* exu = (u32*)exd; // [2][32][128]
  const int nf = (w<2) ? 8 : 4;
  bf16x8 bw[8];
  #pragma unroll
  for (int f=0;f<8;++f){
    union { bf16x8 v; u16 s[8]; } u;
    if (f < nf){
      if (w<2){
        const float* p = Wih + (long)r*512 + w*256 + f*32 + lg*8;
        for (int j=0;j<8;++j) u.s[j]=f2b(p[j]);
      } else {
        const float* p = Whh + (long)r*256 + (w-2)*128 + f*32 + lg*8;
        for (int j=0;j<8;++j) u.s[j]=f2b(p[j]);
      }
    } else { for (int j=0;j<8;++j) u.s[j]=0; }
    bw[f]=u.v;
  }
  if (t<16) biasl[t] = bias[(t&3)*256 + u0 + (t>>2)];
  if (t<128) cst[t]=0.f;
  if (t<128){
    int par=(t>>6)&1, b=(t>>1)&31, j=t&1;
    cstore(exu + par*4096 + b*128 + wg*2 + j, 0);
  }
  __syncthreads();
  if (t==0) cstore(&flags[wg], base+1);
  const int waveOff = (w<2) ? w*16384 : 32768 + (w-2)*8192;
  const int NI  = (w<2) ? 16 : 8;
  const int rpi = (w<2) ? 2 : 4;
  const int sb  = (w<2) ? (lane>>5) : (lane>>4);
  const int coffb = (w<2) ? (lane&31)*16 : (lane&15)*16;
  const int rowB = (w<2) ? 512 : 256;
  for (int s=0; s<T; ++s){
    waitflags(flags, base+s+1, 64);
    const int par = (s-1)&1;
    #pragma unroll
    for (int i=0;i<16;++i){
      if (i>=NI) break;
      int b = i*rpi + sb;
      const char* src = (w<2)
        ? (const char*)xin + (long)s*32768 + w*512 + b*1024 + (coffb ^ ((b&7)<<4))
        : (const char*)exd + par*16384 + (w-2)*256 + b*512 + (coffb ^ ((b&7)<<4));
      void* ldst = (void*)(Vs + waveOff + i*1024);
      if (w<2) __builtin_amdgcn_global_load_lds((const u32*)src, (u32*)ldst, 16, 0, 0);
      else     __builtin_amdgcn_global_load_lds((const u32*)src, (u32*)ldst, 16, 0, 0x11);
    }
    asm volatile("s_waitcnt vmcnt(0)" ::: "memory");
    f32x4 acc0={0.f,0.f,0.f,0.f}, acc1={0.f,0.f,0.f,0.f};
    const int b1 = c+16;
    #pragma unroll
    for (int f=0;f<8;++f){
      if (f>=nf) break;
      int koff = f*64 + lg*16;
      union { bf16x8 v; uint4 q; } a0, a1;
      a0.q = *(const uint4*)(Vs + waveOff + c *rowB + (koff ^ ((c &7)<<4)));
      a1.q = *(const uint4*)(Vs + waveOff + b1*rowB + (koff ^ ((b1&7)<<4)));
      acc0 = __builtin_amdgcn_mfma_f32_16x16x32_bf16(a0.v, bw[f], acc0, 0,0,0);
      acc1 = __builtin_amdgcn_mfma_f32_16x16x32_bf16(a1.v, bw[f], acc1, 0,0,0);
    }
    {
      float* pp = &P[(w*16+c)*36 + lg*4];
      *(f32x4*)pp      = acc0;
      *(f32x4*)(pp+16) = acc1;
    }
    __syncthreads();
    if (t<128){
      const int b = t&31, uu = t>>5, wpw = t>>6;
      float g4[4];
      #pragma unroll
      for (int g=0; g<4; ++g){
        int cc = uu*4+g;
        float sum = biasl[cc];
        #pragma unroll
        for (int ww=0; ww<4; ++ww) sum += P[(ww*16+cc)*36 + b];
        g4[g]=sum;
      }
      float c2 = sigm(g4[1])*cst[t] + sigm(g4[0])*tanh_f(g4[2]);
      float h2 = sigm(g4[3])*tanh_f(c2);
      cst[t]=c2;
      u32 hv = (u32)f2b(h2);
      u32 ot = (u32)__shfl_xor((int)hv, 32);
      if (lane<32)
        cstore(exu + (s&1)*4096 + b*128 + wg*2 + wpw, (hv&0xffffu)|(ot<<16));
      dout[((long)s*32+b)*256 + u0+uu] = h2;
    }
    __syncthreads();
    if (t==0) cstore(&flags[wg], base+s+2);
  }
}

// ---------------- x pre-convert: fp32 (B,1024,320) -> bf16 [t*32+b][512] ----
__global__ void cvt_x(const float* __restrict__ x, u16* __restrict__ xp){
  long id8 = ((long)blockIdx.x*256 + threadIdx.x)*8;
  int rr = (int)(id8 >> 9); int k = (int)(id8 & 511);
  int tt = rr >> 5, b = rr & 31;
  union { uint4 q; u16 s[8]; } u;
  if (k < 320){
    const float* p = x + (long)b*327680 + (long)tt*320 + k;
    float4 v0 = *(const float4*)p, v1 = *(const float4*)(p+4);
    u.s[0]=f2b(v0.x); u.s[1]=f2b(v0.y); u.s[2]=f2b(v0.z); u.s[3]=f2b(v0.w);
    u.s[4]=f2b(v1.x); u.s[5]=f2b(v1.y); u.s[6]=f2b(v1.z); u.s[7]=f2b(v1.w);
  } else {
    for (int j=0;j<8;++j) u.s[j]=0;
  }
  *(uint4*)(xp + id8) = u.q;
}

// ---------------- tiled GEMM: C = [A0|A1] . W^T + bias ---------------------
template<int ABF, int CBF>
__global__ __launch_bounds__(256,1) void gemm_bias(
  const void* __restrict__ A0, long lda0, const void* __restrict__ A1, long lda1, int K0,
  const float* __restrict__ W, const float* __restrict__ bias, void* __restrict__ C,
  int M, int N, int K, int ldw, int act)
{
  __shared__ __align__(16) float As[16*132];
  __shared__ __align__(16) float Bs[16*132];
  const int t = threadIdx.x;
  const int m0 = blockIdx.x*128, n0 = blockIdx.y*128;
  const int tx = t&15, ty = t>>4;
  float acc[8][8];
  for (int i=0;i<8;++i)
    for (int j=0;j<8;++j) acc[i][j]=0.f;
  const int row = t>>1, seg = t&1;
  for (int k0=0;k0<K;k0+=16){
    {
      const int kk = k0 + seg*8;
      const void* Ab; long lda; int kof;
      if (kk < K0){ Ab=A0; lda=lda0; kof=kk; } else { Ab=A1; lda=lda1; kof=kk-K0; }
      float v[8];
      if (ABF){
        const u16* ap = (const u16*)Ab + (long)(m0+row)*lda + kof;
        union { uint4 q; u16 s[8]; } u; u.q = *(const uint4*)ap;
        #pragma unroll
        for (int j=0;j<8;++j) v[j]=b2f(u.s[j]);
      } else {
        const float* ap = (const float*)Ab + (long)(m0+row)*lda + kof;
        float4 x0 = *(const float4*)(ap);
        float4 x1 = *(const float4*)(ap+4);
        v[0]=x0.x;v[1]=x0.y;v[2]=x0.z;v[3]=x0.w;v[4]=x1.x;v[5]=x1.y;v[6]=x1.z;v[7]=x1.w;
      }
      const int kb = seg*8;
      #pragma unroll
      for (int j=0;j<8;++j) As[(kb+j)*132+row]=v[j];
    }
    {
      const int n = n0 + row;
      float4 y0 = {0,0,0,0}, y1 = {0,0,0,0};
      if (n < N){
        const float* wp = W + (long)n*ldw + k0 + seg*8;
        y0 = *(const float4*)(wp); y1 = *(const float4*)(wp+4);
      }
      const int kb = seg*8;
      Bs[(kb+0)*132+row]=y0.x; Bs[(kb+1)*132+row]=y0.y; Bs[(kb+2)*132+row]=y0.z; Bs[(kb+3)*132+row]=y0.w;
      Bs[(kb+4)*132+row]=y1.x; Bs[(kb+5)*132+row]=y1.y; Bs[(kb+6)*132+row]=y1.z; Bs[(kb+7)*132+row]=y1.w;
    }
    __syncthreads();
    #pragma unroll
    for (int k=0;k<16;++k){
      const float* ap = &As[k*132 + ty*8];
      const float* bp = &Bs[k*132 + tx*8];
      float4 A0v=*(const float4*)(ap), A1v=*(const float4*)(ap+4);
      float4 B0v=*(const float4*)(bp), B1v=*(const float4*)(bp+4);
      float av[8]={A0v.x,A0v.y,A0v.z,A0v.w,A1v.x,A1v.y,A1v.z,A1v.w};
      float bv[8]={B0v.x,B0v.y,B0v.z,B0v.w,B1v.x,B1v.y,B1v.z,B1v.w};
      #pragma unroll
      for (int i=0;i<8;++i){
        #pragma unroll
        for (int j=0;j<8;++j) acc[i][j] += av[i]*bv[j];
      }
    }
    __syncthreads();
  }
  float bv[8];
  #pragma unroll
  for (int j=0;j<8;++j){ int n = n0+tx*8+j; bv[j] = (n<N)? bias[n] : 0.f; }
  const bool full = (n0+128 <= N);
  #pragma unroll
  for (int i=0;i<8;++i){
    const int m = m0 + ty*8 + i;
    float v[8];
    #pragma unroll
    for (int j=0;j<8;++j){
      float x = acc[i][j] + bv[j];
      if (act) x = (x > 0.f) ? x : 0.1f*x;
      v[j] = x;
    }
    if (CBF){
      u16* cp = (u16*)C + (long)m*N + n0 + tx*8;
      union { uint4 q; u16 s[8]; } u;
      #pragma unroll
      for (int j=0;j<8;++j) u.s[j]=f2b(v[j]);
      *(uint4*)cp = u.q;
    } else {
      float* cp = (float*)C + (long)m*N + n0 + tx*8;
      if (full){
        float4 s0 = {v[0],v[1],v[2],v[3]}, s1 = {v[4],v[5],v[6],v[7]};
        *(float4*)(cp) = s0; *(float4*)(cp+4) = s1;
      } else {
        #pragma unroll
        for (int j=0;j<8;++j) if (n0+tx*8+j < N) cp[j] = v[j];
      }
    }
  }
}

// ---------------- elementwise helpers --------------------------------------
__global__ void mask_bf16(u16* __restrict__ buf, int F, const float* __restrict__ xm){
  long id8 = ((long)blockIdx.x*256 + threadIdx.x)*8;
  int row = (int)(id8 / F);
  int tt = row>>5, b = row&31;
  float m = xm[b*4096 + 4*tt];
  union { uint4 q; u16 s[8]; } u;
  u.q = *(uint4*)(buf + id8);
  #pragma unroll
  for (int j=0;j<8;++j) u.s[j] = f2b(b2f(u.s[j])*m);
  *(uint4*)(buf + id8) = u.q;
}

__global__ void embed_gather(const float* __restrict__ emb, const int* __restrict__ y,
                             float* __restrict__ out){
  int id = blockIdx.x*256 + threadIdx.x;
  int p = id&255, r = id>>8;
  int l = r>>5, b = r&31;
  out[id] = emb[(long)y[b*65 + l]*256 + p];
}

__global__ void zero_f(float* __restrict__ p, int n){
  int id = blockIdx.x*256 + threadIdx.x;
  if (id < n) p[id] = 0.f;
}

__global__ void set_val(float* p, float v){ p[0] = v; }

__global__ void attfea_k(const float* __restrict__ lstms, const float* __restrict__ ctxs,
                         const float* __restrict__ ym, float* __restrict__ attf,
                         u16* __restrict__ attfb){
  long id4 = ((long)blockIdx.x*256 + threadIdx.x)*4;
  int r = (int)(id4>>9); int f = (int)(id4&511);
  int l = r>>5, b = r&31;
  float m = ym[b*65 + l + 1];
  float4 v = (f<256) ? *(const float4*)(lstms + (long)r*256 + f)
                     : *(const float4*)(ctxs  + (long)r*256 + (f-256));
  v.x*=m; v.y*=m; v.z*=m; v.w*=m;
  *(float4*)(attf + id4) = v;
  u16* ob = attfb + id4;
  ob[0]=f2b(v.x); ob[1]=f2b(v.y); ob[2]=f2b(v.z); ob[3]=f2b(v.w);
}

__global__ void dcat_k(const float* __restrict__ attf, const float* __restrict__ dout,
                       const float* __restrict__ ym, float* __restrict__ dcat){
  long id4 = ((long)blockIdx.x*256 + threadIdx.x)*4;
  int r = (int)(id4/768); int f = (int)(id4 - (long)r*768);
  int l = r>>5, b = r&31;
  float m = ym[b*65 + l + 1];
  float4 v = (f<512) ? *(const float4*)(attf + (long)r*512 + f)
                     : *(const float4*)(dout + (long)r*256 + (f-512));
  v.x*=m; v.y*=m; v.z*=m; v.w*=m;
  *(float4*)(dcat + id4) = v;
}

// ---------------- decoder attention step kernels ----------------------------
__global__ __launch_bounds__(256,1) void k1_dec(
  const float* __restrict__ bodyR, float* __restrict__ bodyW,
  const float* __restrict__ epart, const float* __restrict__ Whh,
  const float* __restrict__ Wih, float* __restrict__ cc,
  float* __restrict__ lstms, int s)
{
  __shared__ __align__(16) float vT[512*36];
  __shared__ float gl[32*32];
  const int t = threadIdx.x, wg = blockIdx.x;
  for (int i = t*4; i < 32*512; i += 1024){
    int b = i>>9, k = i&511;
    float4 v = *(const float4*)(bodyR + b*512 + k);
    vT[(k+0)*36+b]=v.x; vT[(k+1)*36+b]=v.y; vT[(k+2)*36+b]=v.z; vT[(k+3)*36+b]=v.w;
  }
  __syncthreads();
  const int c_l = t>>3, bq = t&7;
  const int col = (c_l&3)*256 + wg*8 + (c_l>>2);
  float a0=0.f,a1=0.f,a2=0.f,a3=0.f;
  for (int k=0;k<256;k+=4){
    float4 w = *(const float4*)(Whh + (long)col*256 + k);
    const float* vp = &vT[k*36 + bq*4];
    float4 v0=*(const float4*)(vp), v1=*(const float4*)(vp+36), v2=*(const float4*)(vp+72), v3=*(const float4*)(vp+108);
    a0 += w.x*v0.x + w.y*v1.x + w.z*v2.x + w.w*v3.x;
    a1 += w.x*v0.y + w.y*v1.y + w.z*v2.y + w.w*v3.y;
    a2 += w.x*v0.z + w.y*v1.z + w.z*v2.z + w.w*v3.z;
    a3 += w.x*v0.w + w.y*v1.w + w.z*v2.w + w.w*v3.w;
  }
  for (int k=256;k<512;k+=4){
    float4 w = *(const float4*)(Wih + (long)col*512 + k);
    const float* vp = &vT[k*36 + bq*4];
    float4 v0=*(const float4*)(vp), v1=*(const float4*)(vp+36), v2=*(const float4*)(vp+72), v3=*(const float4*)(vp+108);
    a0 += w.x*v0.x + w.y*v1.x + w.z*v2.x + w.w*v3.x;
    a1 += w.x*v0.y + w.y*v1.y + w.z*v2.y + w.w*v3.y;
    a2 += w.x*v0.z + w.y*v1.z + w.z*v2.z + w.w*v3.z;
    a3 += w.x*v0.w + w.y*v1.w + w.z*v2.w + w.w*v3.w;
  }
  gl[c_l*32+bq*4+0] = a0 + epart[((long)s*32 + bq*4+0)*1024 + col];
  gl[c_l*32+bq*4+1] = a1 + epart[((long)s*32 + bq*4+1)*1024 + col];
  gl[c_l*32+bq*4+2] = a2 + epart[((long)s*32 + bq*4+2)*1024 + col];
  gl[c_l*32+bq*4+3] = a3 + epart[((long)s*32 + bq*4+3)*1024 + col];
  __syncthreads();
  {
    const int u_ = t>>5, b = t&31, ug = wg*8 + u_;
    const float gi=gl[(u_*4+0)*32+b], gf=gl[(u_*4+1)*32+b], gg=gl[(u_*4+2)*32+b], go=gl[(u_*4+3)*32+b];
    float c0 = cc[b*256+ug];
    float c2 = sigm(gf)*c0 + sigm(gi)*tanh_f(gg);
    float h2 = sigm(go)*tanh_f(c2);
    cc[b*256+ug] = c2;
    bodyW[b*512 + ug] = h2;
    lstms[((long)s*32 + b)*256 + ug] = h2;
  }
}

__global__ __launch_bounds__(256,1) void k2_dec(
  const float* __restrict__ bodyW, const float* __restrict__ vW,
  const float* __restrict__ vb, float* __restrict__ state)
{
  __shared__ __align__(16) float hT[256*36];
  const int t = threadIdx.x, wg = blockIdx.x;
  for (int i = t*4; i < 8192; i += 1024){
    int b = i>>8, k = i&255;
    float4 v = *(const float4*)(bodyW + b*512 + k);
    hT[(k+0)*36+b]=v.x; hT[(k+1)*36+b]=v.y; hT[(k+2)*36+b]=v.z; hT[(k+3)*36+b]=v.w;
  }
  __syncthreads();
  const int p = wg*32 + (t>>3), bq = t&7;
  float a0=0.f,a1=0.f,a2=0.f,a3=0.f;
  for (int k=0;k<256;k+=4){
    float4 w = *(const float4*)(vW + (long)p*256 + k);
    const float* vp = &hT[k*36 + bq*4];
    float4 v0=*(const float4*)(vp), v1=*(const float4*)(vp+36), v2=*(const float4*)(vp+72), v3=*(const float4*)(vp+108);
    a0 += w.x*v0.x + w.y*v1.x + w.z*v2.x + w.w*v3.x;
    a1 += w.x*v0.y + w.y*v1.y + w.z*v2.y + w.w*v3.y;
    a2 += w.x*v0.z + w.y*v1.z + w.z*v2.z + w.w*v3.z;
    a3 += w.x*v0.w + w.y*v1.w + w.z*v2.w + w.w*v3.w;
  }
  float bb = vb[p];
  state[(bq*4+0)*256 + p] = a0 + bb;
  state[(bq*4+1)*256 + p] = a1 + bb;
  state[(bq*4+2)*256 + p] = a2 + bb;
  state[(bq*4+3)*256 + p] = a3 + bb;
}

__global__ __launch_bounds__(256,1) void k3_dec(
  const float* __restrict__ state, const u16* __restrict__ atth,
  const float* __restrict__ wav, const float* __restrict__ xm,
  float* __restrict__ sc, float* __restrict__ scm)
{
  __shared__ float st[256], wv[256], red[256];
  const int t = threadIdx.x;
  const int b = blockIdx.x>>2, ch = blockIdx.x&3;
  st[t] = state[b*256 + t];
  wv[t] = wav[t];
  __syncthreads();
  const int tp = ch*256 + t;
  const u16* ap = atth + ((long)tp*32 + b)*256;
  float acc = 0.f;
  for (int p=0;p<256;p+=4){
    ushort4 a = *(const ushort4*)(ap+p);
    acc += wv[p+0]*tanh_f(st[p+0]+b2f(a.x));
    acc += wv[p+1]*tanh_f(st[p+1]+b2f(a.y));
    acc += wv[p+2]*tanh_f(st[p+2]+b2f(a.z));
    acc += wv[p+3]*tanh_f(st[p+3]+b2f(a.w));
  }
  acc += (xm[b*4096 + 4*tp] - 1.0f)*1e30f;
  sc[b*1024 + tp] = acc;
  red[t] = acc;
  __syncthreads();
  for (int o=128;o>0;o>>=1){ if (t<o) red[t]=fmaxf(red[t],red[t+o]); __syncthreads(); }
  if (t==0) scm[b*4+ch] = red[0];
}

__global__ __launch_bounds__(256,1) void k4_dec(
  const float* __restrict__ sc, const float* __restrict__ scm,
  const u16* __restrict__ eout, float* __restrict__ ctxs,
  float* __restrict__ bodyW, int s)
{
  __shared__ float al[1024];
  __shared__ float red[256];
  const int t = threadIdx.x, b = blockIdx.x;
  float m = fmaxf(fmaxf(scm[b*4+0],scm[b*4+1]), fmaxf(scm[b*4+2],scm[b*4+3]));
  float ps = 0.f;
  #pragma unroll
  for (int j=0;j<4;++j){
    int tp = t + j*256;
    float e = __expf(sc[b*1024+tp] - m);
    al[tp] = e; ps += e;
  }
  red[t]=ps; __syncthreads();
  for (int o=128;o>0;o>>=1){ if (t<o) red[t]+=red[t+o]; __syncthreads(); }
  float rinv = 1.0f/red[0];
  float acc = 0.f;
  const u16* ep = eout + b*256 + t;
  for (int tp=0;tp<1024;++tp) acc += al[tp] * b2f(ep[(long)tp*8192]);
  float cv = acc*rinv;
  ctxs[((long)s*32 + b)*256 + t] = cv;
  bodyW[b*512 + 256 + t] = cv;
}

// ---------------- loss ------------------------------------------------------
__global__ __launch_bounds__(256,1) void loss_row(
  const float* __restrict__ logits, const int* __restrict__ y,
  const float* __restrict__ ym, float* __restrict__ rows)
{
  __shared__ float red[256];
  const int r = blockIdx.x, t = threadIdx.x;
  const float* row = logits + (long)r*4235;
  float mx = -3.0e38f;
  for (int i=t;i<4235;i+=256) mx = fmaxf(mx, row[i]);
  red[t]=mx; __syncthreads();
  for (int o=128;o>0;o>>=1){ if (t<o) red[t]=fmaxf(red[t],red[t+o]); __syncthreads(); }
  const float M = red[0];
  __syncthreads();
  float se=0.f, sl=0.f;
  for (int i=t;i<4235;i+=256){ float v=row[i]; se += __expf(v-M); sl += v; }
  red[t]=se; __syncthreads();
  for (int o=128;o>0;o>>=1){ if (t<o) red[t]+=red[t+o]; __syncthreads(); }
  const float SE = red[0];
  __syncthreads();
  red[t]=sl; __syncthreads();
  for (int o=128;o>0;o>>=1){ if (t<o) red[t]+=red[t+o]; __syncthreads(); }
  const float SL = red[0];
  if (t==0){
    const int tt = r>>5, b = r&31;
    const float lse = M + logf(SE);
    const float mk = (ym[b*65 + tt + 1] > 0.f) ? 1.f : 0.f;
    rows[r]        = (4235.0f*lse - SL)*mk;
    rows[2048 + r] = (lse - row[y[b*65 + tt + 1]])*mk;
    rows[4096 + r] = mk;
  }
}

__global__ __launch_bounds__(256,1) void loss_final(const float* __restrict__ rows, float* __restrict__ out){
  __shared__ float red[256];
  const int t = threadIdx.x;
  float s1=0.f,s2=0.f,s3=0.f;
  for (int i=t;i<2048;i+=256){ s1+=rows[i]; s2+=rows[2048+i]; s3+=rows[4096+i]; }
  red[t]=s1; __syncthreads();
  for (int o=128;o>0;o>>=1){ if (t<o) red[t]+=red[t+o]; __syncthreads(); }
  const float S = red[0]; __syncthreads();
  red[t]=s2; __syncthreads();
  for (int o=128;o>0;o>>=1){ if (t<o) red[t]+=red[t+o]; __syncthreads(); }
  const float NL = red[0]; __syncthreads();
  red[t]=s3; __syncthreads();
  for (int o=128;o>0;o>>=1){ if (t<o) red[t]+=red[t+o]; __syncthreads(); }
  const float N = red[0];
  if (t==0){
    float n = (N > 0.f) ? N : 1.f;
    out[0] = (S/n)*(0.1f/4235.0f) + 0.9f*(NL/n);
  }
}

// ---------------- launcher --------------------------------------------------
extern "C" void kernel_launch(void* const* d_in, const int* in_sizes, int n_in,
                              void* d_out, int out_size, void* d_ws, size_t ws_size,
                              hipStream_t stream)
{
  const float* x    = (const float*)d_in[0];
  const float* xm   = (const float*)d_in[1];
  const int*   y    = (const int*)  d_in[2];
  const float* ym   = (const float*)d_in[3];
  const float* l1_Wih=(const float*)d_in[4];  const float* l1_Whh=(const float*)d_in[5];  const float* l1_b=(const float*)d_in[6];
  const float* l2_Wih=(const float*)d_in[7];  const float* l2_Whh=(const float*)d_in[8];  const float* l2_b=(const float*)d_in[9];
  const float* l3_Wih=(const float*)d_in[10]; const float* l3_Whh=(const float*)d_in[11]; const float* l3_b=(const float*)d_in[12];
  const float* bf_Wih=(const float*)d_in[13]; const float* bf_Whh=(const float*)d_in[14]; const float* bf_b=(const float*)d_in[15];
  const float* bb_Wih=(const float*)d_in[16]; const float* bb_Whh=(const float*)d_in[17]; const float* bb_b=(const float*)d_in[18];
  const float* c1_W=(const float*)d_in[19]; const float* c1_b=(const float*)d_in[20];
  const float* c2_W=(const float*)d_in[21]; const float* c2_b=(const float*)d_in[22];
  const float* emb =(const float*)d_in[23];
  const float* att_Wih=(const float*)d_in[24]; const float* att_Whh=(const float*)d_in[25]; const float* att_b=(const float*)d_in[26];
  const float* w_W=(const float*)d_in[27]; const float* w_b=(const float*)d_in[28];
  const float* v_W=(const float*)d_in[29]; const float* v_b=(const float*)d_in[30];
  const float* wav=(const float*)d_in[31];
  const float* dec_Wih=(const float*)d_in[32]; const float* dec_Whh=(const float*)d_in[33]; const float* dec_b=(const float*)d_in[34];
  const float* cls_W=(const float*)d_in[35]; const float* cls_b=(const float*)d_in[36];

  const size_t REQ = 137625600ull; // ~131.3 MiB (verified fit)
  if (ws_size < REQ){
    set_val<<<1,1,0,stream>>>((float*)d_out, -(float)(ws_size>>20));
    return;
  }
  char* ws = (char*)d_ws;
  unsigned* FLAGS = (unsigned*)(ws);            // 512B
  u16* EXU  = (u16*)(ws + 65536);               // 4 x 2 x 32 x 512 bf16 = 256KB
  u16* EXM  = (u16*)(ws + 327680);              // 2 x 32 x 512 = 64KB
  u16* EXD  = (u16*)(ws + 393216);              // 2 x 32 x 256 = 32KB
  u16* XP   = (u16*)(ws + 2097152);             // 32MB
  u16* HS2  = (u16*)(ws + 35651584);            // 32MB (masked h3)
  u16* HSF  = (u16*)(ws + 69206016);            // 32MB (masked bf)
  u16* HSB  = XP;                               // masked bb overlays XP
  u16* C1OUT = HS2;                             // after bb done
  u16* EOUTB = HSF;                             // 16MB (HSF dead after conv1)
  u16* ATTHB = (u16*)(ws + 85983232);           // 16MB
  float* LOGIT = (float*)XP;                    // 34.7MB after conv2
  float* AR    = (float*)(ws + 102760448);      // decoder arena
  float* EMBED = AR;
  float* EPART = EMBED + 524288;
  float* LSTMS = EPART + 2097152;
  float* CTXS  = LSTMS + 524288;
  float* ATTF  = CTXS  + 524288;
  float* DOUT  = ATTF  + 1048576;
  float* DCAT  = DOUT  + 524288;
  float* SC    = DCAT  + 1572864;
  float* SCM   = SC    + 32768;
  float* ROWS  = SCM   + 128;
  float* BODY  = ROWS  + 6144;
  float* CC    = BODY  + 32768;
  float* STATE = CC    + 8192;
  u16*  ATTFB  = (u16*)(STATE + 8192);

  (void)hipMemsetAsync(ws, 0, 4096, stream);

  // ---------------- encoder: phase A (l1,l2,l3,bf pipelined, fence-free) ----
  cvt_x<<<8192,256,0,stream>>>(x, XP);
  PA2 pa;
  pa.L[0] = { l1_Wih, l1_Whh, l1_b, XP,      nullptr, 320, 0 };
  pa.L[1] = { l2_Wih, l2_Whh, l2_b, nullptr, nullptr, 512, 0 };
  pa.L[2] = { l3_Wih, l3_Whh, l3_b, nullptr, HS2,     512, 0 }; // masked out via special path
  pa.L[3] = { bf_Wih, bf_Whh, bf_b, nullptr, HSF,     512, 1 };
  pa.ex = EXU; pa.exm = EXM; pa.xm = xm; pa.flags = FLAGS;
  pa.T = 1024; pa.nwg = 128; pa.rev = 0; pa.base = 0;
  pipe2<4><<<128,256,0,stream>>>(pa);
  // ---------------- encoder: phase B (bb, reverse) --------------------------
  PA2 pb;
  pb.L[0] = { bb_Wih, bb_Whh, bb_b, HS2, HSB, 512, 1 };
  pb.L[1] = pb.L[0]; pb.L[2] = pb.L[0]; pb.L[3] = pb.L[0];
  pb.ex = EXU; pb.exm = EXM; pb.xm = xm; pb.flags = FLAGS;
  pb.T = 1024; pb.nwg = 128; pb.rev = 1; pb.base = 1028;
  pipe2<1><<<128,256,0,stream>>>(pb);
  // conv1 (leaky) on concat [bf|bb], conv2, mask, att_h
  gemm_bias<1,1><<<dim3(256,4),256,0,stream>>>(HSF, 512, HSB, 512, 512,
      c1_W, c1_b, C1OUT, 32768, 512, 1024, 1024, 1);
  gemm_bias<1,1><<<dim3(256,2),256,0,stream>>>(C1OUT, 512, C1OUT, 512, 512,
      c2_W, c2_b, EOUTB, 32768, 256, 512, 512, 0);
  mask_bf16<<<4096,256,0,stream>>>(EOUTB, 256, xm);
  gemm_bias<1,1><<<dim3(256,2),256,0,stream>>>(EOUTB, 256, EOUTB, 256, 256,
      w_W, w_b, ATTHB, 32768, 256, 256, 256, 0);

  // ---------------- decoder -------------------------------------------------
  embed_gather<<<2048,256,0,stream>>>(emb, y, EMBED);
  gemm_bias<0,0><<<dim3(16,8),256,0,stream>>>(EMBED, 256, EMBED, 256, 256,
      att_Wih, att_b, EPART, 2048, 1024, 256, 512, 0);
  zero_f<<<160,256,0,stream>>>(BODY, 40960);
  for (int s=0;s<64;++s){
    float* bodyR = BODY + (s&1)*16384;
    float* bodyW = BODY + ((s+1)&1)*16384;
    k1_dec<<<32,256,0,stream>>>(bodyR, bodyW, EPART, att_Whh, att_Wih, CC, LSTMS, s);
    k2_dec<<<8,256,0,stream>>>(bodyW, v_W, v_b, STATE);
    k3_dec<<<128,256,0,stream>>>(STATE, ATTHB, wav, xm, SC, SCM);
    k4_dec<<<32,256,0,stream>>>(SC, SCM, EOUTB, CTXS, bodyW, s);
  }
  attfea_k<<<1024,256,0,stream>>>(LSTMS, CTXS, ym, ATTF, ATTFB);
  dec_rec2<<<64,256,0,stream>>>(ATTFB, dec_Wih, dec_Whh, dec_b,
      DOUT, EXD, FLAGS, 2053u, 64);
  dcat_k<<<1536,256,0,stream>>>(ATTF, DOUT, ym, DCAT);
  gemm_bias<0,0><<<dim3(16,34),256,0,stream>>>(DCAT, 768, DCAT, 768, 768,
      cls_W, cls_b, LOGIT, 2048, 4235, 768, 768, 0);
  loss_row<<<2048,256,0,stream>>>(LOGIT, y, ym, ROWS);
  loss_final<<<1,256,0,stream>>>(ROWS, (float*)d_out);
}

// Round 9
// 28025.824 us; speedup vs baseline: 9.6120x; 1.0520x over previous
//
#include <hip/hip_runtime.h>
#include <math.h>

#define DEV static __device__ __forceinline__
typedef unsigned short u16;
typedef unsigned int u32;

typedef __attribute__((ext_vector_type(8))) __bf16 bf16x8;
typedef __attribute__((ext_vector_type(4))) float f32x4;

DEV float sigm(float x){ return 1.0f/(1.0f+__expf(-x)); }
DEV float tanh_f(float x){ float e=__expf(2.0f*x); return 1.0f - 2.0f/(e+1.0f); }

DEV float b2f(u16 u){ union {u32 i; float f;} c; c.i = ((u32)u)<<16; return c.f; }
DEV u16 f2b(float f){ union {u32 i; float f;} c; c.f = f; u32 r = (c.i + 0x7FFFu + ((c.i>>16)&1u)) >> 16; return (u16)r; }

// coherent (cross-XCD) dword ops — system scope, relaxed (verified R6)
DEV void cstore(u32* p, u32 v){ __hip_atomic_store(p, v, __ATOMIC_RELAXED, __HIP_MEMORY_SCOPE_SYSTEM); }
DEV u32  cload(const u32* p){ return __hip_atomic_load(p, __ATOMIC_RELAXED, __HIP_MEMORY_SCOPE_SYSTEM); }

// poll all producer flags >= target (no fences) — ALL threads poll (R6-proven)
DEV void waitflags(unsigned* flags, unsigned target, int nwg){
  const int lane = threadIdx.x & 63;
  unsigned long long spin = 0;
  for(;;){
    bool ok = true;
    for (int j=lane; j<nwg; j+=64)
      ok &= ((int)(cload(&flags[j]) - target) >= 0);
    if (__all(ok)) break;
    if (++spin > 2000000ull) break; // safety: garbage instead of hang
    __builtin_amdgcn_s_sleep(1);
  }
}

// ---------------- pipelined persistent MFMA LSTM (H=512) — R6-proven --------
struct PL2 { const float *Wih, *Whh, *bias; const u16* xplain; u16* hout; int kx, maskout; };
struct PA2 {
  PL2 L[4];
  u16* ex;        // [NL][2][32][512] u16
  u16* exm;       // [2][32][512] u16 (masked l3 output, phase A only)
  const float* xm;
  unsigned* flags;
  int T, nwg, rev; unsigned base;
};

template<int NL>
__global__ __launch_bounds__(256,1) void pipe2(PA2 A){
  __shared__ __align__(16) char Vs[65536];
  __shared__ float P[NL*2304];
  __shared__ float cst[NL*128];
  __shared__ float biasl[NL*16];
  const int t = threadIdx.x, wg = blockIdx.x;
  const int u0 = wg*4;
  const int w = t>>6, lane = t&63;
  const int c = lane&15, lg = lane>>4;
  const int r = (c&3)*512 + u0 + (c>>2);
  u32* exu  = (u32*)A.ex;    // [NL][2][32][256]
  u32* exmu = (u32*)A.exm;   // [2][32][256]
  // one-time weight preload (bf16, 32 VGPR per layer per wave)
  bf16x8 bw[NL][8];
  #pragma unroll
  for (int l=0;l<NL;++l){
    const int kx = A.L[l].kx;
    #pragma unroll
    for (int f=0;f<8;++f){
      union { bf16x8 v; u16 s[8]; } u;
      int k8 = w*256 + f*32 + lg*8;
      if (k8 < 512){
        if (k8 < kx){
          const float* p = A.L[l].Wih + (long)r*kx + k8;
          for (int j=0;j<8;++j) u.s[j]=f2b(p[j]);
        } else { for (int j=0;j<8;++j) u.s[j]=0; }
      } else {
        const float* p = A.L[l].Whh + (long)r*512 + (k8-512);
        for (int j=0;j<8;++j) u.s[j]=f2b(p[j]);
      }
      bw[l][f]=u.v;
    }
  }
  if (t<16){
    #pragma unroll
    for (int l=0;l<NL;++l) biasl[l*16+t] = A.L[l].bias[(t&3)*512 + u0 + (t>>2)];
  }
  if (t<128){
    #pragma unroll
    for (int l=0;l<NL;++l) cst[l*128+t]=0.f;
  }
  // zero own EX columns (both parities, all layers + EXM) via coherent stores
  for (int i=t; i<(NL+1)*128; i+=256){
    int reg = i>>7, rem = i&127;
    int par = (rem>>6)&1, b = (rem>>1)&31, j = rem&1;
    u32* p = (reg<NL) ? exu + (reg*2+par)*8192 + b*256 + wg*2 + j
                      : exmu + par*8192 + b*256 + wg*2 + j;
    cstore(p, 0);
  }
  __syncthreads();  // drains vmcnt per wave before barrier -> stores acked
  if (t==0) cstore(&A.flags[wg], A.base+1);
  const int sb = lane>>5;
  const int coffb = (lane&31)*16;
  const int T = A.T;
  for (int s=0; s<T+NL-1; ++s){
    waitflags(A.flags, A.base+s+1, A.nwg);
    const int par = (s-1)&1;
    #pragma unroll
    for (int l=0;l<NL;++l){
      const int sc = s-l;
      if (sc < 0 || sc >= T) continue;
      const int tt = A.rev ? (T-1-sc) : sc;
      // ---- stage own 512B-per-row k-slice into wave-private LDS ----
      const char* base_;
      if (w<2){
        if (l==0)            base_ = (const char*)A.L[0].xplain + (long)tt*32768 + w*512;
        else if (l==3)       base_ = (const char*)A.exm + par*32768 + w*512;
        else                 base_ = (const char*)A.ex + ((l-1)*2+par)*32768 + w*512;
      } else {
        base_ = (const char*)A.ex + (l*2+par)*32768 + (w-2)*512;
      }
      #pragma unroll
      for (int i=0;i<16;++i){
        int b = i*2 + sb;
        const char* src = base_ + b*1024 + (coffb ^ ((b&7)<<4));
        void* ldst = (void*)(Vs + w*16384 + i*1024);
        if (w<2 && l==0) __builtin_amdgcn_global_load_lds((const u32*)src, (u32*)ldst, 16, 0, 0);
        else             __builtin_amdgcn_global_load_lds((const u32*)src, (u32*)ldst, 16, 0, 0x11);
      }
      asm volatile("s_waitcnt vmcnt(0)" ::: "memory");
      // ---- MFMA over own k-slice ----
      f32x4 acc0={0.f,0.f,0.f,0.f}, acc1={0.f,0.f,0.f,0.f};
      const int b1 = c+16;
      #pragma unroll
      for (int f=0;f<8;++f){
        int koff = f*64 + lg*16;
        union { bf16x8 v; uint4 q; } a0, a1;
        a0.q = *(const uint4*)(Vs + w*16384 + c *512 + (koff ^ ((c &7)<<4)));
        a1.q = *(const uint4*)(Vs + w*16384 + b1*512 + (koff ^ ((b1&7)<<4)));
        acc0 = __builtin_amdgcn_mfma_f32_16x16x32_bf16(a0.v, bw[l][f], acc0, 0,0,0);
        acc1 = __builtin_amdgcn_mfma_f32_16x16x32_bf16(a1.v, bw[l][f], acc1, 0,0,0);
      }
      float* pp = &P[l*2304 + (w*16+c)*36 + lg*4];
      *(f32x4*)pp      = acc0;
      *(f32x4*)(pp+16) = acc1;
    }
    __syncthreads();
    if (t<128){
      const int b = t&31, uu = t>>5, wpw = t>>6;
      #pragma unroll
      for (int l=0;l<NL;++l){
        const int sc = s-l;
        if (sc<0 || sc>=T) continue;
        const int tt = A.rev ? (T-1-sc) : sc;
        float g4[4];
        #pragma unroll
        for (int g=0; g<4; ++g){
          int cc = uu*4+g;
          float sum = biasl[l*16+cc];
          #pragma unroll
          for (int ww=0; ww<4; ++ww) sum += P[l*2304 + (ww*16+cc)*36 + b];
          g4[g]=sum;
        }
        float c2 = sigm(g4[1])*cst[l*128+t] + sigm(g4[0])*tanh_f(g4[2]);
        float h2 = sigm(g4[3])*tanh_f(c2);
        cst[l*128+t]=c2;
        // post unmasked h to EX[l][s&1] (packed u32, coherent)
        u32 hv = (u32)f2b(h2);
        u32 ot = (u32)__shfl_xor((int)hv, 32);
        if (lane<32)
          cstore(exu + (l*2+(s&1))*8192 + b*256 + wg*2 + wpw, (hv&0xffffu)|(ot<<16));
        if (NL==4 && l==2){
          float m = A.xm[b*4096 + 4*tt];
          float hm = h2*m;
          u32 hmv = (u32)f2b(hm);
          u32 otm = (u32)__shfl_xor((int)hmv, 32);
          if (lane<32)
            cstore(exmu + (s&1)*8192 + b*256 + wg*2 + wpw, (hmv&0xffffu)|(otm<<16));
          if (A.L[l].hout) A.L[l].hout[((long)tt*32+b)*512 + u0+uu] = f2b(hm);
        } else if (A.L[l].hout){
          float ov = h2;
          if (A.L[l].maskout) ov *= A.xm[b*4096 + 4*tt];
          A.L[l].hout[((long)tt*32+b)*512 + u0+uu] = f2b(ov);
        }
      }
    }
    __syncthreads();
    if (t==0) cstore(&A.flags[wg], A.base+s+2);
  }
}

// ---------------- decoder persistent MFMA LSTM (H=256) — R6-proven ----------
__global__ __launch_bounds__(256,1) void dec_rec2(
    const u16* __restrict__ xin, const float* __restrict__ Wih,
    const float* __restrict__ Whh, const float* __restrict__ bias,
    float* __restrict__ dout, u16* __restrict__ exd,
    unsigned* flags, unsigned base, int T)
{
  __shared__ __align__(16) char Vs[49152];
  __shared__ float P[2304];
  __shared__ float cst[128];
  __shared__ float biasl[16];
  const int t = threadIdx.x, wg = blockIdx.x; // 64 WGs
  const int u0 = wg*4;
  const int w = t>>6, lane = t&63, c = lane&15, lg = lane>>4;
  const int r = (c&3)*256 + u0 + (c>>2);
  u32* exu = (u32*)exd; // [2][32][128]
  const int nf = (w<2) ? 8 : 4;
  bf16x8 bw[8];
  #pragma unroll
  for (int f=0;f<8;++f){
    union { bf16x8 v; u16 s[8]; } u;
    if (f < nf){
      if (w<2){
        const float* p = Wih + (long)r*512 + w*256 + f*32 + lg*8;
        for (int j=0;j<8;++j) u.s[j]=f2b(p[j]);
      } else {
        const float* p = Whh + (long)r*256 + (w-2)*128 + f*32 + lg*8;
        for (int j=0;j<8;++j) u.s[j]=f2b(p[j]);
      }
    } else { for (int j=0;j<8;++j) u.s[j]=0; }
    bw[f]=u.v;
  }
  if (t<16) biasl[t] = bias[(t&3)*256 + u0 + (t>>2)];
  if (t<128) cst[t]=0.f;
  if (t<128){
    int par=(t>>6)&1, b=(t>>1)&31, j=t&1;
    cstore(exu + par*4096 + b*128 + wg*2 + j, 0);
  }
  __syncthreads();
  if (t==0) cstore(&flags[wg], base+1);
  const int waveOff = (w<2) ? w*16384 : 32768 + (w-2)*8192;
  const int NI  = (w<2) ? 16 : 8;
  const int rpi = (w<2) ? 2 : 4;
  const int sb  = (w<2) ? (lane>>5) : (lane>>4);
  const int coffb = (w<2) ? (lane&31)*16 : (lane&15)*16;
  const int rowB = (w<2) ? 512 : 256;
  for (int s=0; s<T; ++s){
    waitflags(flags, base+s+1, 64);
    const int par = (s-1)&1;
    #pragma unroll
    for (int i=0;i<16;++i){
      if (i>=NI) break;
      int b = i*rpi + sb;
      const char* src = (w<2)
        ? (const char*)xin + (long)s*32768 + w*512 + b*1024 + (coffb ^ ((b&7)<<4))
        : (const char*)exd + par*16384 + (w-2)*256 + b*512 + (coffb ^ ((b&7)<<4));
      void* ldst = (void*)(Vs + waveOff + i*1024);
      if (w<2) __builtin_amdgcn_global_load_lds((const u32*)src, (u32*)ldst, 16, 0, 0);
      else     __builtin_amdgcn_global_load_lds((const u32*)src, (u32*)ldst, 16, 0, 0x11);
    }
    asm volatile("s_waitcnt vmcnt(0)" ::: "memory");
    f32x4 acc0={0.f,0.f,0.f,0.f}, acc1={0.f,0.f,0.f,0.f};
    const int b1 = c+16;
    #pragma unroll
    for (int f=0;f<8;++f){
      if (f>=nf) break;
      int koff = f*64 + lg*16;
      union { bf16x8 v; uint4 q; } a0, a1;
      a0.q = *(const uint4*)(Vs + waveOff + c *rowB + (koff ^ ((c &7)<<4)));
      a1.q = *(const uint4*)(Vs + waveOff + b1*rowB + (koff ^ ((b1&7)<<4)));
      acc0 = __builtin_amdgcn_mfma_f32_16x16x32_bf16(a0.v, bw[f], acc0, 0,0,0);
      acc1 = __builtin_amdgcn_mfma_f32_16x16x32_bf16(a1.v, bw[f], acc1, 0,0,0);
    }
    {
      float* pp = &P[(w*16+c)*36 + lg*4];
      *(f32x4*)pp      = acc0;
      *(f32x4*)(pp+16) = acc1;
    }
    __syncthreads();
    if (t<128){
      const int b = t&31, uu = t>>5, wpw = t>>6;
      float g4[4];
      #pragma unroll
      for (int g=0; g<4; ++g){
        int cc = uu*4+g;
        float sum = biasl[cc];
        #pragma unroll
        for (int ww=0; ww<4; ++ww) sum += P[(ww*16+cc)*36 + b];
        g4[g]=sum;
      }
      float c2 = sigm(g4[1])*cst[t] + sigm(g4[0])*tanh_f(g4[2]);
      float h2 = sigm(g4[3])*tanh_f(c2);
      cst[t]=c2;
      u32 hv = (u32)f2b(h2);
      u32 ot = (u32)__shfl_xor((int)hv, 32);
      if (lane<32)
        cstore(exu + (s&1)*4096 + b*128 + wg*2 + wpw, (hv&0xffffu)|(ot<<16));
      dout[((long)s*32+b)*256 + u0+uu] = h2;
    }
    __syncthreads();
    if (t==0) cstore(&flags[wg], base+s+2);
  }
}

// ---------------- x pre-convert: fp32 (B,1024,320) -> bf16 [t*32+b][512] ----
__global__ void cvt_x(const float* __restrict__ x, u16* __restrict__ xp){
  long id8 = ((long)blockIdx.x*256 + threadIdx.x)*8;
  int rr = (int)(id8 >> 9); int k = (int)(id8 & 511);
  int tt = rr >> 5, b = rr & 31;
  union { uint4 q; u16 s[8]; } u;
  if (k < 320){
    const float* p = x + (long)b*327680 + (long)tt*320 + k;
    float4 v0 = *(const float4*)p, v1 = *(const float4*)(p+4);
    u.s[0]=f2b(v0.x); u.s[1]=f2b(v0.y); u.s[2]=f2b(v0.z); u.s[3]=f2b(v0.w);
    u.s[4]=f2b(v1.x); u.s[5]=f2b(v1.y); u.s[6]=f2b(v1.z); u.s[7]=f2b(v1.w);
  } else {
    for (int j=0;j<8;++j) u.s[j]=0;
  }
  *(uint4*)(xp + id8) = u.q;
}

// ---------------- MFMA GEMM: C[m,n] = [A0|A1][m,:K] . W[n,:K] + bias[n] -----
// 64x64 tile/WG, BK=32, 4 waves (wave = 16 m-rows x 4 n-tiles). Fragment
// conventions identical to rec_mfma (m89-verified). ABF: A bf16(u16)/fp32.
// CBF: C bf16/fp32. W always fp32, converted on stage.
template<int ABF, int CBF>
__global__ __launch_bounds__(256,2) void gemm_mfma(
  const void* __restrict__ A0, long lda0, const void* __restrict__ A1, long lda1, int K0,
  const float* __restrict__ W, const float* __restrict__ bias, void* __restrict__ C,
  int M, int N, int K, int ldw, int act)
{
  __shared__ __align__(16) u16 As[64*32];
  __shared__ __align__(16) u16 Bs[64*32];
  const int t = threadIdx.x;
  const int m0 = blockIdx.x*64, n0 = blockIdx.y*64;
  const int w = t>>6, lane = t&63;
  const int al = lane&15, lg = lane>>4;
  f32x4 acc[4];
  #pragma unroll
  for (int i=0;i<4;++i) acc[i] = (f32x4){0.f,0.f,0.f,0.f};
  const int srow = t>>2, kq = t&3;           // staging: row 0..63, k-quarter
  const int spos = (kq ^ (srow&3))*8;        // swizzled 8-elem slot
  for (int k0=0; k0<K; k0+=32){
    { // stage A row m0+srow, k = k0+kq*8 .. +7
      int kk = k0 + kq*8;
      const void* Ab; long lda; int kof;
      if (kk < K0){ Ab=A0; lda=lda0; kof=kk; } else { Ab=A1; lda=lda1; kof=kk-K0; }
      union { uint4 q; u16 s[8]; } u;
      if (ABF){
        u.q = *(const uint4*)((const u16*)Ab + (long)(m0+srow)*lda + kof);
      } else {
        const float* ap = (const float*)Ab + (long)(m0+srow)*lda + kof;
        float4 x0 = *(const float4*)ap, x1 = *(const float4*)(ap+4);
        u.s[0]=f2b(x0.x); u.s[1]=f2b(x0.y); u.s[2]=f2b(x0.z); u.s[3]=f2b(x0.w);
        u.s[4]=f2b(x1.x); u.s[5]=f2b(x1.y); u.s[6]=f2b(x1.z); u.s[7]=f2b(x1.w);
      }
      *(uint4*)&As[srow*32 + spos] = u.q;
    }
    { // stage B: W row n0+srow (fp32 -> bf16), zero-pad n >= N
      int n = n0 + srow;
      union { uint4 q; u16 s[8]; } u;
      if (n < N){
        const float* wp = W + (long)n*ldw + k0 + kq*8;
        float4 y0 = *(const float4*)wp, y1 = *(const float4*)(wp+4);
        u.s[0]=f2b(y0.x); u.s[1]=f2b(y0.y); u.s[2]=f2b(y0.z); u.s[3]=f2b(y0.w);
        u.s[4]=f2b(y1.x); u.s[5]=f2b(y1.y); u.s[6]=f2b(y1.z); u.s[7]=f2b(y1.w);
      } else {
        for (int j=0;j<8;++j) u.s[j]=0;
      }
      *(uint4*)&Bs[srow*32 + spos] = u.q;
    }
    __syncthreads();
    // compute: wave w owns m-rows w*16+al; 4 n-tiles
    union { bf16x8 v; uint4 q; } a;
    a.q = *(const uint4*)&As[(w*16+al)*32 + ((lg ^ (al&3))*8)];
    #pragma unroll
    for (int nt=0; nt<4; ++nt){
      union { bf16x8 v; uint4 q; } b;
      b.q = *(const uint4*)&Bs[(nt*16+al)*32 + ((lg ^ (al&3))*8)];
      acc[nt] = __builtin_amdgcn_mfma_f32_16x16x32_bf16(a.v, b.v, acc[nt], 0,0,0);
    }
    __syncthreads();
  }
  // epilogue: C/D col = lane&15, row = (lane>>4)*4 + j (m89-verified)
  #pragma unroll
  for (int nt=0; nt<4; ++nt){
    int n = n0 + nt*16 + al;
    if (n >= N) continue;
    float bv = bias[n];
    #pragma unroll
    for (int j=0;j<4;++j){
      int m = m0 + w*16 + lg*4 + j;
      float v = acc[nt][j] + bv;
      if (act) v = (v > 0.f) ? v : 0.1f*v;
      if (CBF) ((u16*)C)[(long)m*N + n] = f2b(v);
      else     ((float*)C)[(long)m*N + n] = v;
    }
  }
}

// ---------------- fp32 SIMD GEMM (kept for epart) ---------------------------
template<int ABF, int CBF>
__global__ __launch_bounds__(256,1) void gemm_bias(
  const void* __restrict__ A0, long lda0, const void* __restrict__ A1, long lda1, int K0,
  const float* __restrict__ W, const float* __restrict__ bias, void* __restrict__ C,
  int M, int N, int K, int ldw, int act)
{
  __shared__ __align__(16) float As[16*132];
  __shared__ __align__(16) float Bs[16*132];
  const int t = threadIdx.x;
  const int m0 = blockIdx.x*128, n0 = blockIdx.y*128;
  const int tx = t&15, ty = t>>4;
  float acc[8][8];
  for (int i=0;i<8;++i)
    for (int j=0;j<8;++j) acc[i][j]=0.f;
  const int row = t>>1, seg = t&1;
  for (int k0=0;k0<K;k0+=16){
    {
      const int kk = k0 + seg*8;
      const void* Ab; long lda; int kof;
      if (kk < K0){ Ab=A0; lda=lda0; kof=kk; } else { Ab=A1; lda=lda1; kof=kk-K0; }
      float v[8];
      if (ABF){
        const u16* ap = (const u16*)Ab + (long)(m0+row)*lda + kof;
        union { uint4 q; u16 s[8]; } u; u.q = *(const uint4*)ap;
        #pragma unroll
        for (int j=0;j<8;++j) v[j]=b2f(u.s[j]);
      } else {
        const float* ap = (const float*)Ab + (long)(m0+row)*lda + kof;
        float4 x0 = *(const float4*)(ap);
        float4 x1 = *(const float4*)(ap+4);
        v[0]=x0.x;v[1]=x0.y;v[2]=x0.z;v[3]=x0.w;v[4]=x1.x;v[5]=x1.y;v[6]=x1.z;v[7]=x1.w;
      }
      const int kb = seg*8;
      #pragma unroll
      for (int j=0;j<8;++j) As[(kb+j)*132+row]=v[j];
    }
    {
      const int n = n0 + row;
      float4 y0 = {0,0,0,0}, y1 = {0,0,0,0};
      if (n < N){
        const float* wp = W + (long)n*ldw + k0 + seg*8;
        y0 = *(const float4*)(wp); y1 = *(const float4*)(wp+4);
      }
      const int kb = seg*8;
      Bs[(kb+0)*132+row]=y0.x; Bs[(kb+1)*132+row]=y0.y; Bs[(kb+2)*132+row]=y0.z; Bs[(kb+3)*132+row]=y0.w;
      Bs[(kb+4)*132+row]=y1.x; Bs[(kb+5)*132+row]=y1.y; Bs[(kb+6)*132+row]=y1.z; Bs[(kb+7)*132+row]=y1.w;
    }
    __syncthreads();
    #pragma unroll
    for (int k=0;k<16;++k){
      const float* ap = &As[k*132 + ty*8];
      const float* bp = &Bs[k*132 + tx*8];
      float4 A0v=*(const float4*)(ap), A1v=*(const float4*)(ap+4);
      float4 B0v=*(const float4*)(bp), B1v=*(const float4*)(bp+4);
      float av[8]={A0v.x,A0v.y,A0v.z,A0v.w,A1v.x,A1v.y,A1v.z,A1v.w};
      float bv[8]={B0v.x,B0v.y,B0v.z,B0v.w,B1v.x,B1v.y,B1v.z,B1v.w};
      #pragma unroll
      for (int i=0;i<8;++i){
        #pragma unroll
        for (int j=0;j<8;++j) acc[i][j] += av[i]*bv[j];
      }
    }
    __syncthreads();
  }
  float bv[8];
  #pragma unroll
  for (int j=0;j<8;++j){ int n = n0+tx*8+j; bv[j] = (n<N)? bias[n] : 0.f; }
  const bool full = (n0+128 <= N);
  #pragma unroll
  for (int i=0;i<8;++i){
    const int m = m0 + ty*8 + i;
    float v[8];
    #pragma unroll
    for (int j=0;j<8;++j){
      float x = acc[i][j] + bv[j];
      if (act) x = (x > 0.f) ? x : 0.1f*x;
      v[j] = x;
    }
    if (CBF){
      u16* cp = (u16*)C + (long)m*N + n0 + tx*8;
      union { uint4 q; u16 s[8]; } u;
      #pragma unroll
      for (int j=0;j<8;++j) u.s[j]=f2b(v[j]);
      *(uint4*)cp = u.q;
    } else {
      float* cp = (float*)C + (long)m*N + n0 + tx*8;
      if (full){
        float4 s0 = {v[0],v[1],v[2],v[3]}, s1 = {v[4],v[5],v[6],v[7]};
        *(float4*)(cp) = s0; *(float4*)(cp+4) = s1;
      } else {
        #pragma unroll
        for (int j=0;j<8;++j) if (n0+tx*8+j < N) cp[j] = v[j];
      }
    }
  }
}

// ---------------- elementwise helpers --------------------------------------
__global__ void mask_bf16(u16* __restrict__ buf, int F, const float* __restrict__ xm){
  long id8 = ((long)blockIdx.x*256 + threadIdx.x)*8;
  int row = (int)(id8 / F);
  int tt = row>>5, b = row&31;
  float m = xm[b*4096 + 4*tt];
  union { uint4 q; u16 s[8]; } u;
  u.q = *(uint4*)(buf + id8);
  #pragma unroll
  for (int j=0;j<8;++j) u.s[j] = f2b(b2f(u.s[j])*m);
  *(uint4*)(buf + id8) = u.q;
}

__global__ void embed_gather(const float* __restrict__ emb, const int* __restrict__ y,
                             float* __restrict__ out){
  int id = blockIdx.x*256 + threadIdx.x;
  int p = id&255, r = id>>8;
  int l = r>>5, b = r&31;
  out[id] = emb[(long)y[b*65 + l]*256 + p];
}

__global__ void zero_f(float* __restrict__ p, int n){
  int id = blockIdx.x*256 + threadIdx.x;
  if (id < n) p[id] = 0.f;
}

__global__ void set_val(float* p, float v){ p[0] = v; }

__global__ void attfea_k(const float* __restrict__ lstms, const float* __restrict__ ctxs,
                         const float* __restrict__ ym, float* __restrict__ attf,
                         u16* __restrict__ attfb){
  long id4 = ((long)blockIdx.x*256 + threadIdx.x)*4;
  int r = (int)(id4>>9); int f = (int)(id4&511);
  int l = r>>5, b = r&31;
  float m = ym[b*65 + l + 1];
  float4 v = (f<256) ? *(const float4*)(lstms + (long)r*256 + f)
                     : *(const float4*)(ctxs  + (long)r*256 + (f-256));
  v.x*=m; v.y*=m; v.z*=m; v.w*=m;
  *(float4*)(attf + id4) = v;
  u16* ob = attfb + id4;
  ob[0]=f2b(v.x); ob[1]=f2b(v.y); ob[2]=f2b(v.z); ob[3]=f2b(v.w);
}

__global__ void dcat_k(const float* __restrict__ attf, const float* __restrict__ dout,
                       const float* __restrict__ ym, float* __restrict__ dcat){
  long id4 = ((long)blockIdx.x*256 + threadIdx.x)*4;
  int r = (int)(id4/768); int f = (int)(id4 - (long)r*768);
  int l = r>>5, b = r&31;
  float m = ym[b*65 + l + 1];
  float4 v = (f<512) ? *(const float4*)(attf + (long)r*512 + f)
                     : *(const float4*)(dout + (long)r*256 + (f-512));
  v.x*=m; v.y*=m; v.z*=m; v.w*=m;
  *(float4*)(dcat + id4) = v;
}

// ---------------- decoder attention step kernels ----------------------------
__global__ __launch_bounds__(256,1) void k1_dec(
  const float* __restrict__ bodyR, float* __restrict__ bodyW,
  const float* __restrict__ epart, const float* __restrict__ Whh,
  const float* __restrict__ Wih, float* __restrict__ cc,
  float* __restrict__ lstms, int s)
{
  __shared__ __align__(16) float vT[512*36];
  __shared__ float gl[32*32];
  const int t = threadIdx.x, wg = blockIdx.x;
  for (int i = t*4; i < 32*512; i += 1024){
    int b = i>>9, k = i&511;
    float4 v = *(const float4*)(bodyR + b*512 + k);
    vT[(k+0)*36+b]=v.x; vT[(k+1)*36+b]=v.y; vT[(k+2)*36+b]=v.z; vT[(k+3)*36+b]=v.w;
  }
  __syncthreads();
  const int c_l = t>>3, bq = t&7;
  const int col = (c_l&3)*256 + wg*8 + (c_l>>2);
  float a0=0.f,a1=0.f,a2=0.f,a3=0.f;
  for (int k=0;k<256;k+=4){
    float4 w = *(const float4*)(Whh + (long)col*256 + k);
    const float* vp = &vT[k*36 + bq*4];
    float4 v0=*(const float4*)(vp), v1=*(const float4*)(vp+36), v2=*(const float4*)(vp+72), v3=*(const float4*)(vp+108);
    a0 += w.x*v0.x + w.y*v1.x + w.z*v2.x + w.w*v3.x;
    a1 += w.x*v0.y + w.y*v1.y + w.z*v2.y + w.w*v3.y;
    a2 += w.x*v0.z + w.y*v1.z + w.z*v2.z + w.w*v3.z;
    a3 += w.x*v0.w + w.y*v1.w + w.z*v2.w + w.w*v3.w;
  }
  for (int k=256;k<512;k+=4){
    float4 w = *(const float4*)(Wih + (long)col*512 + k);
    const float* vp = &vT[k*36 + bq*4];
    float4 v0=*(const float4*)(vp), v1=*(const float4*)(vp+36), v2=*(const float4*)(vp+72), v3=*(const float4*)(vp+108);
    a0 += w.x*v0.x + w.y*v1.x + w.z*v2.x + w.w*v3.x;
    a1 += w.x*v0.y + w.y*v1.y + w.z*v2.y + w.w*v3.y;
    a2 += w.x*v0.z + w.y*v1.z + w.z*v2.z + w.w*v3.z;
    a3 += w.x*v0.w + w.y*v1.w + w.z*v2.w + w.w*v3.w;
  }
  gl[c_l*32+bq*4+0] = a0 + epart[((long)s*32 + bq*4+0)*1024 + col];
  gl[c_l*32+bq*4+1] = a1 + epart[((long)s*32 + bq*4+1)*1024 + col];
  gl[c_l*32+bq*4+2] = a2 + epart[((long)s*32 + bq*4+2)*1024 + col];
  gl[c_l*32+bq*4+3] = a3 + epart[((long)s*32 + bq*4+3)*1024 + col];
  __syncthreads();
  {
    const int u_ = t>>5, b = t&31, ug = wg*8 + u_;
    const float gi=gl[(u_*4+0)*32+b], gf=gl[(u_*4+1)*32+b], gg=gl[(u_*4+2)*32+b], go=gl[(u_*4+3)*32+b];
    float c0 = cc[b*256+ug];
    float c2 = sigm(gf)*c0 + sigm(gi)*tanh_f(gg);
    float h2 = sigm(go)*tanh_f(c2);
    cc[b*256+ug] = c2;
    bodyW[b*512 + ug] = h2;
    lstms[((long)s*32 + b)*256 + ug] = h2;
  }
}

__global__ __launch_bounds__(256,1) void k2_dec(
  const float* __restrict__ bodyW, const float* __restrict__ vW,
  const float* __restrict__ vb, float* __restrict__ state)
{
  __shared__ __align__(16) float hT[256*36];
  const int t = threadIdx.x, wg = blockIdx.x;
  for (int i = t*4; i < 8192; i += 1024){
    int b = i>>8, k = i&255;
    float4 v = *(const float4*)(bodyW + b*512 + k);
    hT[(k+0)*36+b]=v.x; hT[(k+1)*36+b]=v.y; hT[(k+2)*36+b]=v.z; hT[(k+3)*36+b]=v.w;
  }
  __syncthreads();
  const int p = wg*32 + (t>>3), bq = t&7;
  float a0=0.f,a1=0.f,a2=0.f,a3=0.f;
  for (int k=0;k<256;k+=4){
    float4 w = *(const float4*)(vW + (long)p*256 + k);
    const float* vp = &hT[k*36 + bq*4];
    float4 v0=*(const float4*)(vp), v1=*(const float4*)(vp+36), v2=*(const float4*)(vp+72), v3=*(const float4*)(vp+108);
    a0 += w.x*v0.x + w.y*v1.x + w.z*v2.x + w.w*v3.x;
    a1 += w.x*v0.y + w.y*v1.y + w.z*v2.y + w.w*v3.y;
    a2 += w.x*v0.z + w.y*v1.z + w.z*v2.z + w.w*v3.z;
    a3 += w.x*v0.w + w.y*v1.w + w.z*v2.w + w.w*v3.w;
  }
  float bb = vb[p];
  state[(bq*4+0)*256 + p] = a0 + bb;
  state[(bq*4+1)*256 + p] = a1 + bb;
  state[(bq*4+2)*256 + p] = a2 + bb;
  state[(bq*4+3)*256 + p] = a3 + bb;
}

__global__ __launch_bounds__(256,1) void k3_dec(
  const float* __restrict__ state, const u16* __restrict__ atth,
  const float* __restrict__ wav, const float* __restrict__ xm,
  float* __restrict__ sc, float* __restrict__ scm)
{
  __shared__ float st[256], wv[256], red[256];
  const int t = threadIdx.x;
  const int b = blockIdx.x>>2, ch = blockIdx.x&3;
  st[t] = state[b*256 + t];
  wv[t] = wav[t];
  __syncthreads();
  const int tp = ch*256 + t;
  const u16* ap = atth + ((long)tp*32 + b)*256;
  float acc = 0.f;
  for (int p=0;p<256;p+=4){
    ushort4 a = *(const ushort4*)(ap+p);
    acc += wv[p+0]*tanh_f(st[p+0]+b2f(a.x));
    acc += wv[p+1]*tanh_f(st[p+1]+b2f(a.y));
    acc += wv[p+2]*tanh_f(st[p+2]+b2f(a.z));
    acc += wv[p+3]*tanh_f(st[p+3]+b2f(a.w));
  }
  acc += (xm[b*4096 + 4*tp] - 1.0f)*1e30f;
  sc[b*1024 + tp] = acc;
  red[t] = acc;
  __syncthreads();
  for (int o=128;o>0;o>>=1){ if (t<o) red[t]=fmaxf(red[t],red[t+o]); __syncthreads(); }
  if (t==0) scm[b*4+ch] = red[0];
}

__global__ __launch_bounds__(256,1) void k4_dec(
  const float* __restrict__ sc, const float* __restrict__ scm,
  const u16* __restrict__ eout, float* __restrict__ ctxs,
  float* __restrict__ bodyW, int s)
{
  __shared__ float al[1024];
  __shared__ float red[256];
  const int t = threadIdx.x, b = blockIdx.x;
  float m = fmaxf(fmaxf(scm[b*4+0],scm[b*4+1]), fmaxf(scm[b*4+2],scm[b*4+3]));
  float ps = 0.f;
  #pragma unroll
  for (int j=0;j<4;++j){
    int tp = t + j*256;
    float e = __expf(sc[b*1024+tp] - m);
    al[tp] = e; ps += e;
  }
  red[t]=ps; __syncthreads();
  for (int o=128;o>0;o>>=1){ if (t<o) red[t]+=red[t+o]; __syncthreads(); }
  float rinv = 1.0f/red[0];
  float acc = 0.f;
  const u16* ep = eout + b*256 + t;
  for (int tp=0;tp<1024;++tp) acc += al[tp] * b2f(ep[(long)tp*8192]);
  float cv = acc*rinv;
  ctxs[((long)s*32 + b)*256 + t] = cv;
  bodyW[b*512 + 256 + t] = cv;
}

// ---------------- loss ------------------------------------------------------
__global__ __launch_bounds__(256,1) void loss_row(
  const float* __restrict__ logits, const int* __restrict__ y,
  const float* __restrict__ ym, float* __restrict__ rows)
{
  __shared__ float red[256];
  const int r = blockIdx.x, t = threadIdx.x;
  const float* row = logits + (long)r*4235;
  float mx = -3.0e38f;
  for (int i=t;i<4235;i+=256) mx = fmaxf(mx, row[i]);
  red[t]=mx; __syncthreads();
  for (int o=128;o>0;o>>=1){ if (t<o) red[t]=fmaxf(red[t],red[t+o]); __syncthreads(); }
  const float M = red[0];
  __syncthreads();
  float se=0.f, sl=0.f;
  for (int i=t;i<4235;i+=256){ float v=row[i]; se += __expf(v-M); sl += v; }
  red[t]=se; __syncthreads();
  for (int o=128;o>0;o>>=1){ if (t<o) red[t]+=red[t+o]; __syncthreads(); }
  const float SE = red[0];
  __syncthreads();
  red[t]=sl; __syncthreads();
  for (int o=128;o>0;o>>=1){ if (t<o) red[t]+=red[t+o]; __syncthreads(); }
  const float SL = red[0];
  if (t==0){
    const int tt = r>>5, b = r&31;
    const float lse = M + logf(SE);
    const float mk = (ym[b*65 + tt + 1] > 0.f) ? 1.f : 0.f;
    rows[r]        = (4235.0f*lse - SL)*mk;
    rows[2048 + r] = (lse - row[y[b*65 + tt + 1]])*mk;
    rows[4096 + r] = mk;
  }
}

__global__ __launch_bounds__(256,1) void loss_final(const float* __restrict__ rows, float* __restrict__ out){
  __shared__ float red[256];
  const int t = threadIdx.x;
  float s1=0.f,s2=0.f,s3=0.f;
  for (int i=t;i<2048;i+=256){ s1+=rows[i]; s2+=rows[2048+i]; s3+=rows[4096+i]; }
  red[t]=s1; __syncthreads();
  for (int o=128;o>0;o>>=1){ if (t<o) red[t]+=red[t+o]; __syncthreads(); }
  const float S = red[0]; __syncthreads();
  red[t]=s2; __syncthreads();
  for (int o=128;o>0;o>>=1){ if (t<o) red[t]+=red[t+o]; __syncthreads(); }
  const float NL = red[0]; __syncthreads();
  red[t]=s3; __syncthreads();
  for (int o=128;o>0;o>>=1){ if (t<o) red[t]+=red[t+o]; __syncthreads(); }
  const float N = red[0];
  if (t==0){
    float n = (N > 0.f) ? N : 1.f;
    out[0] = (S/n)*(0.1f/4235.0f) + 0.9f*(NL/n);
  }
}

// ---------------- launcher --------------------------------------------------
extern "C" void kernel_launch(void* const* d_in, const int* in_sizes, int n_in,
                              void* d_out, int out_size, void* d_ws, size_t ws_size,
                              hipStream_t stream)
{
  const float* x    = (const float*)d_in[0];
  const float* xm   = (const float*)d_in[1];
  const int*   y    = (const int*)  d_in[2];
  const float* ym   = (const float*)d_in[3];
  const float* l1_Wih=(const float*)d_in[4];  const float* l1_Whh=(const float*)d_in[5];  const float* l1_b=(const float*)d_in[6];
  const float* l2_Wih=(const float*)d_in[7];  const float* l2_Whh=(const float*)d_in[8];  const float* l2_b=(const float*)d_in[9];
  const float* l3_Wih=(const float*)d_in[10]; const float* l3_Whh=(const float*)d_in[11]; const float* l3_b=(const float*)d_in[12];
  const float* bf_Wih=(const float*)d_in[13]; const float* bf_Whh=(const float*)d_in[14]; const float* bf_b=(const float*)d_in[15];
  const float* bb_Wih=(const float*)d_in[16]; const float* bb_Whh=(const float*)d_in[17]; const float* bb_b=(const float*)d_in[18];
  const float* c1_W=(const float*)d_in[19]; const float* c1_b=(const float*)d_in[20];
  const float* c2_W=(const float*)d_in[21]; const float* c2_b=(const float*)d_in[22];
  const float* emb =(const float*)d_in[23];
  const float* att_Wih=(const float*)d_in[24]; const float* att_Whh=(const float*)d_in[25]; const float* att_b=(const float*)d_in[26];
  const float* w_W=(const float*)d_in[27]; const float* w_b=(const float*)d_in[28];
  const float* v_W=(const float*)d_in[29]; const float* v_b=(const float*)d_in[30];
  const float* wav=(const float*)d_in[31];
  const float* dec_Wih=(const float*)d_in[32]; const float* dec_Whh=(const float*)d_in[33]; const float* dec_b=(const float*)d_in[34];
  const float* cls_W=(const float*)d_in[35]; const float* cls_b=(const float*)d_in[36];

  const size_t REQ = 137625600ull; // ~131.3 MiB (verified fit)
  if (ws_size < REQ){
    set_val<<<1,1,0,stream>>>((float*)d_out, -(float)(ws_size>>20));
    return;
  }
  char* ws = (char*)d_ws;
  unsigned* FLAGS = (unsigned*)(ws);            // 512B (dense, R6 layout)
  u16* EXU  = (u16*)(ws + 65536);               // 4x2x32x512 = 256KB
  u16* EXM  = (u16*)(ws + 327680);              // 2x32x512 = 64KB
  u16* EXD  = (u16*)(ws + 393216);              // 2x32x256 = 32KB
  u16* XP   = (u16*)(ws + 2097152);             // 32MB
  u16* HS2  = (u16*)(ws + 35651584);            // 32MB (masked h3)
  u16* HSF  = (u16*)(ws + 69206016);            // 32MB (masked bf)
  u16* HSB  = XP;                               // masked bb overlays XP
  u16* C1OUT = HS2;                             // after bb done
  u16* EOUTB = HSF;                             // 16MB (HSF dead after conv1)
  u16* ATTHB = (u16*)(ws + 85983232);           // 16MB
  float* LOGIT = (float*)XP;                    // after conv2
  float* AR    = (float*)(ws + 102760448);      // decoder arena
  float* EMBED = AR;
  float* EPART = EMBED + 524288;
  float* LSTMS = EPART + 2097152;
  float* CTXS  = LSTMS + 524288;
  float* ATTF  = CTXS  + 524288;
  float* DOUT  = ATTF  + 1048576;
  float* DCAT  = DOUT  + 524288;
  float* SC    = DCAT  + 1572864;
  float* SCM   = SC    + 32768;
  float* ROWS  = SCM   + 128;
  float* BODY  = ROWS  + 6144;
  float* CC    = BODY  + 32768;
  float* STATE = CC    + 8192;
  u16*  ATTFB  = (u16*)(STATE + 8192);

  (void)hipMemsetAsync(ws, 0, 4096, stream);

  // ---------------- encoder: phase A (l1,l2,l3,bf pipelined, fence-free) ----
  cvt_x<<<8192,256,0,stream>>>(x, XP);
  PA2 pa;
  pa.L[0] = { l1_Wih, l1_Whh, l1_b, XP,      nullptr, 320, 0 };
  pa.L[1] = { l2_Wih, l2_Whh, l2_b, nullptr, nullptr, 512, 0 };
  pa.L[2] = { l3_Wih, l3_Whh, l3_b, nullptr, HS2,     512, 0 };
  pa.L[3] = { bf_Wih, bf_Whh, bf_b, nullptr, HSF,     512, 1 };
  pa.ex = EXU; pa.exm = EXM; pa.xm = xm; pa.flags = FLAGS;
  pa.T = 1024; pa.nwg = 128; pa.rev = 0; pa.base = 0;
  pipe2<4><<<128,256,0,stream>>>(pa);
  // ---------------- encoder: phase B (bb, reverse) --------------------------
  PA2 pb;
  pb.L[0] = { bb_Wih, bb_Whh, bb_b, HS2, HSB, 512, 1 };
  pb.L[1] = pb.L[0]; pb.L[2] = pb.L[0]; pb.L[3] = pb.L[0];
  pb.ex = EXU; pb.exm = EXM; pb.xm = xm; pb.flags = FLAGS;
  pb.T = 1024; pb.nwg = 128; pb.rev = 1; pb.base = 1028;
  pipe2<1><<<128,256,0,stream>>>(pb);
  // conv1 (leaky) on concat [bf|bb], conv2, mask, att_h — MFMA GEMMs
  gemm_mfma<1,1><<<dim3(512,8),256,0,stream>>>(HSF, 512, HSB, 512, 512,
      c1_W, c1_b, C1OUT, 32768, 512, 1024, 1024, 1);
  gemm_mfma<1,1><<<dim3(512,4),256,0,stream>>>(C1OUT, 512, C1OUT, 512, 512,
      c2_W, c2_b, EOUTB, 32768, 256, 512, 512, 0);
  mask_bf16<<<4096,256,0,stream>>>(EOUTB, 256, xm);
  gemm_mfma<1,1><<<dim3(512,4),256,0,stream>>>(EOUTB, 256, EOUTB, 256, 256,
      w_W, w_b, ATTHB, 32768, 256, 256, 256, 0);

  // ---------------- decoder -------------------------------------------------
  embed_gather<<<2048,256,0,stream>>>(emb, y, EMBED);
  gemm_bias<0,0><<<dim3(16,8),256,0,stream>>>(EMBED, 256, EMBED, 256, 256,
      att_Wih, att_b, EPART, 2048, 1024, 256, 512, 0);
  zero_f<<<160,256,0,stream>>>(BODY, 40960);
  for (int s=0;s<64;++s){
    float* bodyR = BODY + (s&1)*16384;
    float* bodyW = BODY + ((s+1)&1)*16384;
    k1_dec<<<32,256,0,stream>>>(bodyR, bodyW, EPART, att_Whh, att_Wih, CC, LSTMS, s);
    k2_dec<<<8,256,0,stream>>>(bodyW, v_W, v_b, STATE);
    k3_dec<<<128,256,0,stream>>>(STATE, ATTHB, wav, xm, SC, SCM);
    k4_dec<<<32,256,0,stream>>>(SC, SCM, EOUTB, CTXS, bodyW, s);
  }
  attfea_k<<<1024,256,0,stream>>>(LSTMS, CTXS, ym, ATTF, ATTFB);
  dec_rec2<<<64,256,0,stream>>>(ATTFB, dec_Wih, dec_Whh, dec_b,
      DOUT, EXD, FLAGS, 2053u, 64);
  dcat_k<<<1536,256,0,stream>>>(ATTF, DOUT, ym, DCAT);
  gemm_mfma<0,0><<<dim3(32,67),256,0,stream>>>(DCAT, 768, DCAT, 768, 768,
      cls_W, cls_b, LOGIT, 2048, 4235, 768, 768, 0);
  loss_row<<<2048,256,0,stream>>>(LOGIT, y, ym, ROWS);
  loss_final<<<1,256,0,stream>>>(ROWS, (float*)d_out);
}

// Round 10
// 23354.048 us; speedup vs baseline: 11.5348x; 1.2000x over previous
//
#include <hip/hip_runtime.h>
#include <math.h>

#define DEV static __device__ __forceinline__
typedef unsigned short u16;
typedef unsigned int u32;

typedef __attribute__((ext_vector_type(8))) __bf16 bf16x8;
typedef __attribute__((ext_vector_type(4))) float f32x4;

DEV float sigm(float x){ return 1.0f/(1.0f+__expf(-x)); }
DEV float tanh_f(float x){ float e=__expf(2.0f*x); return 1.0f - 2.0f/(e+1.0f); }

DEV float b2f(u16 u){ union {u32 i; float f;} c; c.i = ((u32)u)<<16; return c.f; }
DEV u16 f2b(float f){ union {u32 i; float f;} c; c.f = f; u32 r = (c.i + 0x7FFFu + ((c.i>>16)&1u)) >> 16; return (u16)r; }

// coherent (cross-XCD) dword ops — system scope, relaxed (verified R6)
DEV void cstore(u32* p, u32 v){ __hip_atomic_store(p, v, __ATOMIC_RELAXED, __HIP_MEMORY_SCOPE_SYSTEM); }
DEV u32  cload(const u32* p){ return __hip_atomic_load(p, __ATOMIC_RELAXED, __HIP_MEMORY_SCOPE_SYSTEM); }

// poll all producer flags >= target (no fences) — ALL threads poll (R6-proven)
DEV void waitflags(unsigned* flags, unsigned target, int nwg){
  const int lane = threadIdx.x & 63;
  unsigned long long spin = 0;
  for(;;){
    bool ok = true;
    for (int j=lane; j<nwg; j+=64)
      ok &= ((int)(cload(&flags[j]) - target) >= 0);
    if (__all(ok)) break;
    if (++spin > 2000000ull) break; // safety: garbage instead of hang
    __builtin_amdgcn_s_sleep(1);
  }
}

// ---------------- pipelined persistent MFMA LSTM (H=512) --------------------
// NEW (R10): 128 WGs = 2 batch-halves x 64 col-groups; WG owns 16 rows x 8
// units. Layer staging double-buffered with counted vmcnt(8) so only S0's
// latency is exposed. Cross-WG sync protocol byte-identical to R6/R9.
struct PL2 { const float *Wih, *Whh, *bias; const u16* xplain; u16* hout; int kx, maskout; };
struct PA2 {
  PL2 L[4];
  u16* ex;        // [NL][2][32][512] u16
  u16* exm;       // [2][32][512] u16 (masked l3 output, phase A only)
  const float* xm;
  unsigned* flags;
  int T, nwg, rev; unsigned base;
};

#define VWAIT(N) { asm volatile("s_waitcnt vmcnt(" #N ")" ::: "memory"); __builtin_amdgcn_sched_barrier(0); }

#define STAGE(LL, Q, TT) { \
  const char* base_; int coh_; \
  if (w<2){ \
    if ((LL)==0){ base_=(const char*)A.L[0].xplain + ((long)(TT)*32)*1024 + w*512; coh_=0; } \
    else if (NL==4 && (LL)==3){ base_=(const char*)A.exm + (long)par*32768 + w*512; coh_=1; } \
    else { base_=(const char*)A.ex + (long)(((LL)-1)*2+par)*32768 + w*512; coh_=1; } \
  } else { base_=(const char*)A.ex + (long)((LL)*2+par)*32768 + (w-2)*512; coh_=1; } \
  _Pragma("unroll") \
  for (int i_=0;i_<8;++i_){ \
    int rl_=i_*2+(lane>>5); \
    int b_=bh*16+rl_; \
    const char* src_=base_ + (long)b_*1024 + (((lane&31)*16) ^ ((rl_&7)<<4)); \
    char* dst_=Vs + (Q)*32768 + w*8192 + i_*1024 + lane*16; \
    if (coh_) __builtin_amdgcn_global_load_lds((const u32*)src_,(u32*)dst_,16,0,0x11); \
    else      __builtin_amdgcn_global_load_lds((const u32*)src_,(u32*)dst_,16,0,0); \
  } }

#define DOMFMA(LL, Q) { \
  const char* vb_=Vs + (Q)*32768 + w*8192; \
  const int sw_=(cl&7)<<4; \
  f32x4 a0_={0.f,0.f,0.f,0.f}, a1_={0.f,0.f,0.f,0.f}; \
  _Pragma("unroll") \
  for (int f_=0;f_<8;++f_){ \
    union{ bf16x8 v; uint4 q; } aa_; \
    aa_.q = *(const uint4*)(vb_ + cl*512 + ((f_*64+lg*16) ^ sw_)); \
    a0_=__builtin_amdgcn_mfma_f32_16x16x32_bf16(aa_.v, bw[LL][0][f_], a0_,0,0,0); \
    a1_=__builtin_amdgcn_mfma_f32_16x16x32_bf16(aa_.v, bw[LL][1][f_], a1_,0,0,0); \
  } \
  *(f32x4*)&P[(LL)*2560 + (w*32 + cl)*20 + lg*4] = a0_; \
  *(f32x4*)&P[(LL)*2560 + (w*32 + 16 + cl)*20 + lg*4] = a1_; \
  __builtin_amdgcn_sched_barrier(0); }

template<int NL>
__global__ __launch_bounds__(256,1) void pipe2(PA2 A){
  __shared__ __align__(16) char Vs[65536];      // 2 bufs x 4 waves x 8KB
  __shared__ float P[NL*2560];                  // [l][w][32 cols][20]
  const int t = threadIdx.x, wg = blockIdx.x;
  const int bh = wg>>6, cg = wg&63;
  const int w = t>>6, lane = t&63;
  const int cl = lane&15, lg = lane>>4;
  u32* exu  = (u32*)A.ex;    // [NL][2][32][256]
  u32* exmu = (u32*)A.exm;   // [2][32][256]
  // ---- one-time weight preload: per wave, 2 n-tiles x 8 k-frags per layer --
  bf16x8 bw[NL][2][8];
  #pragma unroll
  for (int l=0;l<NL;++l){
    const int kx = A.L[l].kx;
    #pragma unroll
    for (int nt=0; nt<2; ++nt){
      const int c32 = nt*16 + cl;
      const int r = (c32&3)*512 + cg*8 + (c32>>2);
      #pragma unroll
      for (int f=0;f<8;++f){
        union { bf16x8 v; u16 s[8]; } u;
        int k8 = w*256 + f*32 + lg*8;
        if (k8 < 512){
          if (k8 < kx){
            const float* p = A.L[l].Wih + (long)r*kx + k8;
            for (int j=0;j<8;++j) u.s[j]=f2b(p[j]);
          } else { for (int j=0;j<8;++j) u.s[j]=0; }
        } else {
          const float* p = A.L[l].Whh + (long)r*512 + (k8-512);
          for (int j=0;j<8;++j) u.s[j]=f2b(p[j]);
        }
        bw[l][nt][f]=u.v;
      }
    }
  }
  float bias_r[NL][4];
  float cst_r[NL];
  #pragma unroll
  for (int l=0;l<NL;++l) cst_r[l]=0.f;
  if (t<128){
    const int uu = t>>4;
    #pragma unroll
    for (int l=0;l<NL;++l)
      #pragma unroll
      for (int g=0;g<4;++g)
        bias_r[l][g] = A.L[l].bias[g*512 + cg*8 + uu];
  }
  // zero own EX slices (both parities, all layers + EXM for NL==4)
  {
    const int tot = (NL==4)? 640 : 128;
    for (int i=t;i<tot;i+=256){
      int l5=i>>7, rem=i&127;
      int par0=rem>>6, bl=(rem>>2)&15, j=rem&3;
      int b=bh*16+bl;
      u32* p = (l5<NL)? exu + (l5*2+par0)*8192 + b*256 + cg*4 + j
                      : exmu + par0*8192 + b*256 + cg*4 + j;
      cstore(p,0);
    }
  }
  __syncthreads();  // drains vmcnt per wave before flag post
  if (t==0) cstore(&A.flags[wg], A.base+1);
  const int T = A.T;
  for (int s=0; s<T+NL-1; ++s){
    waitflags(A.flags, A.base+s+1, A.nwg);
    const int par = (s-1)&1;
    if (NL==4 && s>=3 && s<=T-1){
      // fast path: all 4 layers active, pipelined staging
      const int t0 = A.rev ? (T-1-s) : s;
      STAGE(0,0,t0) STAGE(1,1,0)
      VWAIT(8) DOMFMA(0,0) STAGE(2,0,0)
      VWAIT(8) DOMFMA(1,1) STAGE(3,1,0)
      VWAIT(8) DOMFMA(2,0)
      VWAIT(0) DOMFMA(3,1)
    } else {
      #pragma unroll
      for (int l=0;l<NL;++l){
        const int sc = s-l;
        if (sc<0 || sc>=T) continue;
        const int ttl = A.rev ? (T-1-sc) : sc;
        STAGE(l, (l&1), ttl)
        VWAIT(0)
        DOMFMA(l, (l&1))
      }
    }
    __syncthreads();
    if (t<128){
      const int bl = t&15, uu = t>>4;
      const int b = bh*16 + bl;
      #pragma unroll
      for (int l=0;l<NL;++l){
        const int sc = s-l;
        if (sc<0 || sc>=T) continue;
        const int tt = A.rev ? (T-1-sc) : sc;
        float g4[4];
        #pragma unroll
        for (int g=0;g<4;++g){
          const int c32 = uu*4+g;
          float sum = bias_r[l][g];
          #pragma unroll
          for (int ww=0;ww<4;++ww) sum += P[l*2560 + (ww*32+c32)*20 + bl];
          g4[g]=sum;
        }
        float c2 = sigm(g4[1])*cst_r[l] + sigm(g4[0])*tanh_f(g4[2]);
        float h2 = sigm(g4[3])*tanh_f(c2);
        cst_r[l]=c2;
        float h2n = __shfl_down(h2, 16);
        if (!(uu&1)){
          u32 pk = (u32)f2b(h2) | ((u32)f2b(h2n)<<16);
          cstore(exu + (l*2+(s&1))*8192 + b*256 + cg*4 + (uu>>1), pk);
        }
        if (NL==4 && l==2){
          float m = A.xm[b*4096 + 4*tt];
          float hm = h2*m;
          float hmn = __shfl_down(hm, 16);
          if (!(uu&1)){
            u32 pk = (u32)f2b(hm) | ((u32)f2b(hmn)<<16);
            cstore(exmu + (s&1)*8192 + b*256 + cg*4 + (uu>>1), pk);
          }
          if (A.L[2].hout) A.L[2].hout[((long)tt*32+b)*512 + cg*8+uu] = f2b(hm);
        } else if (A.L[l].hout){
          float ov = h2;
          if (A.L[l].maskout) ov *= A.xm[b*4096 + 4*tt];
          A.L[l].hout[((long)tt*32+b)*512 + cg*8+uu] = f2b(ov);
        }
      }
    }
    __syncthreads();
    if (t==0) cstore(&A.flags[wg], A.base+s+2);
  }
}

// ---------------- decoder persistent MFMA LSTM (H=256) — R6-proven ----------
__global__ __launch_bounds__(256,1) void dec_rec2(
    const u16* __restrict__ xin, const float* __restrict__ Wih,
    const float* __restrict__ Whh, const float* __restrict__ bias,
    float* __restrict__ dout, u16* __restrict__ exd,
    unsigned* flags, unsigned base, int T)
{
  __shared__ __align__(16) char Vs[49152];
  __shared__ float P[2304];
  __shared__ float cst[128];
  __shared__ float biasl[16];
  const int t = threadIdx.x, wg = blockIdx.x; // 64 WGs
  const int u0 = wg*4;
  const int w = t>>6, lane = t&63, c = lane&15, lg = lane>>4;
  const int r = (c&3)*256 + u0 + (c>>2);
  u32* exu = (u32*)exd; // [2][32][128]
  const int nf = (w<2) ? 8 : 4;
  bf16x8 bw[8];
  #pragma unroll
  for (int f=0;f<8;++f){
    union { bf16x8 v; u16 s[8]; } u;
    if (f < nf){
      if (w<2){
        const float* p = Wih + (long)r*512 + w*256 + f*32 + lg*8;
        for (int j=0;j<8;++j) u.s[j]=f2b(p[j]);
      } else {
        const float* p = Whh + (long)r*256 + (w-2)*128 + f*32 + lg*8;
        for (int j=0;j<8;++j) u.s[j]=f2b(p[j]);
      }
    } else { for (int j=0;j<8;++j) u.s[j]=0; }
    bw[f]=u.v;
  }
  if (t<16) biasl[t] = bias[(t&3)*256 + u0 + (t>>2)];
  if (t<128) cst[t]=0.f;
  if (t<128){
    int par=(t>>6)&1, b=(t>>1)&31, j=t&1;
    cstore(exu + par*4096 + b*128 + wg*2 + j, 0);
  }
  __syncthreads();
  if (t==0) cstore(&flags[wg], base+1);
  const int waveOff = (w<2) ? w*16384 : 32768 + (w-2)*8192;
  const int NI  = (w<2) ? 16 : 8;
  const int rpi = (w<2) ? 2 : 4;
  const int sb  = (w<2) ? (lane>>5) : (lane>>4);
  const int coffb = (w<2) ? (lane&31)*16 : (lane&15)*16;
  const int rowB = (w<2) ? 512 : 256;
  for (int s=0; s<T; ++s){
    waitflags(flags, base+s+1, 64);
    const int par = (s-1)&1;
    #pragma unroll
    for (int i=0;i<16;++i){
      if (i>=NI) break;
      int b = i*rpi + sb;
      const char* src = (w<2)
        ? (const char*)xin + (long)s*32768 + w*512 + b*1024 + (coffb ^ ((b&7)<<4))
        : (const char*)exd + par*16384 + (w-2)*256 + b*512 + (coffb ^ ((b&7)<<4));
      void* ldst = (void*)(Vs + waveOff + i*1024);
      if (w<2) __builtin_amdgcn_global_load_lds((const u32*)src, (u32*)ldst, 16, 0, 0);
      else     __builtin_amdgcn_global_load_lds((const u32*)src, (u32*)ldst, 16, 0, 0x11);
    }
    asm volatile("s_waitcnt vmcnt(0)" ::: "memory");
    f32x4 acc0={0.f,0.f,0.f,0.f}, acc1={0.f,0.f,0.f,0.f};
    const int b1 = c+16;
    #pragma unroll
    for (int f=0;f<8;++f){
      if (f>=nf) break;
      int koff = f*64 + lg*16;
      union { bf16x8 v; uint4 q; } a0, a1;
      a0.q = *(const uint4*)(Vs + waveOff + c *rowB + (koff ^ ((c &7)<<4)));
      a1.q = *(const uint4*)(Vs + waveOff + b1*rowB + (koff ^ ((b1&7)<<4)));
      acc0 = __builtin_amdgcn_mfma_f32_16x16x32_bf16(a0.v, bw[f], acc0, 0,0,0);
      acc1 = __builtin_amdgcn_mfma_f32_16x16x32_bf16(a1.v, bw[f], acc1, 0,0,0);
    }
    {
      float* pp = &P[(w*16+c)*36 + lg*4];
      *(f32x4*)pp      = acc0;
      *(f32x4*)(pp+16) = acc1;
    }
    __syncthreads();
    if (t<128){
      const int b = t&31, uu = t>>5, wpw = t>>6;
      float g4[4];
      #pragma unroll
      for (int g=0; g<4; ++g){
        int cc = uu*4+g;
        float sum = biasl[cc];
        #pragma unroll
        for (int ww=0; ww<4; ++ww) sum += P[(ww*16+cc)*36 + b];
        g4[g]=sum;
      }
      float c2 = sigm(g4[1])*cst[t] + sigm(g4[0])*tanh_f(g4[2]);
      float h2 = sigm(g4[3])*tanh_f(c2);
      cst[t]=c2;
      u32 hv = (u32)f2b(h2);
      u32 ot = (u32)__shfl_xor((int)hv, 32);
      if (lane<32)
        cstore(exu + (s&1)*4096 + b*128 + wg*2 + wpw, (hv&0xffffu)|(ot<<16));
      dout[((long)s*32+b)*256 + u0+uu] = h2;
    }
    __syncthreads();
    if (t==0) cstore(&flags[wg], base+s+2);
  }
}

// ---------------- x pre-convert: fp32 (B,1024,320) -> bf16 [t*32+b][512] ----
__global__ void cvt_x(const float* __restrict__ x, u16* __restrict__ xp){
  long id8 = ((long)blockIdx.x*256 + threadIdx.x)*8;
  int rr = (int)(id8 >> 9); int k = (int)(id8 & 511);
  int tt = rr >> 5, b = rr & 31;
  union { uint4 q; u16 s[8]; } u;
  if (k < 320){
    const float* p = x + (long)b*327680 + (long)tt*320 + k;
    float4 v0 = *(const float4*)p, v1 = *(const float4*)(p+4);
    u.s[0]=f2b(v0.x); u.s[1]=f2b(v0.y); u.s[2]=f2b(v0.z); u.s[3]=f2b(v0.w);
    u.s[4]=f2b(v1.x); u.s[5]=f2b(v1.y); u.s[6]=f2b(v1.z); u.s[7]=f2b(v1.w);
  } else {
    for (int j=0;j<8;++j) u.s[j]=0;
  }
  *(uint4*)(xp + id8) = u.q;
}

// ---------------- MFMA GEMM: C[m,n] = [A0|A1][m,:K] . W[n,:K] + bias[n] -----
template<int ABF, int CBF>
__global__ __launch_bounds__(256,2) void gemm_mfma(
  const void* __restrict__ A0, long lda0, const void* __restrict__ A1, long lda1, int K0,
  const float* __restrict__ W, const float* __restrict__ bias, void* __restrict__ C,
  int M, int N, int K, int ldw, int act)
{
  __shared__ __align__(16) u16 As[64*32];
  __shared__ __align__(16) u16 Bs[64*32];
  const int t = threadIdx.x;
  const int m0 = blockIdx.x*64, n0 = blockIdx.y*64;
  const int w = t>>6, lane = t&63;
  const int al = lane&15, lg = lane>>4;
  f32x4 acc[4];
  #pragma unroll
  for (int i=0;i<4;++i) acc[i] = (f32x4){0.f,0.f,0.f,0.f};
  const int srow = t>>2, kq = t&3;
  const int spos = (kq ^ (srow&3))*8;
  for (int k0=0; k0<K; k0+=32){
    {
      int kk = k0 + kq*8;
      const void* Ab; long lda; int kof;
      if (kk < K0){ Ab=A0; lda=lda0; kof=kk; } else { Ab=A1; lda=lda1; kof=kk-K0; }
      union { uint4 q; u16 s[8]; } u;
      if (ABF){
        u.q = *(const uint4*)((const u16*)Ab + (long)(m0+srow)*lda + kof);
      } else {
        const float* ap = (const float*)Ab + (long)(m0+srow)*lda + kof;
        float4 x0 = *(const float4*)ap, x1 = *(const float4*)(ap+4);
        u.s[0]=f2b(x0.x); u.s[1]=f2b(x0.y); u.s[2]=f2b(x0.z); u.s[3]=f2b(x0.w);
        u.s[4]=f2b(x1.x); u.s[5]=f2b(x1.y); u.s[6]=f2b(x1.z); u.s[7]=f2b(x1.w);
      }
      *(uint4*)&As[srow*32 + spos] = u.q;
    }
    {
      int n = n0 + srow;
      union { uint4 q; u16 s[8]; } u;
      if (n < N){
        const float* wp = W + (long)n*ldw + k0 + kq*8;
        float4 y0 = *(const float4*)wp, y1 = *(const float4*)(wp+4);
        u.s[0]=f2b(y0.x); u.s[1]=f2b(y0.y); u.s[2]=f2b(y0.z); u.s[3]=f2b(y0.w);
        u.s[4]=f2b(y1.x); u.s[5]=f2b(y1.y); u.s[6]=f2b(y1.z); u.s[7]=f2b(y1.w);
      } else {
        for (int j=0;j<8;++j) u.s[j]=0;
      }
      *(uint4*)&Bs[srow*32 + spos] = u.q;
    }
    __syncthreads();
    union { bf16x8 v; uint4 q; } a;
    a.q = *(const uint4*)&As[(w*16+al)*32 + ((lg ^ (al&3))*8)];
    #pragma unroll
    for (int nt=0; nt<4; ++nt){
      union { bf16x8 v; uint4 q; } b;
      b.q = *(const uint4*)&Bs[(nt*16+al)*32 + ((lg ^ (al&3))*8)];
      acc[nt] = __builtin_amdgcn_mfma_f32_16x16x32_bf16(a.v, b.v, acc[nt], 0,0,0);
    }
    __syncthreads();
  }
  #pragma unroll
  for (int nt=0; nt<4; ++nt){
    int n = n0 + nt*16 + al;
    if (n >= N) continue;
    float bv = bias[n];
    #pragma unroll
    for (int j=0;j<4;++j){
      int m = m0 + w*16 + lg*4 + j;
      float v = acc[nt][j] + bv;
      if (act) v = (v > 0.f) ? v : 0.1f*v;
      if (CBF) ((u16*)C)[(long)m*N + n] = f2b(v);
      else     ((float*)C)[(long)m*N + n] = v;
    }
  }
}

// ---------------- fp32 SIMD GEMM (kept for epart) ---------------------------
template<int ABF, int CBF>
__global__ __launch_bounds__(256,1) void gemm_bias(
  const void* __restrict__ A0, long lda0, const void* __restrict__ A1, long lda1, int K0,
  const float* __restrict__ W, const float* __restrict__ bias, void* __restrict__ C,
  int M, int N, int K, int ldw, int act)
{
  __shared__ __align__(16) float As[16*132];
  __shared__ __align__(16) float Bs[16*132];
  const int t = threadIdx.x;
  const int m0 = blockIdx.x*128, n0 = blockIdx.y*128;
  const int tx = t&15, ty = t>>4;
  float acc[8][8];
  for (int i=0;i<8;++i)
    for (int j=0;j<8;++j) acc[i][j]=0.f;
  const int row = t>>1, seg = t&1;
  for (int k0=0;k0<K;k0+=16){
    {
      const int kk = k0 + seg*8;
      const void* Ab; long lda; int kof;
      if (kk < K0){ Ab=A0; lda=lda0; kof=kk; } else { Ab=A1; lda=lda1; kof=kk-K0; }
      float v[8];
      if (ABF){
        const u16* ap = (const u16*)Ab + (long)(m0+row)*lda + kof;
        union { uint4 q; u16 s[8]; } u; u.q = *(const uint4*)ap;
        #pragma unroll
        for (int j=0;j<8;++j) v[j]=b2f(u.s[j]);
      } else {
        const float* ap = (const float*)Ab + (long)(m0+row)*lda + kof;
        float4 x0 = *(const float4*)(ap);
        float4 x1 = *(const float4*)(ap+4);
        v[0]=x0.x;v[1]=x0.y;v[2]=x0.z;v[3]=x0.w;v[4]=x1.x;v[5]=x1.y;v[6]=x1.z;v[7]=x1.w;
      }
      const int kb = seg*8;
      #pragma unroll
      for (int j=0;j<8;++j) As[(kb+j)*132+row]=v[j];
    }
    {
      const int n = n0 + row;
      float4 y0 = {0,0,0,0}, y1 = {0,0,0,0};
      if (n < N){
        const float* wp = W + (long)n*ldw + k0 + seg*8;
        y0 = *(const float4*)(wp); y1 = *(const float4*)(wp+4);
      }
      const int kb = seg*8;
      Bs[(kb+0)*132+row]=y0.x; Bs[(kb+1)*132+row]=y0.y; Bs[(kb+2)*132+row]=y0.z; Bs[(kb+3)*132+row]=y0.w;
      Bs[(kb+4)*132+row]=y1.x; Bs[(kb+5)*132+row]=y1.y; Bs[(kb+6)*132+row]=y1.z; Bs[(kb+7)*132+row]=y1.w;
    }
    __syncthreads();
    #pragma unroll
    for (int k=0;k<16;++k){
      const float* ap = &As[k*132 + ty*8];
      const float* bp = &Bs[k*132 + tx*8];
      float4 A0v=*(const float4*)(ap), A1v=*(const float4*)(ap+4);
      float4 B0v=*(const float4*)(bp), B1v=*(const float4*)(bp+4);
      float av[8]={A0v.x,A0v.y,A0v.z,A0v.w,A1v.x,A1v.y,A1v.z,A1v.w};
      float bv[8]={B0v.x,B0v.y,B0v.z,B0v.w,B1v.x,B1v.y,B1v.z,B1v.w};
      #pragma unroll
      for (int i=0;i<8;++i){
        #pragma unroll
        for (int j=0;j<8;++j) acc[i][j] += av[i]*bv[j];
      }
    }
    __syncthreads();
  }
  float bv[8];
  #pragma unroll
  for (int j=0;j<8;++j){ int n = n0+tx*8+j; bv[j] = (n<N)? bias[n] : 0.f; }
  const bool full = (n0+128 <= N);
  #pragma unroll
  for (int i=0;i<8;++i){
    const int m = m0 + ty*8 + i;
    float v[8];
    #pragma unroll
    for (int j=0;j<8;++j){
      float x = acc[i][j] + bv[j];
      if (act) x = (x > 0.f) ? x : 0.1f*x;
      v[j] = x;
    }
    if (CBF){
      u16* cp = (u16*)C + (long)m*N + n0 + tx*8;
      union { uint4 q; u16 s[8]; } u;
      #pragma unroll
      for (int j=0;j<8;++j) u.s[j]=f2b(v[j]);
      *(uint4*)cp = u.q;
    } else {
      float* cp = (float*)C + (long)m*N + n0 + tx*8;
      if (full){
        float4 s0 = {v[0],v[1],v[2],v[3]}, s1 = {v[4],v[5],v[6],v[7]};
        *(float4*)(cp) = s0; *(float4*)(cp+4) = s1;
      } else {
        #pragma unroll
        for (int j=0;j<8;++j) if (n0+tx*8+j < N) cp[j] = v[j];
      }
    }
  }
}

// ---------------- elementwise helpers --------------------------------------
__global__ void mask_bf16(u16* __restrict__ buf, int F, const float* __restrict__ xm){
  long id8 = ((long)blockIdx.x*256 + threadIdx.x)*8;
  int row = (int)(id8 / F);
  int tt = row>>5, b = row&31;
  float m = xm[b*4096 + 4*tt];
  union { uint4 q; u16 s[8]; } u;
  u.q = *(uint4*)(buf + id8);
  #pragma unroll
  for (int j=0;j<8;++j) u.s[j] = f2b(b2f(u.s[j])*m);
  *(uint4*)(buf + id8) = u.q;
}

__global__ void embed_gather(const float* __restrict__ emb, const int* __restrict__ y,
                             float* __restrict__ out){
  int id = blockIdx.x*256 + threadIdx.x;
  int p = id&255, r = id>>8;
  int l = r>>5, b = r&31;
  out[id] = emb[(long)y[b*65 + l]*256 + p];
}

__global__ void zero_f(float* __restrict__ p, int n){
  int id = blockIdx.x*256 + threadIdx.x;
  if (id < n) p[id] = 0.f;
}

__global__ void set_val(float* p, float v){ p[0] = v; }

__global__ void attfea_k(const float* __restrict__ lstms, const float* __restrict__ ctxs,
                         const float* __restrict__ ym, float* __restrict__ attf,
                         u16* __restrict__ attfb){
  long id4 = ((long)blockIdx.x*256 + threadIdx.x)*4;
  int r = (int)(id4>>9); int f = (int)(id4&511);
  int l = r>>5, b = r&31;
  float m = ym[b*65 + l + 1];
  float4 v = (f<256) ? *(const float4*)(lstms + (long)r*256 + f)
                     : *(const float4*)(ctxs  + (long)r*256 + (f-256));
  v.x*=m; v.y*=m; v.z*=m; v.w*=m;
  *(float4*)(attf + id4) = v;
  u16* ob = attfb + id4;
  ob[0]=f2b(v.x); ob[1]=f2b(v.y); ob[2]=f2b(v.z); ob[3]=f2b(v.w);
}

__global__ void dcat_k(const float* __restrict__ attf, const float* __restrict__ dout,
                       const float* __restrict__ ym, float* __restrict__ dcat){
  long id4 = ((long)blockIdx.x*256 + threadIdx.x)*4;
  int r = (int)(id4/768); int f = (int)(id4 - (long)r*768);
  int l = r>>5, b = r&31;
  float m = ym[b*65 + l + 1];
  float4 v = (f<512) ? *(const float4*)(attf + (long)r*512 + f)
                     : *(const float4*)(dout + (long)r*256 + (f-512));
  v.x*=m; v.y*=m; v.z*=m; v.w*=m;
  *(float4*)(dcat + id4) = v;
}

// ---------------- decoder attention step kernels ----------------------------
__global__ __launch_bounds__(256,1) void k1_dec(
  const float* __restrict__ bodyR, float* __restrict__ bodyW,
  const float* __restrict__ epart, const float* __restrict__ Whh,
  const float* __restrict__ Wih, float* __restrict__ cc,
  float* __restrict__ lstms, int s)
{
  __shared__ __align__(16) float vT[512*36];
  __shared__ float gl[32*32];
  const int t = threadIdx.x, wg = blockIdx.x;
  for (int i = t*4; i < 32*512; i += 1024){
    int b = i>>9, k = i&511;
    float4 v = *(const float4*)(bodyR + b*512 + k);
    vT[(k+0)*36+b]=v.x; vT[(k+1)*36+b]=v.y; vT[(k+2)*36+b]=v.z; vT[(k+3)*36+b]=v.w;
  }
  __syncthreads();
  const int c_l = t>>3, bq = t&7;
  const int col = (c_l&3)*256 + wg*8 + (c_l>>2);
  float a0=0.f,a1=0.f,a2=0.f,a3=0.f;
  for (int k=0;k<256;k+=4){
    float4 w = *(const float4*)(Whh + (long)col*256 + k);
    const float* vp = &vT[k*36 + bq*4];
    float4 v0=*(const float4*)(vp), v1=*(const float4*)(vp+36), v2=*(const float4*)(vp+72), v3=*(const float4*)(vp+108);
    a0 += w.x*v0.x + w.y*v1.x + w.z*v2.x + w.w*v3.x;
    a1 += w.x*v0.y + w.y*v1.y + w.z*v2.y + w.w*v3.y;
    a2 += w.x*v0.z + w.y*v1.z + w.z*v2.z + w.w*v3.z;
    a3 += w.x*v0.w + w.y*v1.w + w.z*v2.w + w.w*v3.w;
  }
  for (int k=256;k<512;k+=4){
    float4 w = *(const float4*)(Wih + (long)col*512 + k);
    const float* vp = &vT[k*36 + bq*4];
    float4 v0=*(const float4*)(vp), v1=*(const float4*)(vp+36), v2=*(const float4*)(vp+72), v3=*(const float4*)(vp+108);
    a0 += w.x*v0.x + w.y*v1.x + w.z*v2.x + w.w*v3.x;
    a1 += w.x*v0.y + w.y*v1.y + w.z*v2.y + w.w*v3.y;
    a2 += w.x*v0.z + w.y*v1.z + w.z*v2.z + w.w*v3.z;
    a3 += w.x*v0.w + w.y*v1.w + w.z*v2.w + w.w*v3.w;
  }
  gl[c_l*32+bq*4+0] = a0 + epart[((long)s*32 + bq*4+0)*1024 + col];
  gl[c_l*32+bq*4+1] = a1 + epart[((long)s*32 + bq*4+1)*1024 + col];
  gl[c_l*32+bq*4+2] = a2 + epart[((long)s*32 + bq*4+2)*1024 + col];
  gl[c_l*32+bq*4+3] = a3 + epart[((long)s*32 + bq*4+3)*1024 + col];
  __syncthreads();
  {
    const int u_ = t>>5, b = t&31, ug = wg*8 + u_;
    const float gi=gl[(u_*4+0)*32+b], gf=gl[(u_*4+1)*32+b], gg=gl[(u_*4+2)*32+b], go=gl[(u_*4+3)*32+b];
    float c0 = cc[b*256+ug];
    float c2 = sigm(gf)*c0 + sigm(gi)*tanh_f(gg);
    float h2 = sigm(go)*tanh_f(c2);
    cc[b*256+ug] = c2;
    bodyW[b*512 + ug] = h2;
    lstms[((long)s*32 + b)*256 + ug] = h2;
  }
}

__global__ __launch_bounds__(256,1) void k2_dec(
  const float* __restrict__ bodyW, const float* __restrict__ vW,
  const float* __restrict__ vb, float* __restrict__ state)
{
  __shared__ __align__(16) float hT[256*36];
  const int t = threadIdx.x, wg = blockIdx.x;
  for (int i = t*4; i < 8192; i += 1024){
    int b = i>>8, k = i&255;
    float4 v = *(const float4*)(bodyW + b*512 + k);
    hT[(k+0)*36+b]=v.x; hT[(k+1)*36+b]=v.y; hT[(k+2)*36+b]=v.z; hT[(k+3)*36+b]=v.w;
  }
  __syncthreads();
  const int p = wg*32 + (t>>3), bq = t&7;
  float a0=0.f,a1=0.f,a2=0.f,a3=0.f;
  for (int k=0;k<256;k+=4){
    float4 w = *(const float4*)(vW + (long)p*256 + k);
    const float* vp = &hT[k*36 + bq*4];
    float4 v0=*(const float4*)(vp), v1=*(const float4*)(vp+36), v2=*(const float4*)(vp+72), v3=*(const float4*)(vp+108);
    a0 += w.x*v0.x + w.y*v1.x + w.z*v2.x + w.w*v3.x;
    a1 += w.x*v0.y + w.y*v1.y + w.z*v2.y + w.w*v3.y;
    a2 += w.x*v0.z + w.y*v1.z + w.z*v2.z + w.w*v3.z;
    a3 += w.x*v0.w + w.y*v1.w + w.z*v2.w + w.w*v3.w;
  }
  float bb = vb[p];
  state[(bq*4+0)*256 + p] = a0 + bb;
  state[(bq*4+1)*256 + p] = a1 + bb;
  state[(bq*4+2)*256 + p] = a2 + bb;
  state[(bq*4+3)*256 + p] = a3 + bb;
}

__global__ __launch_bounds__(256,1) void k3_dec(
  const float* __restrict__ state, const u16* __restrict__ atth,
  const float* __restrict__ wav, const float* __restrict__ xm,
  float* __restrict__ sc, float* __restrict__ scm)
{
  __shared__ float st[256], wv[256], red[256];
  const int t = threadIdx.x;
  const int b = blockIdx.x>>2, ch = blockIdx.x&3;
  st[t] = state[b*256 + t];
  wv[t] = wav[t];
  __syncthreads();
  const int tp = ch*256 + t;
  const u16* ap = atth + ((long)tp*32 + b)*256;
  float acc = 0.f;
  for (int p=0;p<256;p+=4){
    ushort4 a = *(const ushort4*)(ap+p);
    acc += wv[p+0]*tanh_f(st[p+0]+b2f(a.x));
    acc += wv[p+1]*tanh_f(st[p+1]+b2f(a.y));
    acc += wv[p+2]*tanh_f(st[p+2]+b2f(a.z));
    acc += wv[p+3]*tanh_f(st[p+3]+b2f(a.w));
  }
  acc += (xm[b*4096 + 4*tp] - 1.0f)*1e30f;
  sc[b*1024 + tp] = acc;
  red[t] = acc;
  __syncthreads();
  for (int o=128;o>0;o>>=1){ if (t<o) red[t]=fmaxf(red[t],red[t+o]); __syncthreads(); }
  if (t==0) scm[b*4+ch] = red[0];
}

__global__ __launch_bounds__(256,1) void k4_dec(
  const float* __restrict__ sc, const float* __restrict__ scm,
  const u16* __restrict__ eout, float* __restrict__ ctxs,
  float* __restrict__ bodyW, int s)
{
  __shared__ float al[1024];
  __shared__ float red[256];
  const int t = threadIdx.x, b = blockIdx.x;
  float m = fmaxf(fmaxf(scm[b*4+0],scm[b*4+1]), fmaxf(scm[b*4+2],scm[b*4+3]));
  float ps = 0.f;
  #pragma unroll
  for (int j=0;j<4;++j){
    int tp = t + j*256;
    float e = __expf(sc[b*1024+tp] - m);
    al[tp] = e; ps += e;
  }
  red[t]=ps; __syncthreads();
  for (int o=128;o>0;o>>=1){ if (t<o) red[t]+=red[t+o]; __syncthreads(); }
  float rinv = 1.0f/red[0];
  float acc = 0.f;
  const u16* ep = eout + b*256 + t;
  for (int tp=0;tp<1024;++tp) acc += al[tp] * b2f(ep[(long)tp*8192]);
  float cv = acc*rinv;
  ctxs[((long)s*32 + b)*256 + t] = cv;
  bodyW[b*512 + 256 + t] = cv;
}

// ---------------- loss ------------------------------------------------------
__global__ __launch_bounds__(256,1) void loss_row(
  const float* __restrict__ logits, const int* __restrict__ y,
  const float* __restrict__ ym, float* __restrict__ rows)
{
  __shared__ float red[256];
  const int r = blockIdx.x, t = threadIdx.x;
  const float* row = logits + (long)r*4235;
  float mx = -3.0e38f;
  for (int i=t;i<4235;i+=256) mx = fmaxf(mx, row[i]);
  red[t]=mx; __syncthreads();
  for (int o=128;o>0;o>>=1){ if (t<o) red[t]=fmaxf(red[t],red[t+o]); __syncthreads(); }
  const float M = red[0];
  __syncthreads();
  float se=0.f, sl=0.f;
  for (int i=t;i<4235;i+=256){ float v=row[i]; se += __expf(v-M); sl += v; }
  red[t]=se; __syncthreads();
  for (int o=128;o>0;o>>=1){ if (t<o) red[t]+=red[t+o]; __syncthreads(); }
  const float SE = red[0];
  __syncthreads();
  red[t]=sl; __syncthreads();
  for (int o=128;o>0;o>>=1){ if (t<o) red[t]+=red[t+o]; __syncthreads(); }
  const float SL = red[0];
  if (t==0){
    const int tt = r>>5, b = r&31;
    const float lse = M + logf(SE);
    const float mk = (ym[b*65 + tt + 1] > 0.f) ? 1.f : 0.f;
    rows[r]        = (4235.0f*lse - SL)*mk;
    rows[2048 + r] = (lse - row[y[b*65 + tt + 1]])*mk;
    rows[4096 + r] = mk;
  }
}

__global__ __launch_bounds__(256,1) void loss_final(const float* __restrict__ rows, float* __restrict__ out){
  __shared__ float red[256];
  const int t = threadIdx.x;
  float s1=0.f,s2=0.f,s3=0.f;
  for (int i=t;i<2048;i+=256){ s1+=rows[i]; s2+=rows[2048+i]; s3+=rows[4096+i]; }
  red[t]=s1; __syncthreads();
  for (int o=128;o>0;o>>=1){ if (t<o) red[t]+=red[t+o]; __syncthreads(); }
  const float S = red[0]; __syncthreads();
  red[t]=s2; __syncthreads();
  for (int o=128;o>0;o>>=1){ if (t<o) red[t]+=red[t+o]; __syncthreads(); }
  const float NL = red[0]; __syncthreads();
  red[t]=s3; __syncthreads();
  for (int o=128;o>0;o>>=1){ if (t<o) red[t]+=red[t+o]; __syncthreads(); }
  const float N = red[0];
  if (t==0){
    float n = (N > 0.f) ? N : 1.f;
    out[0] = (S/n)*(0.1f/4235.0f) + 0.9f*(NL/n);
  }
}

// ---------------- launcher --------------------------------------------------
extern "C" void kernel_launch(void* const* d_in, const int* in_sizes, int n_in,
                              void* d_out, int out_size, void* d_ws, size_t ws_size,
                              hipStream_t stream)
{
  const float* x    = (const float*)d_in[0];
  const float* xm   = (const float*)d_in[1];
  const int*   y    = (const int*)  d_in[2];
  const float* ym   = (const float*)d_in[3];
  const float* l1_Wih=(const float*)d_in[4];  const float* l1_Whh=(const float*)d_in[5];  const float* l1_b=(const float*)d_in[6];
  const float* l2_Wih=(const float*)d_in[7];  const float* l2_Whh=(const float*)d_in[8];  const float* l2_b=(const float*)d_in[9];
  const float* l3_Wih=(const float*)d_in[10]; const float* l3_Whh=(const float*)d_in[11]; const float* l3_b=(const float*)d_in[12];
  const float* bf_Wih=(const float*)d_in[13]; const float* bf_Whh=(const float*)d_in[14]; const float* bf_b=(const float*)d_in[15];
  const float* bb_Wih=(const float*)d_in[16]; const float* bb_Whh=(const float*)d_in[17]; const float* bb_b=(const float*)d_in[18];
  const float* c1_W=(const float*)d_in[19]; const float* c1_b=(const float*)d_in[20];
  const float* c2_W=(const float*)d_in[21]; const float* c2_b=(const float*)d_in[22];
  const float* emb =(const float*)d_in[23];
  const float* att_Wih=(const float*)d_in[24]; const float* att_Whh=(const float*)d_in[25]; const float* att_b=(const float*)d_in[26];
  const float* w_W=(const float*)d_in[27]; const float* w_b=(const float*)d_in[28];
  const float* v_W=(const float*)d_in[29]; const float* v_b=(const float*)d_in[30];
  const float* wav=(const float*)d_in[31];
  const float* dec_Wih=(const float*)d_in[32]; const float* dec_Whh=(const float*)d_in[33]; const float* dec_b=(const float*)d_in[34];
  const float* cls_W=(const float*)d_in[35]; const float* cls_b=(const float*)d_in[36];

  const size_t REQ = 137625600ull; // ~131.3 MiB (verified fit)
  if (ws_size < REQ){
    set_val<<<1,1,0,stream>>>((float*)d_out, -(float)(ws_size>>20));
    return;
  }
  char* ws = (char*)d_ws;
  unsigned* FLAGS = (unsigned*)(ws);            // 512B (dense, R6 layout)
  u16* EXU  = (u16*)(ws + 65536);               // 4x2x32x512 = 256KB
  u16* EXM  = (u16*)(ws + 327680);              // 2x32x512 = 64KB
  u16* EXD  = (u16*)(ws + 393216);              // 2x32x256 = 32KB
  u16* XP   = (u16*)(ws + 2097152);             // 32MB
  u16* HS2  = (u16*)(ws + 35651584);            // 32MB (masked h3)
  u16* HSF  = (u16*)(ws + 69206016);            // 32MB (masked bf)
  u16* HSB  = XP;                               // masked bb overlays XP
  u16* C1OUT = HS2;                             // after bb done
  u16* EOUTB = HSF;                             // 16MB (HSF dead after conv1)
  u16* ATTHB = (u16*)(ws + 85983232);           // 16MB
  float* LOGIT = (float*)XP;                    // after conv2
  float* AR    = (float*)(ws + 102760448);      // decoder arena
  float* EMBED = AR;
  float* EPART = EMBED + 524288;
  float* LSTMS = EPART + 2097152;
  float* CTXS  = LSTMS + 524288;
  float* ATTF  = CTXS  + 524288;
  float* DOUT  = ATTF  + 1048576;
  float* DCAT  = DOUT  + 524288;
  float* SC    = DCAT  + 1572864;
  float* SCM   = SC    + 32768;
  float* ROWS  = SCM   + 128;
  float* BODY  = ROWS  + 6144;
  float* CC    = BODY  + 32768;
  float* STATE = CC    + 8192;
  u16*  ATTFB  = (u16*)(STATE + 8192);

  (void)hipMemsetAsync(ws, 0, 4096, stream);

  // ---------------- encoder: phase A (l1,l2,l3,bf pipelined, fence-free) ----
  cvt_x<<<8192,256,0,stream>>>(x, XP);
  PA2 pa;
  pa.L[0] = { l1_Wih, l1_Whh, l1_b, XP,      nullptr, 320, 0 };
  pa.L[1] = { l2_Wih, l2_Whh, l2_b, nullptr, nullptr, 512, 0 };
  pa.L[2] = { l3_Wih, l3_Whh, l3_b, nullptr, HS2,     512, 0 };
  pa.L[3] = { bf_Wih, bf_Whh, bf_b, nullptr, HSF,     512, 1 };
  pa.ex = EXU; pa.exm = EXM; pa.xm = xm; pa.flags = FLAGS;
  pa.T = 1024; pa.nwg = 128; pa.rev = 0; pa.base = 0;
  pipe2<4><<<128,256,0,stream>>>(pa);
  // ---------------- encoder: phase B (bb, reverse) --------------------------
  PA2 pb;
  pb.L[0] = { bb_Wih, bb_Whh, bb_b, HS2, HSB, 512, 1 };
  pb.L[1] = pb.L[0]; pb.L[2] = pb.L[0]; pb.L[3] = pb.L[0];
  pb.ex = EXU; pb.exm = EXM; pb.xm = xm; pb.flags = FLAGS;
  pb.T = 1024; pb.nwg = 128; pb.rev = 1; pb.base = 1028;
  pipe2<1><<<128,256,0,stream>>>(pb);
  // conv1 (leaky) on concat [bf|bb], conv2, mask, att_h — MFMA GEMMs
  gemm_mfma<1,1><<<dim3(512,8),256,0,stream>>>(HSF, 512, HSB, 512, 512,
      c1_W, c1_b, C1OUT, 32768, 512, 1024, 1024, 1);
  gemm_mfma<1,1><<<dim3(512,4),256,0,stream>>>(C1OUT, 512, C1OUT, 512, 512,
      c2_W, c2_b, EOUTB, 32768, 256, 512, 512, 0);
  mask_bf16<<<4096,256,0,stream>>>(EOUTB, 256, xm);
  gemm_mfma<1,1><<<dim3(512,4),256,0,stream>>>(EOUTB, 256, EOUTB, 256, 256,
      w_W, w_b, ATTHB, 32768, 256, 256, 256, 0);

  // ---------------- decoder -------------------------------------------------
  embed_gather<<<2048,256,0,stream>>>(emb, y, EMBED);
  gemm_bias<0,0><<<dim3(16,8),256,0,stream>>>(EMBED, 256, EMBED, 256, 256,
      att_Wih, att_b, EPART, 2048, 1024, 256, 512, 0);
  zero_f<<<160,256,0,stream>>>(BODY, 40960);
  for (int s=0;s<64;++s){
    float* bodyR = BODY + (s&1)*16384;
    float* bodyW = BODY + ((s+1)&1)*16384;
    k1_dec<<<32,256,0,stream>>>(bodyR, bodyW, EPART, att_Whh, att_Wih, CC, LSTMS, s);
    k2_dec<<<8,256,0,stream>>>(bodyW, v_W, v_b, STATE);
    k3_dec<<<128,256,0,stream>>>(STATE, ATTHB, wav, xm, SC, SCM);
    k4_dec<<<32,256,0,stream>>>(SC, SCM, EOUTB, CTXS, bodyW, s);
  }
  attfea_k<<<1024,256,0,stream>>>(LSTMS, CTXS, ym, ATTF, ATTFB);
  dec_rec2<<<64,256,0,stream>>>(ATTFB, dec_Wih, dec_Whh, dec_b,
      DOUT, EXD, FLAGS, 2053u, 64);
  dcat_k<<<1536,256,0,stream>>>(ATTF, DOUT, ym, DCAT);
  gemm_mfma<0,0><<<dim3(32,67),256,0,stream>>>(DCAT, 768, DCAT, 768, 768,
      cls_W, cls_b, LOGIT, 2048, 4235, 768, 768, 0);
  loss_row<<<2048,256,0,stream>>>(LOGIT, y, ym, ROWS);
  loss_final<<<1,256,0,stream>>>(ROWS, (float*)d_out);
}

// Round 11
// 21176.585 us; speedup vs baseline: 12.7208x; 1.1028x over previous
//
#include <hip/hip_runtime.h>
#include <math.h>

#define DEV static __device__ __forceinline__
typedef unsigned short u16;
typedef unsigned int u32;

typedef __attribute__((ext_vector_type(8))) __bf16 bf16x8;
typedef __attribute__((ext_vector_type(4))) float f32x4;

DEV float sigm(float x){ return 1.0f/(1.0f+__expf(-x)); }
DEV float tanh_f(float x){ float e=__expf(2.0f*x); return 1.0f - 2.0f/(e+1.0f); }

DEV float b2f(u16 u){ union {u32 i; float f;} c; c.i = ((u32)u)<<16; return c.f; }
DEV u16 f2b(float f){ union {u32 i; float f;} c; c.f = f; u32 r = (c.i + 0x7FFFu + ((c.i>>16)&1u)) >> 16; return (u16)r; }

// coherent (cross-XCD) dword ops — system scope, relaxed (verified R6)
DEV void cstore(u32* p, u32 v){ __hip_atomic_store(p, v, __ATOMIC_RELAXED, __HIP_MEMORY_SCOPE_SYSTEM); }
DEV u32  cload(const u32* p){ return __hip_atomic_load(p, __ATOMIC_RELAXED, __HIP_MEMORY_SCOPE_SYSTEM); }

// poll producer flags >= target (no fences) — ALL threads poll (R6-proven)
DEV void waitflags(unsigned* flags, unsigned target, int nwg){
  const int lane = threadIdx.x & 63;
  unsigned long long spin = 0;
  for(;;){
    bool ok = true;
    for (int j=lane; j<nwg; j+=64)
      ok &= ((int)(cload(&flags[j]) - target) >= 0);
    if (__all(ok)) break;
    if (++spin > 2000000ull) break; // safety: garbage instead of hang
    __builtin_amdgcn_s_sleep(1);
  }
}

// ---------------- pipelined persistent MFMA LSTM (H=512) --------------------
// R11: 128 WGs = 2 batch-halves x 64 col-groups (bh halves are data-disjoint
// -> each waits only its own 64 flags). All stages issued up-front (3 LDS
// bufs); plain (x) inputs staged BEFORE the flag wait. Flag/store ordering
// identical to R6/R9/R10.
struct PL2 { const float *Wih, *Whh, *bias; const u16* xplain; u16* hout; int kx, maskout; };
struct PA2 {
  PL2 L[4];
  u16* ex;        // [NL][2][32][512] u16
  u16* exm;       // [2][32][512] u16 (masked l3 output, phase A only)
  const float* xm;
  unsigned* flags;
  int T, nwg, rev; unsigned base;
};

#define VWAIT(N) { asm volatile("s_waitcnt vmcnt(" #N ")" ::: "memory"); __builtin_amdgcn_sched_barrier(0); }

// w<2 lanes: k-slice 0..511 ("x side" of the layer input)
#define STAGE_LO(LL, Q, TT) { \
  const char* base_; int coh_; \
  if ((LL)==0){ base_=(const char*)A.L[0].xplain + ((long)(TT)*32768) + w*512; coh_=0; } \
  else if (NL==4 && (LL)==3){ base_=(const char*)A.exm + (long)par*32768 + w*512; coh_=1; } \
  else { base_=(const char*)A.ex + (long)(((LL)-1)*2+par)*32768 + w*512; coh_=1; } \
  _Pragma("unroll") \
  for (int i_=0;i_<8;++i_){ \
    int rl_=i_*2+(lane>>5); \
    int b_=bh*16+rl_; \
    const char* src_=base_ + (long)b_*1024 + (((lane&31)*16) ^ ((rl_&7)<<4)); \
    char* dst_=Vs + (Q)*32768 + w*8192 + i_*1024 + lane*16; \
    if (coh_) __builtin_amdgcn_global_load_lds((const u32*)src_,(u32*)dst_,16,0,0x11); \
    else      __builtin_amdgcn_global_load_lds((const u32*)src_,(u32*)dst_,16,0,0); \
  } }

// w>=2 lanes: k-slice 512..1023 (own-layer recurrent h, always coherent EX)
#define STAGE_HI(LL, Q) { \
  const char* base_=(const char*)A.ex + (long)((LL)*2+par)*32768 + (w-2)*512; \
  _Pragma("unroll") \
  for (int i_=0;i_<8;++i_){ \
    int rl_=i_*2+(lane>>5); \
    int b_=bh*16+rl_; \
    const char* src_=base_ + (long)b_*1024 + (((lane&31)*16) ^ ((rl_&7)<<4)); \
    char* dst_=Vs + (Q)*32768 + w*8192 + i_*1024 + lane*16; \
    __builtin_amdgcn_global_load_lds((const u32*)src_,(u32*)dst_,16,0,0x11); \
  } }

#define STAGE_ALL(LL, Q, TT) { if (w<2) STAGE_LO(LL, Q, TT) else STAGE_HI(LL, Q) }

#define DOMFMA(LL, Q) { \
  const char* vb_=Vs + (Q)*32768 + w*8192; \
  const int sw_=(cl&7)<<4; \
  f32x4 a0_={0.f,0.f,0.f,0.f}, a1_={0.f,0.f,0.f,0.f}; \
  _Pragma("unroll") \
  for (int f_=0;f_<8;++f_){ \
    union{ bf16x8 v; uint4 q; } aa_; \
    aa_.q = *(const uint4*)(vb_ + cl*512 + ((f_*64+lg*16) ^ sw_)); \
    a0_=__builtin_amdgcn_mfma_f32_16x16x32_bf16(aa_.v, bw[LL][0][f_], a0_,0,0,0); \
    a1_=__builtin_amdgcn_mfma_f32_16x16x32_bf16(aa_.v, bw[LL][1][f_], a1_,0,0,0); \
  } \
  *(f32x4*)&P[(LL)*2560 + (w*32 + cl)*20 + lg*4] = a0_; \
  *(f32x4*)&P[(LL)*2560 + (w*32 + 16 + cl)*20 + lg*4] = a1_; \
  __builtin_amdgcn_sched_barrier(0); }

template<int NL>
__global__ __launch_bounds__(256,1) void pipe2(PA2 A){
  __shared__ __align__(16) char Vs[98304];      // 3 bufs x 4 waves x 8KB
  __shared__ float P[NL*2560];                  // [l][w][32 cols][20]
  const int t = threadIdx.x, wg = blockIdx.x;
  const int bh = wg>>6, cg = wg&63;
  const int w = t>>6, lane = t&63;
  const int cl = lane&15, lg = lane>>4;
  u32* exu  = (u32*)A.ex;    // [NL][2][32][256]
  u32* exmu = (u32*)A.exm;   // [2][32][256]
  // ---- one-time weight preload: per wave, 2 n-tiles x 8 k-frags per layer --
  bf16x8 bw[NL][2][8];
  #pragma unroll
  for (int l=0;l<NL;++l){
    const int kx = A.L[l].kx;
    #pragma unroll
    for (int nt=0; nt<2; ++nt){
      const int c32 = nt*16 + cl;
      const int r = (c32&3)*512 + cg*8 + (c32>>2);
      #pragma unroll
      for (int f=0;f<8;++f){
        union { bf16x8 v; u16 s[8]; } u;
        int k8 = w*256 + f*32 + lg*8;
        if (k8 < 512){
          if (k8 < kx){
            const float* p = A.L[l].Wih + (long)r*kx + k8;
            for (int j=0;j<8;++j) u.s[j]=f2b(p[j]);
          } else { for (int j=0;j<8;++j) u.s[j]=0; }
        } else {
          const float* p = A.L[l].Whh + (long)r*512 + (k8-512);
          for (int j=0;j<8;++j) u.s[j]=f2b(p[j]);
        }
        bw[l][nt][f]=u.v;
      }
    }
  }
  float bias_r[NL][4];
  float cst_r[NL];
  #pragma unroll
  for (int l=0;l<NL;++l) cst_r[l]=0.f;
  if (t<128){
    const int uu = t>>4;
    #pragma unroll
    for (int l=0;l<NL;++l)
      #pragma unroll
      for (int g=0;g<4;++g)
        bias_r[l][g] = A.L[l].bias[g*512 + cg*8 + uu];
  }
  // zero own EX slices (both parities, all layers + EXM for NL==4)
  {
    const int tot = (NL==4)? 640 : 128;
    for (int i=t;i<tot;i+=256){
      int l5=i>>7, rem=i&127;
      int par0=rem>>6, bl=(rem>>2)&15, j=rem&3;
      int b=bh*16+bl;
      u32* p = (l5<NL)? exu + (l5*2+par0)*8192 + b*256 + cg*4 + j
                      : exmu + par0*8192 + b*256 + cg*4 + j;
      cstore(p,0);
    }
  }
  __syncthreads();  // drains vmcnt per wave before flag post
  if (t==0) cstore(&A.flags[wg], A.base+1);
  const int T = A.T;
  unsigned* myflags = A.flags + bh*64;  // bh halves are data-disjoint
  for (int s=0; s<T+NL-1; ++s){
    const int par = (s-1)&1;
    if constexpr (NL==1){
      const int tt0 = A.rev ? (T-1-s) : s;
      if (w<2) STAGE_LO(0,0,tt0)          // plain input: hide under poll
      waitflags(myflags, A.base+s+1, 64);
      if (w>=2) STAGE_HI(0,0)
      VWAIT(0)
      DOMFMA(0,0)
    } else {
      if (s>=3 && s<=T-1){
        // fast path: all 4 layers active; all stages issued up-front
        const int tt0 = A.rev ? (T-1-s) : s;
        if (w<2) STAGE_LO(0,0,tt0)        // plain x: pre-flag
        waitflags(myflags, A.base+s+1, 64);
        if (w>=2) STAGE_HI(0,0)
        STAGE_ALL(1,1,0)
        STAGE_ALL(2,2,0)
        VWAIT(16) DOMFMA(0,0)
        asm volatile("s_waitcnt lgkmcnt(0)" ::: "memory");
        __builtin_amdgcn_sched_barrier(0);
        STAGE_ALL(3,0,0)                   // reuse buf0 (MFMA0 reads retired)
        VWAIT(16) DOMFMA(1,1)
        VWAIT(8)  DOMFMA(2,2)
        VWAIT(0)  DOMFMA(3,0)
      } else {
        waitflags(myflags, A.base+s+1, 64);
        #pragma unroll
        for (int l=0;l<NL;++l){
          const int sc = s-l;
          if (sc<0 || sc>=T) continue;
          const int ttl = A.rev ? (T-1-sc) : sc;
          STAGE_ALL(l, (l&1), ttl)
          VWAIT(0)
          DOMFMA(l, (l&1))
        }
      }
    }
    __syncthreads();
    if (t<128){
      const int bl = t&15, uu = t>>4;
      const int b = bh*16 + bl;
      #pragma unroll
      for (int l=0;l<NL;++l){
        const int sc = s-l;
        if (sc<0 || sc>=T) continue;
        const int tt = A.rev ? (T-1-sc) : sc;
        float g4[4];
        #pragma unroll
        for (int g=0;g<4;++g){
          const int c32 = uu*4+g;
          float sum = bias_r[l][g];
          #pragma unroll
          for (int ww=0;ww<4;++ww) sum += P[l*2560 + (ww*32+c32)*20 + bl];
          g4[g]=sum;
        }
        float c2 = sigm(g4[1])*cst_r[l] + sigm(g4[0])*tanh_f(g4[2]);
        float h2 = sigm(g4[3])*tanh_f(c2);
        cst_r[l]=c2;
        float h2n = __shfl_down(h2, 16);
        if (!(uu&1)){
          u32 pk = (u32)f2b(h2) | ((u32)f2b(h2n)<<16);
          cstore(exu + (l*2+(s&1))*8192 + b*256 + cg*4 + (uu>>1), pk);
        }
        if (NL==4 && l==2){
          float m = A.xm[b*4096 + 4*tt];
          float hm = h2*m;
          float hmn = __shfl_down(hm, 16);
          if (!(uu&1)){
            u32 pk = (u32)f2b(hm) | ((u32)f2b(hmn)<<16);
            cstore(exmu + (s&1)*8192 + b*256 + cg*4 + (uu>>1), pk);
          }
          if (A.L[2].hout) A.L[2].hout[((long)tt*32+b)*512 + cg*8+uu] = f2b(hm);
        } else if (A.L[l].hout){
          float ov = h2;
          if (A.L[l].maskout) ov *= A.xm[b*4096 + 4*tt];
          A.L[l].hout[((long)tt*32+b)*512 + cg*8+uu] = f2b(ov);
        }
      }
    }
    __syncthreads();
    if (t==0) cstore(&A.flags[wg], A.base+s+2);
  }
}

// ---------------- decoder persistent MFMA LSTM (H=256) — R6-proven ----------
__global__ __launch_bounds__(256,1) void dec_rec2(
    const u16* __restrict__ xin, const float* __restrict__ Wih,
    const float* __restrict__ Whh, const float* __restrict__ bias,
    float* __restrict__ dout, u16* __restrict__ exd,
    unsigned* flags, unsigned base, int T)
{
  __shared__ __align__(16) char Vs[49152];
  __shared__ float P[2304];
  __shared__ float cst[128];
  __shared__ float biasl[16];
  const int t = threadIdx.x, wg = blockIdx.x; // 64 WGs
  const int u0 = wg*4;
  const int w = t>>6, lane = t&63, c = lane&15, lg = lane>>4;
  const int r = (c&3)*256 + u0 + (c>>2);
  u32* exu = (u32*)exd; // [2][32][128]
  const int nf = (w<2) ? 8 : 4;
  bf16x8 bw[8];
  #pragma unroll
  for (int f=0;f<8;++f){
    union { bf16x8 v; u16 s[8]; } u;
    if (f < nf){
      if (w<2){
        const float* p = Wih + (long)r*512 + w*256 + f*32 + lg*8;
        for (int j=0;j<8;++j) u.s[j]=f2b(p[j]);
      } else {
        const float* p = Whh + (long)r*256 + (w-2)*128 + f*32 + lg*8;
        for (int j=0;j<8;++j) u.s[j]=f2b(p[j]);
      }
    } else { for (int j=0;j<8;++j) u.s[j]=0; }
    bw[f]=u.v;
  }
  if (t<16) biasl[t] = bias[(t&3)*256 + u0 + (t>>2)];
  if (t<128) cst[t]=0.f;
  if (t<128){
    int par=(t>>6)&1, b=(t>>1)&31, j=t&1;
    cstore(exu + par*4096 + b*128 + wg*2 + j, 0);
  }
  __syncthreads();
  if (t==0) cstore(&flags[wg], base+1);
  const int waveOff = (w<2) ? w*16384 : 32768 + (w-2)*8192;
  const int NI  = (w<2) ? 16 : 8;
  const int rpi = (w<2) ? 2 : 4;
  const int sb  = (w<2) ? (lane>>5) : (lane>>4);
  const int coffb = (w<2) ? (lane&31)*16 : (lane&15)*16;
  const int rowB = (w<2) ? 512 : 256;
  for (int s=0; s<T; ++s){
    // x-half staging is flag-free (ATTFB is plain): issue before poll
    if (w<2){
      #pragma unroll
      for (int i=0;i<16;++i){
        int b = i*rpi + sb;
        const char* src = (const char*)xin + (long)s*32768 + w*512 + b*1024 + (coffb ^ ((b&7)<<4));
        void* ldst = (void*)(Vs + waveOff + i*1024);
        __builtin_amdgcn_global_load_lds((const u32*)src, (u32*)ldst, 16, 0, 0);
      }
    }
    waitflags(flags, base+s+1, 64);
    const int par = (s-1)&1;
    if (w>=2){
      #pragma unroll
      for (int i=0;i<8;++i){
        int b = i*rpi + sb;
        const char* src = (const char*)exd + par*16384 + (w-2)*256 + b*512 + (coffb ^ ((b&7)<<4));
        void* ldst = (void*)(Vs + waveOff + i*1024);
        __builtin_amdgcn_global_load_lds((const u32*)src, (u32*)ldst, 16, 0, 0x11);
      }
    }
    asm volatile("s_waitcnt vmcnt(0)" ::: "memory");
    __builtin_amdgcn_sched_barrier(0);
    f32x4 acc0={0.f,0.f,0.f,0.f}, acc1={0.f,0.f,0.f,0.f};
    const int b1 = c+16;
    #pragma unroll
    for (int f=0;f<8;++f){
      if (f>=nf) break;
      int koff = f*64 + lg*16;
      union { bf16x8 v; uint4 q; } a0, a1;
      a0.q = *(const uint4*)(Vs + waveOff + c *rowB + (koff ^ ((c &7)<<4)));
      a1.q = *(const uint4*)(Vs + waveOff + b1*rowB + (koff ^ ((b1&7)<<4)));
      acc0 = __builtin_amdgcn_mfma_f32_16x16x32_bf16(a0.v, bw[f], acc0, 0,0,0);
      acc1 = __builtin_amdgcn_mfma_f32_16x16x32_bf16(a1.v, bw[f], acc1, 0,0,0);
    }
    {
      float* pp = &P[(w*16+c)*36 + lg*4];
      *(f32x4*)pp      = acc0;
      *(f32x4*)(pp+16) = acc1;
    }
    __syncthreads();
    if (t<128){
      const int b = t&31, uu = t>>5, wpw = t>>6;
      float g4[4];
      #pragma unroll
      for (int g=0; g<4; ++g){
        int cc = uu*4+g;
        float sum = biasl[cc];
        #pragma unroll
        for (int ww=0; ww<4; ++ww) sum += P[(ww*16+cc)*36 + b];
        g4[g]=sum;
      }
      float c2 = sigm(g4[1])*cst[t] + sigm(g4[0])*tanh_f(g4[2]);
      float h2 = sigm(g4[3])*tanh_f(c2);
      cst[t]=c2;
      u32 hv = (u32)f2b(h2);
      u32 ot = (u32)__shfl_xor((int)hv, 32);
      if (lane<32)
        cstore(exu + (s&1)*4096 + b*128 + wg*2 + wpw, (hv&0xffffu)|(ot<<16));
      dout[((long)s*32+b)*256 + u0+uu] = h2;
    }
    __syncthreads();
    if (t==0) cstore(&flags[wg], base+s+2);
  }
}

// ---------------- x pre-convert: fp32 (B,1024,320) -> bf16 [t*32+b][512] ----
__global__ void cvt_x(const float* __restrict__ x, u16* __restrict__ xp){
  long id8 = ((long)blockIdx.x*256 + threadIdx.x)*8;
  int rr = (int)(id8 >> 9); int k = (int)(id8 & 511);
  int tt = rr >> 5, b = rr & 31;
  union { uint4 q; u16 s[8]; } u;
  if (k < 320){
    const float* p = x + (long)b*327680 + (long)tt*320 + k;
    float4 v0 = *(const float4*)p, v1 = *(const float4*)(p+4);
    u.s[0]=f2b(v0.x); u.s[1]=f2b(v0.y); u.s[2]=f2b(v0.z); u.s[3]=f2b(v0.w);
    u.s[4]=f2b(v1.x); u.s[5]=f2b(v1.y); u.s[6]=f2b(v1.z); u.s[7]=f2b(v1.w);
  } else {
    for (int j=0;j<8;++j) u.s[j]=0;
  }
  *(uint4*)(xp + id8) = u.q;
}

// ---------------- MFMA GEMM: C[m,n] = [A0|A1][m,:K] . W[n,:K] + bias[n] -----
template<int ABF, int CBF>
__global__ __launch_bounds__(256,2) void gemm_mfma(
  const void* __restrict__ A0, long lda0, const void* __restrict__ A1, long lda1, int K0,
  const float* __restrict__ W, const float* __restrict__ bias, void* __restrict__ C,
  int M, int N, int K, int ldw, int act)
{
  __shared__ __align__(16) u16 As[64*32];
  __shared__ __align__(16) u16 Bs[64*32];
  const int t = threadIdx.x;
  const int m0 = blockIdx.x*64, n0 = blockIdx.y*64;
  const int w = t>>6, lane = t&63;
  const int al = lane&15, lg = lane>>4;
  f32x4 acc[4];
  #pragma unroll
  for (int i=0;i<4;++i) acc[i] = (f32x4){0.f,0.f,0.f,0.f};
  const int srow = t>>2, kq = t&3;
  const int spos = (kq ^ (srow&3))*8;
  for (int k0=0; k0<K; k0+=32){
    {
      int kk = k0 + kq*8;
      const void* Ab; long lda; int kof;
      if (kk < K0){ Ab=A0; lda=lda0; kof=kk; } else { Ab=A1; lda=lda1; kof=kk-K0; }
      union { uint4 q; u16 s[8]; } u;
      if (ABF){
        u.q = *(const uint4*)((const u16*)Ab + (long)(m0+srow)*lda + kof);
      } else {
        const float* ap = (const float*)Ab + (long)(m0+srow)*lda + kof;
        float4 x0 = *(const float4*)ap, x1 = *(const float4*)(ap+4);
        u.s[0]=f2b(x0.x); u.s[1]=f2b(x0.y); u.s[2]=f2b(x0.z); u.s[3]=f2b(x0.w);
        u.s[4]=f2b(x1.x); u.s[5]=f2b(x1.y); u.s[6]=f2b(x1.z); u.s[7]=f2b(x1.w);
      }
      *(uint4*)&As[srow*32 + spos] = u.q;
    }
    {
      int n = n0 + srow;
      union { uint4 q; u16 s[8]; } u;
      if (n < N){
        const float* wp = W + (long)n*ldw + k0 + kq*8;
        float4 y0 = *(const float4*)wp, y1 = *(const float4*)(wp+4);
        u.s[0]=f2b(y0.x); u.s[1]=f2b(y0.y); u.s[2]=f2b(y0.z); u.s[3]=f2b(y0.w);
        u.s[4]=f2b(y1.x); u.s[5]=f2b(y1.y); u.s[6]=f2b(y1.z); u.s[7]=f2b(y1.w);
      } else {
        for (int j=0;j<8;++j) u.s[j]=0;
      }
      *(uint4*)&Bs[srow*32 + spos] = u.q;
    }
    __syncthreads();
    union { bf16x8 v; uint4 q; } a;
    a.q = *(const uint4*)&As[(w*16+al)*32 + ((lg ^ (al&3))*8)];
    #pragma unroll
    for (int nt=0; nt<4; ++nt){
      union { bf16x8 v; uint4 q; } b;
      b.q = *(const uint4*)&Bs[(nt*16+al)*32 + ((lg ^ (al&3))*8)];
      acc[nt] = __builtin_amdgcn_mfma_f32_16x16x32_bf16(a.v, b.v, acc[nt], 0,0,0);
    }
    __syncthreads();
  }
  #pragma unroll
  for (int nt=0; nt<4; ++nt){
    int n = n0 + nt*16 + al;
    if (n >= N) continue;
    float bv = bias[n];
    #pragma unroll
    for (int j=0;j<4;++j){
      int m = m0 + w*16 + lg*4 + j;
      float v = acc[nt][j] + bv;
      if (act) v = (v > 0.f) ? v : 0.1f*v;
      if (CBF) ((u16*)C)[(long)m*N + n] = f2b(v);
      else     ((float*)C)[(long)m*N + n] = v;
    }
  }
}

// ---------------- elementwise helpers --------------------------------------
__global__ void mask_bf16(u16* __restrict__ buf, int F, const float* __restrict__ xm){
  long id8 = ((long)blockIdx.x*256 + threadIdx.x)*8;
  int row = (int)(id8 / F);
  int tt = row>>5, b = row&31;
  float m = xm[b*4096 + 4*tt];
  union { uint4 q; u16 s[8]; } u;
  u.q = *(uint4*)(buf + id8);
  #pragma unroll
  for (int j=0;j<8;++j) u.s[j] = f2b(b2f(u.s[j])*m);
  *(uint4*)(buf + id8) = u.q;
}

__global__ void embed_gather(const float* __restrict__ emb, const int* __restrict__ y,
                             float* __restrict__ out){
  int id = blockIdx.x*256 + threadIdx.x;
  int p = id&255, r = id>>8;
  int l = r>>5, b = r&31;
  out[id] = emb[(long)y[b*65 + l]*256 + p];
}

__global__ void zero_f(float* __restrict__ p, int n){
  int id = blockIdx.x*256 + threadIdx.x;
  if (id < n) p[id] = 0.f;
}

__global__ void set_val(float* p, float v){ p[0] = v; }

__global__ void attfea_k(const float* __restrict__ lstms, const float* __restrict__ ctxs,
                         const float* __restrict__ ym, float* __restrict__ attf,
                         u16* __restrict__ attfb){
  long id4 = ((long)blockIdx.x*256 + threadIdx.x)*4;
  int r = (int)(id4>>9); int f = (int)(id4&511);
  int l = r>>5, b = r&31;
  float m = ym[b*65 + l + 1];
  float4 v = (f<256) ? *(const float4*)(lstms + (long)r*256 + f)
                     : *(const float4*)(ctxs  + (long)r*256 + (f-256));
  v.x*=m; v.y*=m; v.z*=m; v.w*=m;
  *(float4*)(attf + id4) = v;
  u16* ob = attfb + id4;
  ob[0]=f2b(v.x); ob[1]=f2b(v.y); ob[2]=f2b(v.z); ob[3]=f2b(v.w);
}

__global__ void dcat_k(const float* __restrict__ attf, const float* __restrict__ dout,
                       const float* __restrict__ ym, float* __restrict__ dcat){
  long id4 = ((long)blockIdx.x*256 + threadIdx.x)*4;
  int r = (int)(id4/768); int f = (int)(id4 - (long)r*768);
  int l = r>>5, b = r&31;
  float m = ym[b*65 + l + 1];
  float4 v = (f<512) ? *(const float4*)(attf + (long)r*512 + f)
                     : *(const float4*)(dout + (long)r*256 + (f-512));
  v.x*=m; v.y*=m; v.z*=m; v.w*=m;
  *(float4*)(dcat + id4) = v;
}

// ---------------- decoder attention step kernels ----------------------------
__global__ __launch_bounds__(256,1) void k1_dec(
  const float* __restrict__ bodyR, float* __restrict__ bodyW,
  const float* __restrict__ epart, const float* __restrict__ Whh,
  const float* __restrict__ Wih, float* __restrict__ cc,
  float* __restrict__ lstms, int s)
{
  __shared__ __align__(16) float vT[512*36];
  __shared__ float gl[32*32];
  const int t = threadIdx.x, wg = blockIdx.x;
  for (int i = t*4; i < 32*512; i += 1024){
    int b = i>>9, k = i&511;
    float4 v = *(const float4*)(bodyR + b*512 + k);
    vT[(k+0)*36+b]=v.x; vT[(k+1)*36+b]=v.y; vT[(k+2)*36+b]=v.z; vT[(k+3)*36+b]=v.w;
  }
  __syncthreads();
  const int c_l = t>>3, bq = t&7;
  const int col = (c_l&3)*256 + wg*8 + (c_l>>2);
  float a0=0.f,a1=0.f,a2=0.f,a3=0.f;
  for (int k=0;k<256;k+=4){
    float4 w = *(const float4*)(Whh + (long)col*256 + k);
    const float* vp = &vT[k*36 + bq*4];
    float4 v0=*(const float4*)(vp), v1=*(const float4*)(vp+36), v2=*(const float4*)(vp+72), v3=*(const float4*)(vp+108);
    a0 += w.x*v0.x + w.y*v1.x + w.z*v2.x + w.w*v3.x;
    a1 += w.x*v0.y + w.y*v1.y + w.z*v2.y + w.w*v3.y;
    a2 += w.x*v0.z + w.y*v1.z + w.z*v2.z + w.w*v3.z;
    a3 += w.x*v0.w + w.y*v1.w + w.z*v2.w + w.w*v3.w;
  }
  for (int k=256;k<512;k+=4){
    float4 w = *(const float4*)(Wih + (long)col*512 + k);
    const float* vp = &vT[k*36 + bq*4];
    float4 v0=*(const float4*)(vp), v1=*(const float4*)(vp+36), v2=*(const float4*)(vp+72), v3=*(const float4*)(vp+108);
    a0 += w.x*v0.x + w.y*v1.x + w.z*v2.x + w.w*v3.x;
    a1 += w.x*v0.y + w.y*v1.y + w.z*v2.y + w.w*v3.y;
    a2 += w.x*v0.z + w.y*v1.z + w.z*v2.z + w.w*v3.z;
    a3 += w.x*v0.w + w.y*v1.w + w.z*v2.w + w.w*v3.w;
  }
  gl[c_l*32+bq*4+0] = a0 + epart[((long)s*32 + bq*4+0)*1024 + col];
  gl[c_l*32+bq*4+1] = a1 + epart[((long)s*32 + bq*4+1)*1024 + col];
  gl[c_l*32+bq*4+2] = a2 + epart[((long)s*32 + bq*4+2)*1024 + col];
  gl[c_l*32+bq*4+3] = a3 + epart[((long)s*32 + bq*4+3)*1024 + col];
  __syncthreads();
  {
    const int u_ = t>>5, b = t&31, ug = wg*8 + u_;
    const float gi=gl[(u_*4+0)*32+b], gf=gl[(u_*4+1)*32+b], gg=gl[(u_*4+2)*32+b], go=gl[(u_*4+3)*32+b];
    float c0 = cc[b*256+ug];
    float c2 = sigm(gf)*c0 + sigm(gi)*tanh_f(gg);
    float h2 = sigm(go)*tanh_f(c2);
    cc[b*256+ug] = c2;
    bodyW[b*512 + ug] = h2;
    lstms[((long)s*32 + b)*256 + ug] = h2;
  }
}

__global__ __launch_bounds__(256,1) void k2_dec(
  const float* __restrict__ bodyW, const float* __restrict__ vW,
  const float* __restrict__ vb, float* __restrict__ state)
{
  __shared__ __align__(16) float hT[256*36];
  const int t = threadIdx.x, wg = blockIdx.x;
  for (int i = t*4; i < 8192; i += 1024){
    int b = i>>8, k = i&255;
    float4 v = *(const float4*)(bodyW + b*512 + k);
    hT[(k+0)*36+b]=v.x; hT[(k+1)*36+b]=v.y; hT[(k+2)*36+b]=v.z; hT[(k+3)*36+b]=v.w;
  }
  __syncthreads();
  const int p = wg*32 + (t>>3), bq = t&7;
  float a0=0.f,a1=0.f,a2=0.f,a3=0.f;
  for (int k=0;k<256;k+=4){
    float4 w = *(const float4*)(vW + (long)p*256 + k);
    const float* vp = &hT[k*36 + bq*4];
    float4 v0=*(const float4*)(vp), v1=*(const float4*)(vp+36), v2=*(const float4*)(vp+72), v3=*(const float4*)(vp+108);
    a0 += w.x*v0.x + w.y*v1.x + w.z*v2.x + w.w*v3.x;
    a1 += w.x*v0.y + w.y*v1.y + w.z*v2.y + w.w*v3.y;
    a2 += w.x*v0.z + w.y*v1.z + w.z*v2.z + w.w*v3.z;
    a3 += w.x*v0.w + w.y*v1.w + w.z*v2.w + w.w*v3.w;
  }
  float bb = vb[p];
  state[(bq*4+0)*256 + p] = a0 + bb;
  state[(bq*4+1)*256 + p] = a1 + bb;
  state[(bq*4+2)*256 + p] = a2 + bb;
  state[(bq*4+3)*256 + p] = a3 + bb;
}

__global__ __launch_bounds__(256,1) void k3_dec(
  const float* __restrict__ state, const u16* __restrict__ atth,
  const float* __restrict__ wav, const float* __restrict__ xm,
  float* __restrict__ sc, float* __restrict__ scm)
{
  __shared__ float st[256], wv[256], red[256];
  const int t = threadIdx.x;
  const int b = blockIdx.x>>2, ch = blockIdx.x&3;
  st[t] = state[b*256 + t];
  wv[t] = wav[t];
  __syncthreads();
  const int tp = ch*256 + t;
  const u16* ap = atth + ((long)tp*32 + b)*256;
  float acc = 0.f;
  for (int p=0;p<256;p+=4){
    ushort4 a = *(const ushort4*)(ap+p);
    acc += wv[p+0]*tanh_f(st[p+0]+b2f(a.x));
    acc += wv[p+1]*tanh_f(st[p+1]+b2f(a.y));
    acc += wv[p+2]*tanh_f(st[p+2]+b2f(a.z));
    acc += wv[p+3]*tanh_f(st[p+3]+b2f(a.w));
  }
  acc += (xm[b*4096 + 4*tp] - 1.0f)*1e30f;
  sc[b*1024 + tp] = acc;
  red[t] = acc;
  __syncthreads();
  for (int o=128;o>0;o>>=1){ if (t<o) red[t]=fmaxf(red[t],red[t+o]); __syncthreads(); }
  if (t==0) scm[b*4+ch] = red[0];
}

__global__ __launch_bounds__(256,1) void k4_dec(
  const float* __restrict__ sc, const float* __restrict__ scm,
  const u16* __restrict__ eout, float* __restrict__ ctxs,
  float* __restrict__ bodyW, int s)
{
  __shared__ float al[1024];
  __shared__ float red[256];
  const int t = threadIdx.x, b = blockIdx.x;
  float m = fmaxf(fmaxf(scm[b*4+0],scm[b*4+1]), fmaxf(scm[b*4+2],scm[b*4+3]));
  float ps = 0.f;
  #pragma unroll
  for (int j=0;j<4;++j){
    int tp = t + j*256;
    float e = __expf(sc[b*1024+tp] - m);
    al[tp] = e; ps += e;
  }
  red[t]=ps; __syncthreads();
  for (int o=128;o>0;o>>=1){ if (t<o) red[t]+=red[t+o]; __syncthreads(); }
  float rinv = 1.0f/red[0];
  float acc = 0.f;
  const u16* ep = eout + b*256 + t;
  for (int tp=0;tp<1024;++tp) acc += al[tp] * b2f(ep[(long)tp*8192]);
  float cv = acc*rinv;
  ctxs[((long)s*32 + b)*256 + t] = cv;
  bodyW[b*512 + 256 + t] = cv;
}

// ---------------- loss ------------------------------------------------------
__global__ __launch_bounds__(256,1) void loss_row(
  const float* __restrict__ logits, const int* __restrict__ y,
  const float* __restrict__ ym, float* __restrict__ rows)
{
  __shared__ float red[256];
  const int r = blockIdx.x, t = threadIdx.x;
  const float* row = logits + (long)r*4235;
  float mx = -3.0e38f;
  for (int i=t;i<4235;i+=256) mx = fmaxf(mx, row[i]);
  red[t]=mx; __syncthreads();
  for (int o=128;o>0;o>>=1){ if (t<o) red[t]=fmaxf(red[t],red[t+o]); __syncthreads(); }
  const float M = red[0];
  __syncthreads();
  float se=0.f, sl=0.f;
  for (int i=t;i<4235;i+=256){ float v=row[i]; se += __expf(v-M); sl += v; }
  red[t]=se; __syncthreads();
  for (int o=128;o>0;o>>=1){ if (t<o) red[t]+=red[t+o]; __syncthreads(); }
  const float SE = red[0];
  __syncthreads();
  red[t]=sl; __syncthreads();
  for (int o=128;o>0;o>>=1){ if (t<o) red[t]+=red[t+o]; __syncthreads(); }
  const float SL = red[0];
  if (t==0){
    const int tt = r>>5, b = r&31;
    const float lse = M + logf(SE);
    const float mk = (ym[b*65 + tt + 1] > 0.f) ? 1.f : 0.f;
    rows[r]        = (4235.0f*lse - SL)*mk;
    rows[2048 + r] = (lse - row[y[b*65 + tt + 1]])*mk;
    rows[4096 + r] = mk;
  }
}

__global__ __launch_bounds__(256,1) void loss_final(const float* __restrict__ rows, float* __restrict__ out){
  __shared__ float red[256];
  const int t = threadIdx.x;
  float s1=0.f,s2=0.f,s3=0.f;
  for (int i=t;i<2048;i+=256){ s1+=rows[i]; s2+=rows[2048+i]; s3+=rows[4096+i]; }
  red[t]=s1; __syncthreads();
  for (int o=128;o>0;o>>=1){ if (t<o) red[t]+=red[t+o]; __syncthreads(); }
  const float S = red[0]; __syncthreads();
  red[t]=s2; __syncthreads();
  for (int o=128;o>0;o>>=1){ if (t<o) red[t]+=red[t+o]; __syncthreads(); }
  const float NL = red[0]; __syncthreads();
  red[t]=s3; __syncthreads();
  for (int o=128;o>0;o>>=1){ if (t<o) red[t]+=red[t+o]; __syncthreads(); }
  const float N = red[0];
  if (t==0){
    float n = (N > 0.f) ? N : 1.f;
    out[0] = (S/n)*(0.1f/4235.0f) + 0.9f*(NL/n);
  }
}

// ---------------- launcher --------------------------------------------------
extern "C" void kernel_launch(void* const* d_in, const int* in_sizes, int n_in,
                              void* d_out, int out_size, void* d_ws, size_t ws_size,
                              hipStream_t stream)
{
  const float* x    = (const float*)d_in[0];
  const float* xm   = (const float*)d_in[1];
  const int*   y    = (const int*)  d_in[2];
  const float* ym   = (const float*)d_in[3];
  const float* l1_Wih=(const float*)d_in[4];  const float* l1_Whh=(const float*)d_in[5];  const float* l1_b=(const float*)d_in[6];
  const float* l2_Wih=(const float*)d_in[7];  const float* l2_Whh=(const float*)d_in[8];  const float* l2_b=(const float*)d_in[9];
  const float* l3_Wih=(const float*)d_in[10]; const float* l3_Whh=(const float*)d_in[11]; const float* l3_b=(const float*)d_in[12];
  const float* bf_Wih=(const float*)d_in[13]; const float* bf_Whh=(const float*)d_in[14]; const float* bf_b=(const float*)d_in[15];
  const float* bb_Wih=(const float*)d_in[16]; const float* bb_Whh=(const float*)d_in[17]; const float* bb_b=(const float*)d_in[18];
  const float* c1_W=(const float*)d_in[19]; const float* c1_b=(const float*)d_in[20];
  const float* c2_W=(const float*)d_in[21]; const float* c2_b=(const float*)d_in[22];
  const float* emb =(const float*)d_in[23];
  const float* att_Wih=(const float*)d_in[24]; const float* att_Whh=(const float*)d_in[25]; const float* att_b=(const float*)d_in[26];
  const float* w_W=(const float*)d_in[27]; const float* w_b=(const float*)d_in[28];
  const float* v_W=(const float*)d_in[29]; const float* v_b=(const float*)d_in[30];
  const float* wav=(const float*)d_in[31];
  const float* dec_Wih=(const float*)d_in[32]; const float* dec_Whh=(const float*)d_in[33]; const float* dec_b=(const float*)d_in[34];
  const float* cls_W=(const float*)d_in[35]; const float* cls_b=(const float*)d_in[36];

  const size_t REQ = 137625600ull; // ~131.3 MiB (verified fit)
  if (ws_size < REQ){
    set_val<<<1,1,0,stream>>>((float*)d_out, -(float)(ws_size>>20));
    return;
  }
  char* ws = (char*)d_ws;
  unsigned* FLAGS = (unsigned*)(ws);            // 512B (dense, R6 layout)
  u16* EXU  = (u16*)(ws + 65536);               // 4x2x32x512 = 256KB
  u16* EXM  = (u16*)(ws + 327680);              // 2x32x512 = 64KB
  u16* EXD  = (u16*)(ws + 393216);              // 2x32x256 = 32KB
  u16* XP   = (u16*)(ws + 2097152);             // 32MB
  u16* HS2  = (u16*)(ws + 35651584);            // 32MB (masked h3)
  u16* HSF  = (u16*)(ws + 69206016);            // 32MB (masked bf)
  u16* HSB  = XP;                               // masked bb overlays XP
  u16* C1OUT = HS2;                             // after bb done
  u16* EOUTB = HSF;                             // 16MB (HSF dead after conv1)
  u16* ATTHB = (u16*)(ws + 85983232);           // 16MB
  float* LOGIT = (float*)XP;                    // after conv2
  float* AR    = (float*)(ws + 102760448);      // decoder arena
  float* EMBED = AR;
  float* EPART = EMBED + 524288;
  float* LSTMS = EPART + 2097152;
  float* CTXS  = LSTMS + 524288;
  float* ATTF  = CTXS  + 524288;
  float* DOUT  = ATTF  + 1048576;
  float* DCAT  = DOUT  + 524288;
  float* SC    = DCAT  + 1572864;
  float* SCM   = SC    + 32768;
  float* ROWS  = SCM   + 128;
  float* BODY  = ROWS  + 6144;
  float* CC    = BODY  + 32768;
  float* STATE = CC    + 8192;
  u16*  ATTFB  = (u16*)(STATE + 8192);

  (void)hipMemsetAsync(ws, 0, 4096, stream);

  // ---------------- encoder: phase A (l1,l2,l3,bf pipelined, fence-free) ----
  cvt_x<<<8192,256,0,stream>>>(x, XP);
  PA2 pa;
  pa.L[0] = { l1_Wih, l1_Whh, l1_b, XP,      nullptr, 320, 0 };
  pa.L[1] = { l2_Wih, l2_Whh, l2_b, nullptr, nullptr, 512, 0 };
  pa.L[2] = { l3_Wih, l3_Whh, l3_b, nullptr, HS2,     512, 0 };
  pa.L[3] = { bf_Wih, bf_Whh, bf_b, nullptr, HSF,     512, 1 };
  pa.ex = EXU; pa.exm = EXM; pa.xm = xm; pa.flags = FLAGS;
  pa.T = 1024; pa.nwg = 128; pa.rev = 0; pa.base = 0;
  pipe2<4><<<128,256,0,stream>>>(pa);
  // ---------------- encoder: phase B (bb, reverse) --------------------------
  PA2 pb;
  pb.L[0] = { bb_Wih, bb_Whh, bb_b, HS2, HSB, 512, 1 };
  pb.L[1] = pb.L[0]; pb.L[2] = pb.L[0]; pb.L[3] = pb.L[0];
  pb.ex = EXU; pb.exm = EXM; pb.xm = xm; pb.flags = FLAGS;
  pb.T = 1024; pb.nwg = 128; pb.rev = 1; pb.base = 1028;
  pipe2<1><<<128,256,0,stream>>>(pb);
  // conv1 (leaky) on concat [bf|bb], conv2, mask, att_h — MFMA GEMMs
  gemm_mfma<1,1><<<dim3(512,8),256,0,stream>>>(HSF, 512, HSB, 512, 512,
      c1_W, c1_b, C1OUT, 32768, 512, 1024, 1024, 1);
  gemm_mfma<1,1><<<dim3(512,4),256,0,stream>>>(C1OUT, 512, C1OUT, 512, 512,
      c2_W, c2_b, EOUTB, 32768, 256, 512, 512, 0);
  mask_bf16<<<4096,256,0,stream>>>(EOUTB, 256, xm);
  gemm_mfma<1,1><<<dim3(512,4),256,0,stream>>>(EOUTB, 256, EOUTB, 256, 256,
      w_W, w_b, ATTHB, 32768, 256, 256, 256, 0);

  // ---------------- decoder -------------------------------------------------
  embed_gather<<<2048,256,0,stream>>>(emb, y, EMBED);
  gemm_mfma<0,0><<<dim3(32,16),256,0,stream>>>(EMBED, 256, EMBED, 256, 256,
      att_Wih, att_b, EPART, 2048, 1024, 256, 512, 0);
  zero_f<<<160,256,0,stream>>>(BODY, 40960);
  for (int s=0;s<64;++s){
    float* bodyR = BODY + (s&1)*16384;
    float* bodyW = BODY + ((s+1)&1)*16384;
    k1_dec<<<32,256,0,stream>>>(bodyR, bodyW, EPART, att_Whh, att_Wih, CC, LSTMS, s);
    k2_dec<<<8,256,0,stream>>>(bodyW, v_W, v_b, STATE);
    k3_dec<<<128,256,0,stream>>>(STATE, ATTHB, wav, xm, SC, SCM);
    k4_dec<<<32,256,0,stream>>>(SC, SCM, EOUTB, CTXS, bodyW, s);
  }
  attfea_k<<<1024,256,0,stream>>>(LSTMS, CTXS, ym, ATTF, ATTFB);
  dec_rec2<<<64,256,0,stream>>>(ATTFB, dec_Wih, dec_Whh, dec_b,
      DOUT, EXD, FLAGS, 2053u, 64);
  dcat_k<<<1536,256,0,stream>>>(ATTF, DOUT, ym, DCAT);
  gemm_mfma<0,0><<<dim3(32,67),256,0,stream>>>(DCAT, 768, DCAT, 768, 768,
      cls_W, cls_b, LOGIT, 2048, 4235, 768, 768, 0);
  loss_row<<<2048,256,0,stream>>>(LOGIT, y, ym, ROWS);
  loss_final<<<1,256,0,stream>>>(ROWS, (float*)d_out);
}

// Round 12
// 18234.344 us; speedup vs baseline: 14.7734x; 1.1614x over previous
//
#include <hip/hip_runtime.h>
#include <math.h>

#define DEV static __device__ __forceinline__
typedef unsigned short u16;
typedef unsigned int u32;

typedef __attribute__((ext_vector_type(8))) __bf16 bf16x8;
typedef __attribute__((ext_vector_type(4))) float f32x4;

DEV float sigm(float x){ return 1.0f/(1.0f+__expf(-x)); }
DEV float tanh_f(float x){ float e=__expf(2.0f*x); return 1.0f - 2.0f/(e+1.0f); }

DEV float b2f(u16 u){ union {u32 i; float f;} c; c.i = ((u32)u)<<16; return c.f; }
DEV u16 f2b(float f){ union {u32 i; float f;} c; c.f = f; u32 r = (c.i + 0x7FFFu + ((c.i>>16)&1u)) >> 16; return (u16)r; }

// coherent (cross-XCD) dword ops — system scope, relaxed (verified R6)
DEV void cstore(u32* p, u32 v){ __hip_atomic_store(p, v, __ATOMIC_RELAXED, __HIP_MEMORY_SCOPE_SYSTEM); }
DEV u32  cload(const u32* p){ return __hip_atomic_load(p, __ATOMIC_RELAXED, __HIP_MEMORY_SCOPE_SYSTEM); }

// R12: flags padded to one per 128B cacheline (index stride 32 u32).
// Poll protocol identical to R6/R9/R10/R11 — ALL threads poll.
#define FSTRIDE 32
DEV void waitflags(unsigned* flags, unsigned target, int nwg){
  const int lane = threadIdx.x & 63;
  unsigned long long spin = 0;
  for(;;){
    bool ok = true;
    for (int j=lane; j<nwg; j+=64)
      ok &= ((int)(cload(&flags[j*FSTRIDE]) - target) >= 0);
    if (__all(ok)) break;
    if (++spin > 2000000ull) break; // safety: garbage instead of hang
    __builtin_amdgcn_s_sleep(1);
  }
}

// ---------------- pipelined persistent MFMA LSTM (H=512) --------------------
// 128 WGs = 2 batch-halves x 64 col-groups (bh halves data-disjoint -> each
// waits only its own 64 flags). All stages issued up-front (3 LDS bufs);
// plain (x) inputs staged BEFORE the flag wait. Ordering identical to R6.
struct PL2 { const float *Wih, *Whh, *bias; const u16* xplain; u16* hout; int kx, maskout; };
struct PA2 {
  PL2 L[4];
  u16* ex;        // [NL][2][32][512] u16
  u16* exm;       // [2][32][512] u16 (masked l3 output, phase A only)
  const float* xm;
  unsigned* flags;
  int T, nwg, rev; unsigned base;
};

#define VWAIT(N) { asm volatile("s_waitcnt vmcnt(" #N ")" ::: "memory"); __builtin_amdgcn_sched_barrier(0); }

// w<2 lanes: k-slice 0..511 ("x side" of the layer input)
#define STAGE_LO(LL, Q, TT) { \
  const char* base_; int coh_; \
  if ((LL)==0){ base_=(const char*)A.L[0].xplain + ((long)(TT)*32768) + w*512; coh_=0; } \
  else if (NL==4 && (LL)==3){ base_=(const char*)A.exm + (long)par*32768 + w*512; coh_=1; } \
  else { base_=(const char*)A.ex + (long)(((LL)-1)*2+par)*32768 + w*512; coh_=1; } \
  _Pragma("unroll") \
  for (int i_=0;i_<8;++i_){ \
    int rl_=i_*2+(lane>>5); \
    int b_=bh*16+rl_; \
    const char* src_=base_ + (long)b_*1024 + (((lane&31)*16) ^ ((rl_&7)<<4)); \
    char* dst_=Vs + (Q)*32768 + w*8192 + i_*1024 + lane*16; \
    if (coh_) __builtin_amdgcn_global_load_lds((const u32*)src_,(u32*)dst_,16,0,0x11); \
    else      __builtin_amdgcn_global_load_lds((const u32*)src_,(u32*)dst_,16,0,0); \
  } }

// w>=2 lanes: k-slice 512..1023 (own-layer recurrent h, always coherent EX)
#define STAGE_HI(LL, Q) { \
  const char* base_=(const char*)A.ex + (long)((LL)*2+par)*32768 + (w-2)*512; \
  _Pragma("unroll") \
  for (int i_=0;i_<8;++i_){ \
    int rl_=i_*2+(lane>>5); \
    int b_=bh*16+rl_; \
    const char* src_=base_ + (long)b_*1024 + (((lane&31)*16) ^ ((rl_&7)<<4)); \
    char* dst_=Vs + (Q)*32768 + w*8192 + i_*1024 + lane*16; \
    __builtin_amdgcn_global_load_lds((const u32*)src_,(u32*)dst_,16,0,0x11); \
  } }

#define STAGE_ALL(LL, Q, TT) { if (w<2) STAGE_LO(LL, Q, TT) else STAGE_HI(LL, Q) }

#define DOMFMA(LL, Q) { \
  const char* vb_=Vs + (Q)*32768 + w*8192; \
  const int sw_=(cl&7)<<4; \
  f32x4 a0_={0.f,0.f,0.f,0.f}, a1_={0.f,0.f,0.f,0.f}; \
  _Pragma("unroll") \
  for (int f_=0;f_<8;++f_){ \
    union{ bf16x8 v; uint4 q; } aa_; \
    aa_.q = *(const uint4*)(vb_ + cl*512 + ((f_*64+lg*16) ^ sw_)); \
    a0_=__builtin_amdgcn_mfma_f32_16x16x32_bf16(aa_.v, bw[LL][0][f_], a0_,0,0,0); \
    a1_=__builtin_amdgcn_mfma_f32_16x16x32_bf16(aa_.v, bw[LL][1][f_], a1_,0,0,0); \
  } \
  *(f32x4*)&P[(LL)*2560 + (w*32 + cl)*20 + lg*4] = a0_; \
  *(f32x4*)&P[(LL)*2560 + (w*32 + 16 + cl)*20 + lg*4] = a1_; \
  __builtin_amdgcn_sched_barrier(0); }

template<int NL>
__global__ __launch_bounds__(256,1) void pipe2(PA2 A){
  __shared__ __align__(16) char Vs[98304];      // 3 bufs x 4 waves x 8KB
  __shared__ float P[NL*2560];                  // [l][w][32 cols][20]
  const int t = threadIdx.x, wg = blockIdx.x;
  const int bh = wg>>6, cg = wg&63;
  const int w = t>>6, lane = t&63;
  const int cl = lane&15, lg = lane>>4;
  u32* exu  = (u32*)A.ex;    // [NL][2][32][256]
  u32* exmu = (u32*)A.exm;   // [2][32][256]
  // ---- one-time weight preload: per wave, 2 n-tiles x 8 k-frags per layer --
  bf16x8 bw[NL][2][8];
  #pragma unroll
  for (int l=0;l<NL;++l){
    const int kx = A.L[l].kx;
    #pragma unroll
    for (int nt=0; nt<2; ++nt){
      const int c32 = nt*16 + cl;
      const int r = (c32&3)*512 + cg*8 + (c32>>2);
      #pragma unroll
      for (int f=0;f<8;++f){
        union { bf16x8 v; u16 s[8]; } u;
        int k8 = w*256 + f*32 + lg*8;
        if (k8 < 512){
          if (k8 < kx){
            const float* p = A.L[l].Wih + (long)r*kx + k8;
            for (int j=0;j<8;++j) u.s[j]=f2b(p[j]);
          } else { for (int j=0;j<8;++j) u.s[j]=0; }
        } else {
          const float* p = A.L[l].Whh + (long)r*512 + (k8-512);
          for (int j=0;j<8;++j) u.s[j]=f2b(p[j]);
        }
        bw[l][nt][f]=u.v;
      }
    }
  }
  float bias_r[NL][4];
  float cst_r[NL];
  #pragma unroll
  for (int l=0;l<NL;++l) cst_r[l]=0.f;
  if (t<128){
    const int uu = t>>4;
    #pragma unroll
    for (int l=0;l<NL;++l)
      #pragma unroll
      for (int g=0;g<4;++g)
        bias_r[l][g] = A.L[l].bias[g*512 + cg*8 + uu];
  }
  // zero own EX slices (both parities, all layers + EXM for NL==4)
  {
    const int tot = (NL==4)? 640 : 128;
    for (int i=t;i<tot;i+=256){
      int l5=i>>7, rem=i&127;
      int par0=rem>>6, bl=(rem>>2)&15, j=rem&3;
      int b=bh*16+bl;
      u32* p = (l5<NL)? exu + (l5*2+par0)*8192 + b*256 + cg*4 + j
                      : exmu + par0*8192 + b*256 + cg*4 + j;
      cstore(p,0);
    }
  }
  __syncthreads();  // drains vmcnt per wave before flag post
  if (t==0) cstore(&A.flags[wg*FSTRIDE], A.base+1);
  const int T = A.T;
  unsigned* myflags = A.flags + (bh*64)*FSTRIDE;  // bh halves are data-disjoint
  for (int s=0; s<T+NL-1; ++s){
    const int par = (s-1)&1;
    if constexpr (NL==1){
      const int tt0 = A.rev ? (T-1-s) : s;
      if (w<2) STAGE_LO(0,0,tt0)          // plain input: hide under poll
      waitflags(myflags, A.base+s+1, 64);
      if (w>=2) STAGE_HI(0,0)
      VWAIT(0)
      DOMFMA(0,0)
    } else {
      if (s>=3 && s<=T-1){
        // fast path: all 4 layers active; all stages issued up-front
        const int tt0 = A.rev ? (T-1-s) : s;
        if (w<2) STAGE_LO(0,0,tt0)        // plain x: pre-flag
        waitflags(myflags, A.base+s+1, 64);
        if (w>=2) STAGE_HI(0,0)
        STAGE_ALL(1,1,0)
        STAGE_ALL(2,2,0)
        VWAIT(16) DOMFMA(0,0)
        asm volatile("s_waitcnt lgkmcnt(0)" ::: "memory");
        __builtin_amdgcn_sched_barrier(0);
        STAGE_ALL(3,0,0)                   // reuse buf0 (MFMA0 reads retired)
        VWAIT(16) DOMFMA(1,1)
        VWAIT(8)  DOMFMA(2,2)
        VWAIT(0)  DOMFMA(3,0)
      } else {
        waitflags(myflags, A.base+s+1, 64);
        #pragma unroll
        for (int l=0;l<NL;++l){
          const int sc = s-l;
          if (sc<0 || sc>=T) continue;
          const int ttl = A.rev ? (T-1-sc) : sc;
          STAGE_ALL(l, (l&1), ttl)
          VWAIT(0)
          DOMFMA(l, (l&1))
        }
      }
    }
    __syncthreads();
    if (t<128){
      const int bl = t&15, uu = t>>4;
      const int b = bh*16 + bl;
      #pragma unroll
      for (int l=0;l<NL;++l){
        const int sc = s-l;
        if (sc<0 || sc>=T) continue;
        const int tt = A.rev ? (T-1-sc) : sc;
        float g4[4];
        #pragma unroll
        for (int g=0;g<4;++g){
          const int c32 = uu*4+g;
          float sum = bias_r[l][g];
          #pragma unroll
          for (int ww=0;ww<4;++ww) sum += P[l*2560 + (ww*32+c32)*20 + bl];
          g4[g]=sum;
        }
        float c2 = sigm(g4[1])*cst_r[l] + sigm(g4[0])*tanh_f(g4[2]);
        float h2 = sigm(g4[3])*tanh_f(c2);
        cst_r[l]=c2;
        float h2n = __shfl_down(h2, 16);
        if (!(uu&1)){
          u32 pk = (u32)f2b(h2) | ((u32)f2b(h2n)<<16);
          cstore(exu + (l*2+(s&1))*8192 + b*256 + cg*4 + (uu>>1), pk);
        }
        if (NL==4 && l==2){
          float m = A.xm[b*4096 + 4*tt];
          float hm = h2*m;
          float hmn = __shfl_down(hm, 16);
          if (!(uu&1)){
            u32 pk = (u32)f2b(hm) | ((u32)f2b(hmn)<<16);
            cstore(exmu + (s&1)*8192 + b*256 + cg*4 + (uu>>1), pk);
          }
          if (A.L[2].hout) A.L[2].hout[((long)tt*32+b)*512 + cg*8+uu] = f2b(hm);
        } else if (A.L[l].hout){
          float ov = h2;
          if (A.L[l].maskout) ov *= A.xm[b*4096 + 4*tt];
          A.L[l].hout[((long)tt*32+b)*512 + cg*8+uu] = f2b(ov);
        }
      }
    }
    __syncthreads();
    if (t==0) cstore(&A.flags[wg*FSTRIDE], A.base+s+2);
  }
}

// ---------------- decoder persistent MFMA LSTM (H=256) — R6-proven ----------
__global__ __launch_bounds__(256,1) void dec_rec2(
    const u16* __restrict__ xin, const float* __restrict__ Wih,
    const float* __restrict__ Whh, const float* __restrict__ bias,
    float* __restrict__ dout, u16* __restrict__ exd,
    unsigned* flags, unsigned base, int T)
{
  __shared__ __align__(16) char Vs[49152];
  __shared__ float P[2304];
  __shared__ float cst[128];
  __shared__ float biasl[16];
  const int t = threadIdx.x, wg = blockIdx.x; // 64 WGs
  const int u0 = wg*4;
  const int w = t>>6, lane = t&63, c = lane&15, lg = lane>>4;
  const int r = (c&3)*256 + u0 + (c>>2);
  u32* exu = (u32*)exd; // [2][32][128]
  const int nf = (w<2) ? 8 : 4;
  bf16x8 bw[8];
  #pragma unroll
  for (int f=0;f<8;++f){
    union { bf16x8 v; u16 s[8]; } u;
    if (f < nf){
      if (w<2){
        const float* p = Wih + (long)r*512 + w*256 + f*32 + lg*8;
        for (int j=0;j<8;++j) u.s[j]=f2b(p[j]);
      } else {
        const float* p = Whh + (long)r*256 + (w-2)*128 + f*32 + lg*8;
        for (int j=0;j<8;++j) u.s[j]=f2b(p[j]);
      }
    } else { for (int j=0;j<8;++j) u.s[j]=0; }
    bw[f]=u.v;
  }
  if (t<16) biasl[t] = bias[(t&3)*256 + u0 + (t>>2)];
  if (t<128) cst[t]=0.f;
  if (t<128){
    int par=(t>>6)&1, b=(t>>1)&31, j=t&1;
    cstore(exu + par*4096 + b*128 + wg*2 + j, 0);
  }
  __syncthreads();
  if (t==0) cstore(&flags[wg*FSTRIDE], base+1);
  const int waveOff = (w<2) ? w*16384 : 32768 + (w-2)*8192;
  const int NI  = (w<2) ? 16 : 8;
  const int rpi = (w<2) ? 2 : 4;
  const int sb  = (w<2) ? (lane>>5) : (lane>>4);
  const int coffb = (w<2) ? (lane&31)*16 : (lane&15)*16;
  const int rowB = (w<2) ? 512 : 256;
  for (int s=0; s<T; ++s){
    // x-half staging is flag-free (ATTFB is plain): issue before poll
    if (w<2){
      #pragma unroll
      for (int i=0;i<16;++i){
        int b = i*rpi + sb;
        const char* src = (const char*)xin + (long)s*32768 + w*512 + b*1024 + (coffb ^ ((b&7)<<4));
        void* ldst = (void*)(Vs + waveOff + i*1024);
        __builtin_amdgcn_global_load_lds((const u32*)src, (u32*)ldst, 16, 0, 0);
      }
    }
    waitflags(flags, base+s+1, 64);
    const int par = (s-1)&1;
    if (w>=2){
      #pragma unroll
      for (int i=0;i<8;++i){
        int b = i*rpi + sb;
        const char* src = (const char*)exd + par*16384 + (w-2)*256 + b*512 + (coffb ^ ((b&7)<<4));
        void* ldst = (void*)(Vs + waveOff + i*1024);
        __builtin_amdgcn_global_load_lds((const u32*)src, (u32*)ldst, 16, 0, 0x11);
      }
    }
    asm volatile("s_waitcnt vmcnt(0)" ::: "memory");
    __builtin_amdgcn_sched_barrier(0);
    f32x4 acc0={0.f,0.f,0.f,0.f}, acc1={0.f,0.f,0.f,0.f};
    const int b1 = c+16;
    #pragma unroll
    for (int f=0;f<8;++f){
      if (f>=nf) break;
      int koff = f*64 + lg*16;
      union { bf16x8 v; uint4 q; } a0, a1;
      a0.q = *(const uint4*)(Vs + waveOff + c *rowB + (koff ^ ((c &7)<<4)));
      a1.q = *(const uint4*)(Vs + waveOff + b1*rowB + (koff ^ ((b1&7)<<4)));
      acc0 = __builtin_amdgcn_mfma_f32_16x16x32_bf16(a0.v, bw[f], acc0, 0,0,0);
      acc1 = __builtin_amdgcn_mfma_f32_16x16x32_bf16(a1.v, bw[f], acc1, 0,0,0);
    }
    {
      float* pp = &P[(w*16+c)*36 + lg*4];
      *(f32x4*)pp      = acc0;
      *(f32x4*)(pp+16) = acc1;
    }
    __syncthreads();
    if (t<128){
      const int b = t&31, uu = t>>5, wpw = t>>6;
      float g4[4];
      #pragma unroll
      for (int g=0; g<4; ++g){
        int cc = uu*4+g;
        float sum = biasl[cc];
        #pragma unroll
        for (int ww=0; ww<4; ++ww) sum += P[(ww*16+cc)*36 + b];
        g4[g]=sum;
      }
      float c2 = sigm(g4[1])*cst[t] + sigm(g4[0])*tanh_f(g4[2]);
      float h2 = sigm(g4[3])*tanh_f(c2);
      cst[t]=c2;
      u32 hv = (u32)f2b(h2);
      u32 ot = (u32)__shfl_xor((int)hv, 32);
      if (lane<32)
        cstore(exu + (s&1)*4096 + b*128 + wg*2 + wpw, (hv&0xffffu)|(ot<<16));
      dout[((long)s*32+b)*256 + u0+uu] = h2;
    }
    __syncthreads();
    if (t==0) cstore(&flags[wg*FSTRIDE], base+s+2);
  }
}

// ---------------- x pre-convert: fp32 (B,1024,320) -> bf16 [t*32+b][512] ----
__global__ void cvt_x(const float* __restrict__ x, u16* __restrict__ xp){
  long id8 = ((long)blockIdx.x*256 + threadIdx.x)*8;
  int rr = (int)(id8 >> 9); int k = (int)(id8 & 511);
  int tt = rr >> 5, b = rr & 31;
  union { uint4 q; u16 s[8]; } u;
  if (k < 320){
    const float* p = x + (long)b*327680 + (long)tt*320 + k;
    float4 v0 = *(const float4*)p, v1 = *(const float4*)(p+4);
    u.s[0]=f2b(v0.x); u.s[1]=f2b(v0.y); u.s[2]=f2b(v0.z); u.s[3]=f2b(v0.w);
    u.s[4]=f2b(v1.x); u.s[5]=f2b(v1.y); u.s[6]=f2b(v1.z); u.s[7]=f2b(v1.w);
  } else {
    for (int j=0;j<8;++j) u.s[j]=0;
  }
  *(uint4*)(xp + id8) = u.q;
}

// ---------------- MFMA GEMM: C[m,n] = [A0|A1][m,:K] . W[n,:K] + bias[n] -----
// Optional xmask: multiply row m's output by xm[(m&31)*4096 + 4*(m>>5)].
template<int ABF, int CBF>
__global__ __launch_bounds__(256,2) void gemm_mfma(
  const void* __restrict__ A0, long lda0, const void* __restrict__ A1, long lda1, int K0,
  const float* __restrict__ W, const float* __restrict__ bias, void* __restrict__ C,
  int M, int N, int K, int ldw, int act, const float* __restrict__ xmask)
{
  __shared__ __align__(16) u16 As[64*32];
  __shared__ __align__(16) u16 Bs[64*32];
  const int t = threadIdx.x;
  const int m0 = blockIdx.x*64, n0 = blockIdx.y*64;
  const int w = t>>6, lane = t&63;
  const int al = lane&15, lg = lane>>4;
  f32x4 acc[4];
  #pragma unroll
  for (int i=0;i<4;++i) acc[i] = (f32x4){0.f,0.f,0.f,0.f};
  const int srow = t>>2, kq = t&3;
  const int spos = (kq ^ (srow&3))*8;
  for (int k0=0; k0<K; k0+=32){
    {
      int kk = k0 + kq*8;
      const void* Ab; long lda; int kof;
      if (kk < K0){ Ab=A0; lda=lda0; kof=kk; } else { Ab=A1; lda=lda1; kof=kk-K0; }
      union { uint4 q; u16 s[8]; } u;
      if (ABF){
        u.q = *(const uint4*)((const u16*)Ab + (long)(m0+srow)*lda + kof);
      } else {
        const float* ap = (const float*)Ab + (long)(m0+srow)*lda + kof;
        float4 x0 = *(const float4*)ap, x1 = *(const float4*)(ap+4);
        u.s[0]=f2b(x0.x); u.s[1]=f2b(x0.y); u.s[2]=f2b(x0.z); u.s[3]=f2b(x0.w);
        u.s[4]=f2b(x1.x); u.s[5]=f2b(x1.y); u.s[6]=f2b(x1.z); u.s[7]=f2b(x1.w);
      }
      *(uint4*)&As[srow*32 + spos] = u.q;
    }
    {
      int n = n0 + srow;
      union { uint4 q; u16 s[8]; } u;
      if (n < N){
        const float* wp = W + (long)n*ldw + k0 + kq*8;
        float4 y0 = *(const float4*)wp, y1 = *(const float4*)(wp+4);
        u.s[0]=f2b(y0.x); u.s[1]=f2b(y0.y); u.s[2]=f2b(y0.z); u.s[3]=f2b(y0.w);
        u.s[4]=f2b(y1.x); u.s[5]=f2b(y1.y); u.s[6]=f2b(y1.z); u.s[7]=f2b(y1.w);
      } else {
        for (int j=0;j<8;++j) u.s[j]=0;
      }
      *(uint4*)&Bs[srow*32 + spos] = u.q;
    }
    __syncthreads();
    union { bf16x8 v; uint4 q; } a;
    a.q = *(const uint4*)&As[(w*16+al)*32 + ((lg ^ (al&3))*8)];
    #pragma unroll
    for (int nt=0; nt<4; ++nt){
      union { bf16x8 v; uint4 q; } b;
      b.q = *(const uint4*)&Bs[(nt*16+al)*32 + ((lg ^ (al&3))*8)];
      acc[nt] = __builtin_amdgcn_mfma_f32_16x16x32_bf16(a.v, b.v, acc[nt], 0,0,0);
    }
    __syncthreads();
  }
  #pragma unroll
  for (int nt=0; nt<4; ++nt){
    int n = n0 + nt*16 + al;
    if (n >= N) continue;
    float bv = bias[n];
    #pragma unroll
    for (int j=0;j<4;++j){
      int m = m0 + w*16 + lg*4 + j;
      float v = acc[nt][j] + bv;
      if (act) v = (v > 0.f) ? v : 0.1f*v;
      if (xmask) v *= xmask[(m&31)*4096 + 4*(m>>5)];
      if (CBF) ((u16*)C)[(long)m*N + n] = f2b(v);
      else     ((float*)C)[(long)m*N + n] = v;
    }
  }
}

// ---------------- elementwise helpers --------------------------------------
__global__ void embed_gather(const float* __restrict__ emb, const int* __restrict__ y,
                             float* __restrict__ out){
  int id = blockIdx.x*256 + threadIdx.x;
  int p = id&255, r = id>>8;
  int l = r>>5, b = r&31;
  out[id] = emb[(long)y[b*65 + l]*256 + p];
}

__global__ void zero_f(float* __restrict__ p, int n){
  int id = blockIdx.x*256 + threadIdx.x;
  if (id < n) p[id] = 0.f;
}

__global__ void set_val(float* p, float v){ p[0] = v; }

__global__ void attfea_k(const float* __restrict__ lstms, const float* __restrict__ ctxs,
                         const float* __restrict__ ym, float* __restrict__ attf,
                         u16* __restrict__ attfb){
  long id4 = ((long)blockIdx.x*256 + threadIdx.x)*4;
  int r = (int)(id4>>9); int f = (int)(id4&511);
  int l = r>>5, b = r&31;
  float m = ym[b*65 + l + 1];
  float4 v = (f<256) ? *(const float4*)(lstms + (long)r*256 + f)
                     : *(const float4*)(ctxs  + (long)r*256 + (f-256));
  v.x*=m; v.y*=m; v.z*=m; v.w*=m;
  *(float4*)(attf + id4) = v;
  u16* ob = attfb + id4;
  ob[0]=f2b(v.x); ob[1]=f2b(v.y); ob[2]=f2b(v.z); ob[3]=f2b(v.w);
}

__global__ void dcat_k(const float* __restrict__ attf, const float* __restrict__ dout,
                       const float* __restrict__ ym, float* __restrict__ dcat){
  long id4 = ((long)blockIdx.x*256 + threadIdx.x)*4;
  int r = (int)(id4/768); int f = (int)(id4 - (long)r*768);
  int l = r>>5, b = r&31;
  float m = ym[b*65 + l + 1];
  float4 v = (f<512) ? *(const float4*)(attf + (long)r*512 + f)
                     : *(const float4*)(dout + (long)r*256 + (f-512));
  v.x*=m; v.y*=m; v.z*=m; v.w*=m;
  *(float4*)(dcat + id4) = v;
}

// ---------------- decoder attention step kernels ----------------------------
__global__ __launch_bounds__(256,1) void k1_dec(
  const float* __restrict__ bodyR, float* __restrict__ bodyW,
  const float* __restrict__ epart, const float* __restrict__ Whh,
  const float* __restrict__ Wih, float* __restrict__ cc,
  float* __restrict__ lstms, int s)
{
  __shared__ __align__(16) float vT[512*36];
  __shared__ float gl[32*32];
  const int t = threadIdx.x, wg = blockIdx.x;
  for (int i = t*4; i < 32*512; i += 1024){
    int b = i>>9, k = i&511;
    float4 v = *(const float4*)(bodyR + b*512 + k);
    vT[(k+0)*36+b]=v.x; vT[(k+1)*36+b]=v.y; vT[(k+2)*36+b]=v.z; vT[(k+3)*36+b]=v.w;
  }
  __syncthreads();
  const int c_l = t>>3, bq = t&7;
  const int col = (c_l&3)*256 + wg*8 + (c_l>>2);
  float a0=0.f,a1=0.f,a2=0.f,a3=0.f;
  for (int k=0;k<256;k+=4){
    float4 w = *(const float4*)(Whh + (long)col*256 + k);
    const float* vp = &vT[k*36 + bq*4];
    float4 v0=*(const float4*)(vp), v1=*(const float4*)(vp+36), v2=*(const float4*)(vp+72), v3=*(const float4*)(vp+108);
    a0 += w.x*v0.x + w.y*v1.x + w.z*v2.x + w.w*v3.x;
    a1 += w.x*v0.y + w.y*v1.y + w.z*v2.y + w.w*v3.y;
    a2 += w.x*v0.z + w.y*v1.z + w.z*v2.z + w.w*v3.z;
    a3 += w.x*v0.w + w.y*v1.w + w.z*v2.w + w.w*v3.w;
  }
  for (int k=256;k<512;k+=4){
    float4 w = *(const float4*)(Wih + (long)col*512 + k);
    const float* vp = &vT[k*36 + bq*4];
    float4 v0=*(const float4*)(vp), v1=*(const float4*)(vp+36), v2=*(const float4*)(vp+72), v3=*(const float4*)(vp+108);
    a0 += w.x*v0.x + w.y*v1.x + w.z*v2.x + w.w*v3.x;
    a1 += w.x*v0.y + w.y*v1.y + w.z*v2.y + w.w*v3.y;
    a2 += w.x*v0.z + w.y*v1.z + w.z*v2.z + w.w*v3.z;
    a3 += w.x*v0.w + w.y*v1.w + w.z*v2.w + w.w*v3.w;
  }
  gl[c_l*32+bq*4+0] = a0 + epart[((long)s*32 + bq*4+0)*1024 + col];
  gl[c_l*32+bq*4+1] = a1 + epart[((long)s*32 + bq*4+1)*1024 + col];
  gl[c_l*32+bq*4+2] = a2 + epart[((long)s*32 + bq*4+2)*1024 + col];
  gl[c_l*32+bq*4+3] = a3 + epart[((long)s*32 + bq*4+3)*1024 + col];
  __syncthreads();
  {
    const int u_ = t>>5, b = t&31, ug = wg*8 + u_;
    const float gi=gl[(u_*4+0)*32+b], gf=gl[(u_*4+1)*32+b], gg=gl[(u_*4+2)*32+b], go=gl[(u_*4+3)*32+b];
    float c0 = cc[b*256+ug];
    float c2 = sigm(gf)*c0 + sigm(gi)*tanh_f(gg);
    float h2 = sigm(go)*tanh_f(c2);
    cc[b*256+ug] = c2;
    bodyW[b*512 + ug] = h2;
    lstms[((long)s*32 + b)*256 + ug] = h2;
  }
}

__global__ __launch_bounds__(256,1) void k2_dec(
  const float* __restrict__ bodyW, const float* __restrict__ vW,
  const float* __restrict__ vb, float* __restrict__ state)
{
  __shared__ __align__(16) float hT[256*36];
  const int t = threadIdx.x, wg = blockIdx.x;
  for (int i = t*4; i < 8192; i += 1024){
    int b = i>>8, k = i&255;
    float4 v = *(const float4*)(bodyW + b*512 + k);
    hT[(k+0)*36+b]=v.x; hT[(k+1)*36+b]=v.y; hT[(k+2)*36+b]=v.z; hT[(k+3)*36+b]=v.w;
  }
  __syncthreads();
  const int p = wg*32 + (t>>3), bq = t&7;
  float a0=0.f,a1=0.f,a2=0.f,a3=0.f;
  for (int k=0;k<256;k+=4){
    float4 w = *(const float4*)(vW + (long)p*256 + k);
    const float* vp = &hT[k*36 + bq*4];
    float4 v0=*(const float4*)(vp), v1=*(const float4*)(vp+36), v2=*(const float4*)(vp+72), v3=*(const float4*)(vp+108);
    a0 += w.x*v0.x + w.y*v1.x + w.z*v2.x + w.w*v3.x;
    a1 += w.x*v0.y + w.y*v1.y + w.z*v2.y + w.w*v3.y;
    a2 += w.x*v0.z + w.y*v1.z + w.z*v2.z + w.w*v3.z;
    a3 += w.x*v0.w + w.y*v1.w + w.z*v2.w + w.w*v3.w;
  }
  float bb = vb[p];
  state[(bq*4+0)*256 + p] = a0 + bb;
  state[(bq*4+1)*256 + p] = a1 + bb;
  state[(bq*4+2)*256 + p] = a2 + bb;
  state[(bq*4+3)*256 + p] = a3 + bb;
}

__global__ __launch_bounds__(256,1) void k3_dec(
  const float* __restrict__ state, const u16* __restrict__ atth,
  const float* __restrict__ wav, const float* __restrict__ xm,
  float* __restrict__ sc, float* __restrict__ scm)
{
  __shared__ float st[256], wv[256], red[256];
  const int t = threadIdx.x;
  const int b = blockIdx.x>>2, ch = blockIdx.x&3;
  st[t] = state[b*256 + t];
  wv[t] = wav[t];
  __syncthreads();
  const int tp = ch*256 + t;
  const u16* ap = atth + ((long)tp*32 + b)*256;
  float acc = 0.f;
  for (int p=0;p<256;p+=4){
    ushort4 a = *(const ushort4*)(ap+p);
    acc += wv[p+0]*tanh_f(st[p+0]+b2f(a.x));
    acc += wv[p+1]*tanh_f(st[p+1]+b2f(a.y));
    acc += wv[p+2]*tanh_f(st[p+2]+b2f(a.z));
    acc += wv[p+3]*tanh_f(st[p+3]+b2f(a.w));
  }
  acc += (xm[b*4096 + 4*tp] - 1.0f)*1e30f;
  sc[b*1024 + tp] = acc;
  red[t] = acc;
  __syncthreads();
  for (int o=128;o>0;o>>=1){ if (t<o) red[t]=fmaxf(red[t],red[t+o]); __syncthreads(); }
  if (t==0) scm[b*4+ch] = red[0];
}

__global__ __launch_bounds__(256,1) void k4_dec(
  const float* __restrict__ sc, const float* __restrict__ scm,
  const u16* __restrict__ eout, float* __restrict__ ctxs,
  float* __restrict__ bodyW, int s)
{
  __shared__ float al[1024];
  __shared__ float red[256];
  const int t = threadIdx.x, b = blockIdx.x;
  float m = fmaxf(fmaxf(scm[b*4+0],scm[b*4+1]), fmaxf(scm[b*4+2],scm[b*4+3]));
  float ps = 0.f;
  #pragma unroll
  for (int j=0;j<4;++j){
    int tp = t + j*256;
    float e = __expf(sc[b*1024+tp] - m);
    al[tp] = e; ps += e;
  }
  red[t]=ps; __syncthreads();
  for (int o=128;o>0;o>>=1){ if (t<o) red[t]+=red[t+o]; __syncthreads(); }
  float rinv = 1.0f/red[0];
  float acc = 0.f;
  const u16* ep = eout + b*256 + t;
  for (int tp=0;tp<1024;++tp) acc += al[tp] * b2f(ep[(long)tp*8192]);
  float cv = acc*rinv;
  ctxs[((long)s*32 + b)*256 + t] = cv;
  bodyW[b*512 + 256 + t] = cv;
}

// ---------------- loss ------------------------------------------------------
__global__ __launch_bounds__(256,1) void loss_row(
  const float* __restrict__ logits, const int* __restrict__ y,
  const float* __restrict__ ym, float* __restrict__ rows)
{
  __shared__ float red[256];
  const int r = blockIdx.x, t = threadIdx.x;
  const float* row = logits + (long)r*4235;
  float mx = -3.0e38f;
  for (int i=t;i<4235;i+=256) mx = fmaxf(mx, row[i]);
  red[t]=mx; __syncthreads();
  for (int o=128;o>0;o>>=1){ if (t<o) red[t]=fmaxf(red[t],red[t+o]); __syncthreads(); }
  const float M = red[0];
  __syncthreads();
  float se=0.f, sl=0.f;
  for (int i=t;i<4235;i+=256){ float v=row[i]; se += __expf(v-M); sl += v; }
  red[t]=se; __syncthreads();
  for (int o=128;o>0;o>>=1){ if (t<o) red[t]+=red[t+o]; __syncthreads(); }
  const float SE = red[0];
  __syncthreads();
  red[t]=sl; __syncthreads();
  for (int o=128;o>0;o>>=1){ if (t<o) red[t]+=red[t+o]; __syncthreads(); }
  const float SL = red[0];
  if (t==0){
    const int tt = r>>5, b = r&31;
    const float lse = M + logf(SE);
    const float mk = (ym[b*65 + tt + 1] > 0.f) ? 1.f : 0.f;
    rows[r]        = (4235.0f*lse - SL)*mk;
    rows[2048 + r] = (lse - row[y[b*65 + tt + 1]])*mk;
    rows[4096 + r] = mk;
  }
}

__global__ __launch_bounds__(256,1) void loss_final(const float* __restrict__ rows, float* __restrict__ out){
  __shared__ float red[256];
  const int t = threadIdx.x;
  float s1=0.f,s2=0.f,s3=0.f;
  for (int i=t;i<2048;i+=256){ s1+=rows[i]; s2+=rows[2048+i]; s3+=rows[4096+i]; }
  red[t]=s1; __syncthreads();
  for (int o=128;o>0;o>>=1){ if (t<o) red[t]+=red[t+o]; __syncthreads(); }
  const float S = red[0]; __syncthreads();
  red[t]=s2; __syncthreads();
  for (int o=128;o>0;o>>=1){ if (t<o) red[t]+=red[t+o]; __syncthreads(); }
  const float NL = red[0]; __syncthreads();
  red[t]=s3; __syncthreads();
  for (int o=128;o>0;o>>=1){ if (t<o) red[t]+=red[t+o]; __syncthreads(); }
  const float N = red[0];
  if (t==0){
    float n = (N > 0.f) ? N : 1.f;
    out[0] = (S/n)*(0.1f/4235.0f) + 0.9f*(NL/n);
  }
}

// ---------------- launcher --------------------------------------------------
extern "C" void kernel_launch(void* const* d_in, const int* in_sizes, int n_in,
                              void* d_out, int out_size, void* d_ws, size_t ws_size,
                              hipStream_t stream)
{
  const float* x    = (const float*)d_in[0];
  const float* xm   = (const float*)d_in[1];
  const int*   y    = (const int*)  d_in[2];
  const float* ym   = (const float*)d_in[3];
  const float* l1_Wih=(const float*)d_in[4];  const float* l1_Whh=(const float*)d_in[5];  const float* l1_b=(const float*)d_in[6];
  const float* l2_Wih=(const float*)d_in[7];  const float* l2_Whh=(const float*)d_in[8];  const float* l2_b=(const float*)d_in[9];
  const float* l3_Wih=(const float*)d_in[10]; const float* l3_Whh=(const float*)d_in[11]; const float* l3_b=(const float*)d_in[12];
  const float* bf_Wih=(const float*)d_in[13]; const float* bf_Whh=(const float*)d_in[14]; const float* bf_b=(const float*)d_in[15];
  const float* bb_Wih=(const float*)d_in[16]; const float* bb_Whh=(const float*)d_in[17]; const float* bb_b=(const float*)d_in[18];
  const float* c1_W=(const float*)d_in[19]; const float* c1_b=(const float*)d_in[20];
  const float* c2_W=(const float*)d_in[21]; const float* c2_b=(const float*)d_in[22];
  const float* emb =(const float*)d_in[23];
  const float* att_Wih=(const float*)d_in[24]; const float* att_Whh=(const float*)d_in[25]; const float* att_b=(const float*)d_in[26];
  const float* w_W=(const float*)d_in[27]; const float* w_b=(const float*)d_in[28];
  const float* v_W=(const float*)d_in[29]; const float* v_b=(const float*)d_in[30];
  const float* wav=(const float*)d_in[31];
  const float* dec_Wih=(const float*)d_in[32]; const float* dec_Whh=(const float*)d_in[33]; const float* dec_b=(const float*)d_in[34];
  const float* cls_W=(const float*)d_in[35]; const float* cls_b=(const float*)d_in[36];

  const size_t REQ = 137625600ull; // ~131.3 MiB (verified fit)
  if (ws_size < REQ){
    set_val<<<1,1,0,stream>>>((float*)d_out, -(float)(ws_size>>20));
    return;
  }
  char* ws = (char*)d_ws;
  unsigned* FLAGS  = (unsigned*)(ws);           // 128 WGs x 128B = 16KB (padded)
  unsigned* FLAGSD = (unsigned*)(ws + 16384);   // decoder: 64 x 128B = 8KB
  u16* EXU  = (u16*)(ws + 65536);               // 4x2x32x512 = 256KB
  u16* EXM  = (u16*)(ws + 327680);              // 2x32x512 = 64KB
  u16* EXD  = (u16*)(ws + 393216);              // 2x32x256 = 32KB
  u16* XP   = (u16*)(ws + 2097152);             // 32MB
  u16* HS2  = (u16*)(ws + 35651584);            // 32MB (masked h3)
  u16* HSF  = (u16*)(ws + 69206016);            // 32MB (masked bf)
  u16* HSB  = XP;                               // masked bb overlays XP
  u16* C1OUT = HS2;                             // after bb done
  u16* EOUTB = HSF;                             // 16MB (HSF dead after conv1)
  u16* ATTHB = (u16*)(ws + 85983232);           // 16MB
  float* LOGIT = (float*)XP;                    // after conv2
  float* AR    = (float*)(ws + 102760448);      // decoder arena
  float* EMBED = AR;
  float* EPART = EMBED + 524288;
  float* LSTMS = EPART + 2097152;
  float* CTXS  = LSTMS + 524288;
  float* ATTF  = CTXS  + 524288;
  float* DOUT  = ATTF  + 1048576;
  float* DCAT  = DOUT  + 524288;
  float* SC    = DCAT  + 1572864;
  float* SCM   = SC    + 32768;
  float* ROWS  = SCM   + 128;
  float* BODY  = ROWS  + 6144;
  float* CC    = BODY  + 32768;
  float* STATE = CC    + 8192;
  u16*  ATTFB  = (u16*)(STATE + 8192);

  (void)hipMemsetAsync(ws, 0, 32768, stream);

  // ---------------- encoder: phase A (l1,l2,l3,bf pipelined, fence-free) ----
  cvt_x<<<8192,256,0,stream>>>(x, XP);
  PA2 pa;
  pa.L[0] = { l1_Wih, l1_Whh, l1_b, XP,      nullptr, 320, 0 };
  pa.L[1] = { l2_Wih, l2_Whh, l2_b, nullptr, nullptr, 512, 0 };
  pa.L[2] = { l3_Wih, l3_Whh, l3_b, nullptr, HS2,     512, 0 };
  pa.L[3] = { bf_Wih, bf_Whh, bf_b, nullptr, HSF,     512, 1 };
  pa.ex = EXU; pa.exm = EXM; pa.xm = xm; pa.flags = FLAGS;
  pa.T = 1024; pa.nwg = 128; pa.rev = 0; pa.base = 0;
  pipe2<4><<<128,256,0,stream>>>(pa);
  // ---------------- encoder: phase B (bb, reverse) --------------------------
  PA2 pb;
  pb.L[0] = { bb_Wih, bb_Whh, bb_b, HS2, HSB, 512, 1 };
  pb.L[1] = pb.L[0]; pb.L[2] = pb.L[0]; pb.L[3] = pb.L[0];
  pb.ex = EXU; pb.exm = EXM; pb.xm = xm; pb.flags = FLAGS;
  pb.T = 1024; pb.nwg = 128; pb.rev = 1; pb.base = 1028;
  pipe2<1><<<128,256,0,stream>>>(pb);
  // conv1 (leaky) on concat [bf|bb], conv2+mask fused, att_h — MFMA GEMMs
  gemm_mfma<1,1><<<dim3(512,8),256,0,stream>>>(HSF, 512, HSB, 512, 512,
      c1_W, c1_b, C1OUT, 32768, 512, 1024, 1024, 1, nullptr);
  gemm_mfma<1,1><<<dim3(512,4),256,0,stream>>>(C1OUT, 512, C1OUT, 512, 512,
      c2_W, c2_b, EOUTB, 32768, 256, 512, 512, 0, xm);
  gemm_mfma<1,1><<<dim3(512,4),256,0,stream>>>(EOUTB, 256, EOUTB, 256, 256,
      w_W, w_b, ATTHB, 32768, 256, 256, 256, 0, nullptr);

  // ---------------- decoder -------------------------------------------------
  embed_gather<<<2048,256,0,stream>>>(emb, y, EMBED);
  gemm_mfma<0,0><<<dim3(32,16),256,0,stream>>>(EMBED, 256, EMBED, 256, 256,
      att_Wih, att_b, EPART, 2048, 1024, 256, 512, 0, nullptr);
  zero_f<<<160,256,0,stream>>>(BODY, 40960);
  for (int s=0;s<64;++s){
    float* bodyR = BODY + (s&1)*16384;
    float* bodyW = BODY + ((s+1)&1)*16384;
    k1_dec<<<32,256,0,stream>>>(bodyR, bodyW, EPART, att_Whh, att_Wih, CC, LSTMS, s);
    k2_dec<<<8,256,0,stream>>>(bodyW, v_W, v_b, STATE);
    k3_dec<<<128,256,0,stream>>>(STATE, ATTHB, wav, xm, SC, SCM);
    k4_dec<<<32,256,0,stream>>>(SC, SCM, EOUTB, CTXS, bodyW, s);
  }
  attfea_k<<<1024,256,0,stream>>>(LSTMS, CTXS, ym, ATTF, ATTFB);
  dec_rec2<<<64,256,0,stream>>>(ATTFB, dec_Wih, dec_Whh, dec_b,
      DOUT, EXD, FLAGSD, 0u, 64);
  dcat_k<<<1536,256,0,stream>>>(ATTF, DOUT, ym, DCAT);
  gemm_mfma<0,0><<<dim3(32,67),256,0,stream>>>(DCAT, 768, DCAT, 768, 768,
      cls_W, cls_b, LOGIT, 2048, 4235, 768, 768, 0, nullptr);
  loss_row<<<2048,256,0,stream>>>(LOGIT, y, ym, ROWS);
  loss_final<<<1,256,0,stream>>>(ROWS, (float*)d_out);
}